// Round 9
// baseline (318.563 us; speedup 1.0000x reference)
//
#include <hip/hip_runtime.h>
#include <hip/hip_bf16.h>

#define B_ 2
#define N_ 4096
#define D_ 1024
#define QLD_ 3072
#define H_ 16
#define GH_ 8
#define DH_ 64
#define M_ 256
#define W_ 256
#define NW_ 16
#define EPS_ 1e-4f
#define RATIO_ 0.0625f
#define R_ (B_*N_)

typedef __attribute__((ext_vector_type(8))) short short8;
typedef __attribute__((ext_vector_type(4))) short short4_;
typedef __attribute__((ext_vector_type(4))) float float4_;

__device__ __forceinline__ float b2f(unsigned short u){
  union { unsigned int i; float f; } x; x.i = ((unsigned int)u) << 16; return x.f;
}
__device__ __forceinline__ unsigned short f2b(float f){
  unsigned int u = __float_as_uint(f);
  u = u + 0x7FFFu + ((u >> 16) & 1u);
  return (unsigned short)(u >> 16);
}
__device__ __forceinline__ unsigned int encf(float x){
  unsigned int u = __float_as_uint(x);
  return (u & 0x80000000u) ? ~u : (u | 0x80000000u);
}
__device__ __forceinline__ float decf(unsigned int e){
  unsigned int u = (e & 0x80000000u) ? (e ^ 0x80000000u) : ~e;
  return __uint_as_float(u);
}
__device__ __forceinline__ void gl_lds16(const unsigned short* g, unsigned short* l){
  __builtin_amdgcn_global_load_lds((const __attribute__((address_space(1))) unsigned int*)g,
                                   (__attribute__((address_space(3))) unsigned int*)l, 16, 0, 0);
}

// ---------------------------------------------------------------- casts (init fused into cast_proj)
__global__ void cast_f32_bf16(const float* __restrict__ src, unsigned short* __restrict__ dst, int n8){
  int i = blockIdx.x*256 + threadIdx.x;
  if (i >= n8) return;
  const float4_* sp = (const float4_*)src + (size_t)i*2;
  float4_ a = sp[0], b = sp[1];
  short8 o;
  o[0]=(short)f2b(a[0]); o[1]=(short)f2b(a[1]); o[2]=(short)f2b(a[2]); o[3]=(short)f2b(a[3]);
  o[4]=(short)f2b(b[0]); o[5]=(short)f2b(b[1]); o[6]=(short)f2b(b[2]); o[7]=(short)f2b(b[3]);
  *((short8*)dst + i) = o;
}

__global__ void cast_proj(const float* __restrict__ proj, unsigned short* __restrict__ projb,
                          unsigned int* __restrict__ stab_enc){
  int i = blockIdx.x*256 + threadIdx.x;
  if (i == 0) *stab_enc = encf(-3.0e38f);
  if (i < M_*DH_) projb[i] = f2b(proj[i]*0.35355339059327373f);
}

__global__ void transpose_w(const float* w0, const float* w1, const float* w2, const float* w3,
                            unsigned short* t0, unsigned short* t1, unsigned short* t2, unsigned short* t3){
  const float* src; unsigned short* dst;
  switch (blockIdx.z){
    case 0: src = w0; dst = t0; break;
    case 1: src = w1; dst = t1; break;
    case 2: src = w2; dst = t2; break;
    default: src = w3; dst = t3; break;
  }
  __shared__ float tile[64][65];
  int r0 = blockIdx.x*64, c0 = blockIdx.y*64;
  for (int it = 0; it < 16; ++it){
    int idx = it*256 + threadIdx.x;
    int r = idx >> 6, c = idx & 63;
    tile[r][c] = src[(size_t)(r0 + r)*D_ + c0 + c];
  }
  __syncthreads();
  for (int it = 0; it < 16; ++it){
    int idx = it*256 + threadIdx.x;
    int r = idx >> 6, c = idx & 63;
    dst[(size_t)(c0 + r)*D_ + r0 + c] = f2b(tile[c][r]);
  }
}

// QKV[b][n][2048+col] (V cols) -> Vt[b*H+h][d][n]; also vcol[bh][d] = sum_n V for global heads
__global__ void transpose_v(const unsigned short* __restrict__ Vb, unsigned short* __restrict__ Vt,
                            float* __restrict__ vcol){
  __shared__ unsigned short tile[64*72];
  int nt = blockIdx.x, h = blockIdx.y, b = blockIdx.z;
  int n0 = nt*64, col0 = h*64;
  int tid = threadIdx.x;
  int r = tid >> 2, c16 = (tid & 3)*16;
  #pragma unroll
  for (int g = 0; g < 2; ++g){
    short8 v = *(const short8*)&Vb[((size_t)b*N_ + n0 + r)*QLD_ + col0 + c16 + g*8];
    #pragma unroll
    for (int e = 0; e < 8; ++e) tile[r*72 + c16 + g*8 + e] = (unsigned short)v[e];
  }
  __syncthreads();
  if (h < GH_){
    int c = tid & 63, g = tid >> 6;
    float s = 0.f;
    #pragma unroll
    for (int i = 0; i < 16; ++i) s += b2f(tile[(g*16 + i)*72 + c]);
    atomicAdd(&vcol[(b*GH_ + h)*64 + c], s);
  }
  int d = tid >> 2, ng = (tid & 3)*16;
  short8 o0, o1;
  #pragma unroll
  for (int e = 0; e < 8; ++e){ o0[e] = (short)tile[(ng + e)*72 + d]; o1[e] = (short)tile[(ng + 8 + e)*72 + d]; }
  size_t ob = ((size_t)(b*H_ + h)*64 + d)*N_ + n0 + ng;
  *(short8*)&Vt[ob] = o0;
  *(short8*)&Vt[ob + 8] = o1;
}

// ---------------------------------------------------------------- GEMM, m97 structure (global_load_lds, BK=32)
// swizzled source chunks + matching ds_read XOR -> conflict-free (verified R7: conflicts 6.3M -> 0)
template<int FINAL>
__launch_bounds__(256)
__global__ void gemm_bf16(const unsigned short* __restrict__ A, const unsigned short* __restrict__ Bt,
                          unsigned short* __restrict__ Cb, float* __restrict__ Cf,
                          const float* __restrict__ bias, int K, int Ncols){
  __shared__ __attribute__((aligned(16))) unsigned short As[128*32];
  __shared__ __attribute__((aligned(16))) unsigned short Bs[128*32];
  int tid = threadIdx.x, lane = tid & 63, wave = tid >> 6;
  int bm = blockIdx.x*128, bn = blockIdx.y*128;
  int wm = (wave >> 1)*64, wn = (wave & 1)*64;
  float4_ acc[4][4];
  #pragma unroll
  for (int i = 0; i < 4; ++i)
    #pragma unroll
    for (int j = 0; j < 4; ++j)
      #pragma unroll
      for (int r = 0; r < 4; ++r) acc[i][j][r] = 0.f;
  int srow = tid >> 2, c = tid & 3;
  int scol = (c ^ ((srow >> 1) & 3))*8;
  const unsigned short* a0 = &A[(size_t)(bm + srow)*K + scol];
  const unsigned short* a1 = &A[(size_t)(bm + 64 + srow)*K + scol];
  const unsigned short* b0 = &Bt[(size_t)(bn + srow)*K + scol];
  const unsigned short* b1 = &Bt[(size_t)(bn + 64 + srow)*K + scol];
  unsigned short* la0 = &As[tid*8];
  unsigned short* la1 = &As[2048 + tid*8];
  unsigned short* lb0 = &Bs[tid*8];
  unsigned short* lb1 = &Bs[2048 + tid*8];
  int p4 = lane >> 4, l15 = lane & 15;
  for (int k0 = 0; k0 < K; k0 += 32){
    gl_lds16(a0, la0); gl_lds16(a1, la1);
    gl_lds16(b0, lb0); gl_lds16(b1, lb1);
    a0 += 32; a1 += 32; b0 += 32; b1 += 32;
    __syncthreads();
    short8 af[4], bf[4];
    #pragma unroll
    for (int i = 0; i < 4; ++i){
      int row = wm + i*16 + l15;
      af[i] = *(const short8*)&As[row*32 + (p4 ^ ((row >> 1) & 3))*8];
    }
    #pragma unroll
    for (int j = 0; j < 4; ++j){
      int row = wn + j*16 + l15;
      bf[j] = *(const short8*)&Bs[row*32 + (p4 ^ ((row >> 1) & 3))*8];
    }
    #pragma unroll
    for (int i = 0; i < 4; ++i)
      #pragma unroll
      for (int j = 0; j < 4; ++j)
        acc[i][j] = __builtin_amdgcn_mfma_f32_16x16x32_bf16(af[i], bf[j], acc[i][j], 0, 0, 0);
    __syncthreads();
  }
  int rr = p4*4, cc = l15;
  #pragma unroll
  for (int i = 0; i < 4; ++i)
    #pragma unroll
    for (int j = 0; j < 4; ++j)
      #pragma unroll
      for (int r = 0; r < 4; ++r){
        size_t row = bm + wm + i*16 + rr + r;
        int col = bn + wn + j*16 + cc;
        if (FINAL) Cf[row*(size_t)Ncols + col] = acc[i][j][r] + bias[col];
        else       Cb[row*(size_t)Ncols + col] = f2b(acc[i][j][r]);
      }
}

// ---------------------------------------------------------------- fused phi-K + ctx (stab-deferred):
// u = exp(dd - diag) into swizzled LDS -> ksum atomic + max(dd) atomic -> in-place MFMA with Vt chunk
// -> atomicAdd into single L2-resident ctx[bh][m][d] f32 (no phikT, no split partials).
__launch_bounds__(256)
__global__ void phik_ctx(const unsigned short* __restrict__ Kb, const unsigned short* __restrict__ projb,
                         const unsigned short* __restrict__ Vt, float* __restrict__ ctx,
                         float* __restrict__ ksum, unsigned int* __restrict__ stab_enc){
  __shared__ __attribute__((aligned(16))) unsigned short pl[256*64];
  int tid = threadIdx.x, lane = tid & 63, wave = tid >> 6;
  int h = blockIdx.y, b = blockIdx.z, nb = blockIdx.x;
  int n0 = nb*64;
  int col0 = h*64;
  int p4 = lane >> 4, l15 = lane & 15, kk = p4*8;
  int bh = b*GH_ + h;
  size_t rowbase = (size_t)b*N_ + n0 + wave*16;
  short8 qa[2];
  #pragma unroll
  for (int ks = 0; ks < 2; ++ks)
    qa[ks] = *(const short8*)&Kb[(rowbase + l15)*QLD_ + col0 + ks*32 + kk];
  float s = 0.f;
  #pragma unroll
  for (int ks = 0; ks < 2; ++ks)
    #pragma unroll
    for (int j = 0; j < 8; ++j){ float q = b2f((unsigned short)qa[ks][j]); s += q*q; }
  s += __shfl_xor(s, 16, 64);
  s += __shfl_xor(s, 32, 64);
  s *= 0.0625f;
  float dg[4];
  #pragma unroll
  for (int r = 0; r < 4; ++r) dg[r] = __shfl(s, (lane & 48) | (p4*4 + r), 64);
  float mxall = -3e38f;
  #pragma unroll
  for (int mt = 0; mt < 16; ++mt){
    float4_ a; a[0]=a[1]=a[2]=a[3]=0.f;
    #pragma unroll
    for (int ks = 0; ks < 2; ++ks){
      short8 bfr = *(const short8*)&projb[(size_t)(mt*16 + l15)*DH_ + ks*32 + kk];
      a = __builtin_amdgcn_mfma_f32_16x16x32_bf16(qa[ks], bfr, a, 0, 0, 0);
    }
    int m = mt*16 + l15;
    #pragma unroll
    for (int r = 0; r < 4; ++r){
      float ddv = a[r];
      mxall = fmaxf(mxall, ddv);
      float v = __expf(ddv - dg[r]);     // u, stab applied analytically later
      int n = wave*16 + p4*4 + r;
      int slot = (n >> 3) ^ (m & 7);
      pl[m*64 + slot*8 + (n & 7)] = f2b(v);
    }
  }
  #pragma unroll
  for (int mm = 1; mm < 64; mm <<= 1) mxall = fmaxf(mxall, __shfl_xor(mxall, mm, 64));
  if (lane == 0) atomicMax(stab_enc, encf(mxall));
  __syncthreads();
  // ksum pass (reads pl, un-swizzled row walk)
  {
    int m = tid;
    float ssum = 0.f;
    #pragma unroll
    for (int j = 0; j < 8; ++j){
      int slot = j ^ (m & 7);
      short8 v = *(const short8*)&pl[m*64 + slot*8];
      #pragma unroll
      for (int e = 0; e < 8; ++e) ssum += b2f((unsigned short)v[e]);
    }
    atomicAdd(&ksum[bh*M_ + m], ssum);
  }
  // ctx partial: u-chunk (256m x 64n) @ V-chunk (64n x 64d), accumulate into ctx via atomics
  float4_ acc[4][4];
  #pragma unroll
  for (int i = 0; i < 4; ++i)
    #pragma unroll
    for (int j = 0; j < 4; ++j)
      #pragma unroll
      for (int r = 0; r < 4; ++r) acc[i][j][r] = 0.f;
  const unsigned short* Bbase = Vt + (size_t)(b*H_ + h)*64*N_;
  #pragma unroll
  for (int ks = 0; ks < 2; ++ks){
    short8 af[4], bf[4];
    #pragma unroll
    for (int mt = 0; mt < 4; ++mt){
      int m = wave*64 + mt*16 + l15;
      int q = ks*4 + p4;
      af[mt] = *(const short8*)&pl[m*64 + (q ^ (m & 7))*8];
    }
    #pragma unroll
    for (int dt = 0; dt < 4; ++dt)
      bf[dt] = *(const short8*)&Bbase[(size_t)(dt*16 + l15)*N_ + n0 + ks*32 + kk];
    #pragma unroll
    for (int mt = 0; mt < 4; ++mt)
      #pragma unroll
      for (int dt = 0; dt < 4; ++dt)
        acc[mt][dt] = __builtin_amdgcn_mfma_f32_16x16x32_bf16(af[mt], bf[dt], acc[mt][dt], 0, 0, 0);
  }
  int rr = p4*4;
  #pragma unroll
  for (int mt = 0; mt < 4; ++mt)
    #pragma unroll
    for (int dt = 0; dt < 4; ++dt)
      #pragma unroll
      for (int r = 0; r < 4; ++r)
        atomicAdd(&ctx[((size_t)bh*M_ + wave*64 + mt*16 + rr + r)*64 + dt*16 + l15], acc[mt][dt][r]);
}

// finalize ctx: apply ratio*e^{-stab} + ratio*eps*vcol, transpose -> ctxbT[bh][d][m] bf16
__launch_bounds__(256)
__global__ void ctx_finalize(const float* __restrict__ ctx, const float* __restrict__ vcol,
                             const unsigned int* __restrict__ stab_enc, unsigned short* __restrict__ ctxbT){
  __shared__ float tile[16*65];
  int mt = blockIdx.x, bh = blockIdx.y;
  int tid = threadIdx.x;
  float es = RATIO_*__expf(-decf(*stab_enc));
  float epsr = RATIO_*EPS_;
  int ml = tid >> 4, d4 = (tid & 15)*4;
  float4_ v = *(const float4_*)&ctx[((size_t)bh*M_ + mt*16 + ml)*64 + d4];
  float4_ acc;
  #pragma unroll
  for (int e = 0; e < 4; ++e) acc[e] = es*v[e] + epsr*vcol[bh*64 + d4 + e];
  *(float4_*)&tile[ml*65 + d4] = acc;
  __syncthreads();
  int d = tid >> 2, mg = (tid & 3)*4;
  short4_ o;
  #pragma unroll
  for (int e = 0; e < 4; ++e) o[e] = (short)f2b(tile[(mg + e)*65 + d]);
  *(short4_*)&ctxbT[((size_t)bh*64 + d)*256 + mt*16 + mg] = o;
}

// ---------------------------------------------------------------- fused phi-Q + out_g
__launch_bounds__(256)
__global__ void phiq_outg(const unsigned short* __restrict__ Qb, const unsigned short* __restrict__ projb,
                          const unsigned short* __restrict__ ctxbT, const float* __restrict__ ksum_u,
                          const unsigned int* __restrict__ stab_enc, unsigned short* __restrict__ attnb){
  __shared__ __attribute__((aligned(16))) unsigned short pl[4][16*256];
  __shared__ float ks_l[256];
  int tid = threadIdx.x, lane = tid & 63, wave = tid >> 6;
  int h = blockIdx.y, b = blockIdx.z;
  int n0 = blockIdx.x*64;
  int col0 = h*64;
  int bh = b*GH_ + h;
  int p4 = lane >> 4, l15 = lane & 15, kk = p4*8;
  {
    float es = __expf(-decf(*stab_enc));
    ks_l[tid] = RATIO_*(es*ksum_u[bh*M_ + tid] + EPS_*(float)N_);
  }
  __syncthreads();
  size_t rowbase = (size_t)b*N_ + n0 + wave*16;
  short8 qa[2];
  #pragma unroll
  for (int ks = 0; ks < 2; ++ks)
    qa[ks] = *(const short8*)&Qb[(rowbase + l15)*QLD_ + col0 + ks*32 + kk];
  float s = 0.f;
  #pragma unroll
  for (int ks = 0; ks < 2; ++ks)
    #pragma unroll
    for (int j = 0; j < 8; ++j){ float q = b2f((unsigned short)qa[ks][j]); s += q*q; }
  s += __shfl_xor(s, 16, 64);
  s += __shfl_xor(s, 32, 64);
  s *= 0.0625f;
  float dg[4];
  #pragma unroll
  for (int r = 0; r < 4; ++r) dg[r] = __shfl(s, (lane & 48) | (p4*4 + r), 64);
  float4_ dd[16];
  #pragma unroll
  for (int mt = 0; mt < 16; ++mt){
    float4_ a; a[0]=a[1]=a[2]=a[3]=0.f;
    #pragma unroll
    for (int ks = 0; ks < 2; ++ks){
      short8 bfr = *(const short8*)&projb[(size_t)(mt*16 + l15)*DH_ + ks*32 + kk];
      a = __builtin_amdgcn_mfma_f32_16x16x32_bf16(qa[ks], bfr, a, 0, 0, 0);
    }
    dd[mt] = a;
  }
  unsigned short* plw = &pl[wave][0];
  float dinv[4];
  #pragma unroll
  for (int r = 0; r < 4; ++r){
    float mx = dd[0][r];
    #pragma unroll
    for (int mt = 1; mt < 16; ++mt) mx = fmaxf(mx, dd[mt][r]);
    mx = fmaxf(mx, __shfl_xor(mx, 1, 64));
    mx = fmaxf(mx, __shfl_xor(mx, 2, 64));
    mx = fmaxf(mx, __shfl_xor(mx, 4, 64));
    mx = fmaxf(mx, __shfl_xor(mx, 8, 64));
    float sb = mx + dg[r];
    int row = p4*4 + r;
    float dpr = 0.f;
    #pragma unroll
    for (int mt = 0; mt < 16; ++mt){
      float v = RATIO_*(__expf(dd[mt][r] - sb) + EPS_);
      dpr += v*ks_l[mt*16 + l15];
      int q = mt*2 + (l15 >> 3);
      plw[row*256 + ((q ^ (row & 7)) << 3) + (l15 & 7)] = f2b(v);
    }
    dpr += __shfl_xor(dpr, 1, 64);
    dpr += __shfl_xor(dpr, 2, 64);
    dpr += __shfl_xor(dpr, 4, 64);
    dpr += __shfl_xor(dpr, 8, 64);
    dinv[r] = 1.f/dpr;
  }
  float4_ acc[4];
  #pragma unroll
  for (int dt = 0; dt < 4; ++dt){ acc[dt][0]=acc[dt][1]=acc[dt][2]=acc[dt][3]=0.f; }
  #pragma unroll
  for (int ks = 0; ks < 8; ++ks){
    int q = ks*4 + p4;
    short8 af = *(const short8*)&plw[l15*256 + ((q ^ (l15 & 7)) << 3)];
    #pragma unroll
    for (int dt = 0; dt < 4; ++dt){
      short8 bf = *(const short8*)&ctxbT[((size_t)bh*64 + dt*16 + l15)*M_ + ks*32 + kk];
      acc[dt] = __builtin_amdgcn_mfma_f32_16x16x32_bf16(af, bf, acc[dt], 0, 0, 0);
    }
  }
  #pragma unroll
  for (int dt = 0; dt < 4; ++dt)
    #pragma unroll
    for (int r = 0; r < 4; ++r){
      int rloc = wave*16 + p4*4 + r;
      attnb[((size_t)b*N_ + n0 + rloc)*D_ + col0 + dt*16 + l15] = f2b(acc[dt][r]*dinv[r]);
    }
}

// ---------------------------------------------------------------- local windowed attention
// Swapped QK, no online rescale, QT=2. 1-D grid with XCD-aware decode: all 32 q-blocks of a
// given (head,batch) land on one XCD -> its 2MB K/V slice stays L2-resident (T1).
__launch_bounds__(256)
__global__ void local_attn_kernel(const unsigned short* __restrict__ Qb, const unsigned short* __restrict__ Kb,
                                  const unsigned short* __restrict__ Vt, unsigned short* __restrict__ attnb){
  int tid = threadIdx.x, lane = tid & 63, wv = tid >> 6;
  int wg = blockIdx.x;
  int xcd = wg & 7, k = wg >> 3;
  int pair = xcd*2 + (k >> 5);
  int bx = k & 31;
  int hl = pair & 7, b = pair >> 3;
  int w = bx >> 1;
  int col0 = (GH_ + hl)*64;
  int q0 = bx*128 + wv*32;
  int l15 = lane & 15, p4 = lane >> 4, kk = p4*8;
  int sA = ((l15 >> 2) << 3) + (l15 & 3);
  const unsigned short* Kbase = Kb + (size_t)b*N_*QLD_ + col0;
  const unsigned short* Vrow  = Vt + (size_t)(b*H_ + GH_ + hl)*64*N_;
  short8 qa[2][2];
  #pragma unroll
  for (int qt = 0; qt < 2; ++qt)
    #pragma unroll
    for (int ks = 0; ks < 2; ++ks){
      short8 v = *(const short8*)&Qb[((size_t)b*N_ + q0 + qt*16 + l15)*QLD_ + col0 + ks*32 + kk];
      #pragma unroll
      for (int j = 0; j < 8; ++j) v[j] = (short)f2b(b2f((unsigned short)v[j])*0.125f);
      qa[qt][ks] = v;
    }
  float l_part[2] = {0.f, 0.f};
  float4_ accv[2][4];
  #pragma unroll
  for (int qt = 0; qt < 2; ++qt)
    #pragma unroll
    for (int dt = 0; dt < 4; ++dt){ accv[qt][dt][0]=accv[qt][dt][1]=accv[qt][dt][2]=accv[qt][dt][3]=0.f; }
  int wlo = (w > 0) ? w - 1 : 0;
  int whi = (w < NW_ - 1) ? w + 1 : NW_ - 1;
  for (int wi = wlo; wi <= whi; ++wi){
    #pragma unroll
    for (int c = 0; c < 4; ++c){
      int key0 = wi*W_ + c*64;
      const unsigned short* Kc = Kbase + (size_t)key0*QLD_;
      float4_ s[2][4];
      #pragma unroll
      for (int qt = 0; qt < 2; ++qt)
        #pragma unroll
        for (int kt = 0; kt < 4; ++kt){ s[qt][kt][0]=s[qt][kt][1]=s[qt][kt][2]=s[qt][kt][3]=0.f; }
      #pragma unroll
      for (int ks = 0; ks < 2; ++ks){
        short8 kb0 = *(const short8*)&Kc[(size_t)(sA +  0)*QLD_ + ks*32 + kk];
        short8 kb1 = *(const short8*)&Kc[(size_t)(sA +  4)*QLD_ + ks*32 + kk];
        short8 kb2 = *(const short8*)&Kc[(size_t)(sA + 32)*QLD_ + ks*32 + kk];
        short8 kb3 = *(const short8*)&Kc[(size_t)(sA + 36)*QLD_ + ks*32 + kk];
        #pragma unroll
        for (int qt = 0; qt < 2; ++qt){
          s[qt][0] = __builtin_amdgcn_mfma_f32_16x16x32_bf16(kb0, qa[qt][ks], s[qt][0], 0, 0, 0);
          s[qt][1] = __builtin_amdgcn_mfma_f32_16x16x32_bf16(kb1, qa[qt][ks], s[qt][1], 0, 0, 0);
          s[qt][2] = __builtin_amdgcn_mfma_f32_16x16x32_bf16(kb2, qa[qt][ks], s[qt][2], 0, 0, 0);
          s[qt][3] = __builtin_amdgcn_mfma_f32_16x16x32_bf16(kb3, qa[qt][ks], s[qt][3], 0, 0, 0);
        }
      }
      short8 af[2][2];
      #pragma unroll
      for (int qt = 0; qt < 2; ++qt){
        float p[4][4];
        float rs = 0.f;
        #pragma unroll
        for (int kt = 0; kt < 4; ++kt)
          #pragma unroll
          for (int r = 0; r < 4; ++r){
            p[kt][r] = __expf(s[qt][kt][r]);
            rs += p[kt][r];
          }
        l_part[qt] += rs;
        #pragma unroll
        for (int half = 0; half < 2; ++half){
          short8 a;
          #pragma unroll
          for (int r = 0; r < 4; ++r){
            a[r]     = (short)f2b(p[half*2 + 0][r]);
            a[r + 4] = (short)f2b(p[half*2 + 1][r]);
          }
          af[qt][half] = a;
        }
      }
      #pragma unroll
      for (int ks = 0; ks < 2; ++ks){
        short8 vb0 = *(const short8*)&Vrow[(size_t)( 0 + l15)*N_ + key0 + ks*32 + kk];
        short8 vb1 = *(const short8*)&Vrow[(size_t)(16 + l15)*N_ + key0 + ks*32 + kk];
        short8 vb2 = *(const short8*)&Vrow[(size_t)(32 + l15)*N_ + key0 + ks*32 + kk];
        short8 vb3 = *(const short8*)&Vrow[(size_t)(48 + l15)*N_ + key0 + ks*32 + kk];
        #pragma unroll
        for (int qt = 0; qt < 2; ++qt){
          accv[qt][0] = __builtin_amdgcn_mfma_f32_16x16x32_bf16(af[qt][ks], vb0, accv[qt][0], 0, 0, 0);
          accv[qt][1] = __builtin_amdgcn_mfma_f32_16x16x32_bf16(af[qt][ks], vb1, accv[qt][1], 0, 0, 0);
          accv[qt][2] = __builtin_amdgcn_mfma_f32_16x16x32_bf16(af[qt][ks], vb2, accv[qt][2], 0, 0, 0);
          accv[qt][3] = __builtin_amdgcn_mfma_f32_16x16x32_bf16(af[qt][ks], vb3, accv[qt][3], 0, 0, 0);
        }
      }
    }
  }
  #pragma unroll
  for (int qt = 0; qt < 2; ++qt){
    float lv = l_part[qt];
    lv += __shfl_xor(lv, 16, 64);
    lv += __shfl_xor(lv, 32, 64);
    float ilq[4];
    #pragma unroll
    for (int r = 0; r < 4; ++r)
      ilq[r] = 1.f/__shfl(lv, (lane & 48) | (p4*4 + r), 64);
    #pragma unroll
    for (int dt = 0; dt < 4; ++dt)
      #pragma unroll
      for (int r = 0; r < 4; ++r)
        attnb[((size_t)b*N_ + q0 + qt*16 + p4*4 + r)*D_ + col0 + dt*16 + l15] = f2b(accv[qt][dt][r]*ilq[r]);
  }
}

// ---------------------------------------------------------------- host launch
extern "C" void kernel_launch(void* const* d_in, const int* in_sizes, int n_in,
                              void* d_out, int out_size, void* d_ws, size_t ws_size,
                              hipStream_t stream){
  const float* x    = (const float*)d_in[0];
  const float* Wq   = (const float*)d_in[1];
  const float* Wk   = (const float*)d_in[2];
  const float* Wv   = (const float*)d_in[3];
  const float* Wo   = (const float*)d_in[4];
  const float* bo   = (const float*)d_in[5];
  const float* proj = (const float*)d_in[6];
  float* out = (float*)d_out;
  char* ws = (char*)d_ws;

  const size_t o_Wqt  = 0;                               // Wqt|Wkt|Wvt contiguous = fused B
  const size_t o_Wkt  = o_Wqt  + (size_t)D_*D_*2;
  const size_t o_Wvt  = o_Wkt  + (size_t)D_*D_*2;
  const size_t o_Wot  = o_Wvt  + (size_t)D_*D_*2;
  const size_t o_Xb   = o_Wot  + (size_t)D_*D_*2;        // reused as attnb
  const size_t o_QKV  = o_Xb   + (size_t)R_*D_*2;        // [R][3072]
  const size_t o_Vt   = o_QKV  + (size_t)R_*QLD_*2;
  const size_t o_ksum = o_Vt   + (size_t)B_*H_*DH_*N_*2; // ksum|vcol|ctx contiguous (one memset)
  const size_t o_vcol = o_ksum + (size_t)B_*GH_*M_*4;
  const size_t o_ctx  = o_vcol + (size_t)B_*GH_*DH_*4;
  const size_t o_ctxT = o_ctx  + (size_t)B_*GH_*M_*DH_*4;
  const size_t o_projb= o_ctxT + (size_t)B_*GH_*DH_*M_*2;
  const size_t o_stab = o_projb+ (size_t)M_*DH_*2;

  unsigned short* Wqt  = (unsigned short*)(ws + o_Wqt);
  unsigned short* Wkt  = (unsigned short*)(ws + o_Wkt);
  unsigned short* Wvt  = (unsigned short*)(ws + o_Wvt);
  unsigned short* Wot  = (unsigned short*)(ws + o_Wot);
  unsigned short* Xb   = (unsigned short*)(ws + o_Xb);
  unsigned short* attnb= Xb;
  unsigned short* QKV  = (unsigned short*)(ws + o_QKV);
  unsigned short* Vt   = (unsigned short*)(ws + o_Vt);
  float*          ksum = (float*)(ws + o_ksum);
  float*          vcol = (float*)(ws + o_vcol);
  float*          ctx  = (float*)(ws + o_ctx);
  unsigned short* ctxT = (unsigned short*)(ws + o_ctxT);
  unsigned short* projb= (unsigned short*)(ws + o_projb);
  unsigned int*   stab = (unsigned int*)(ws + o_stab);

  (void)in_sizes; (void)n_in; (void)out_size; (void)ws_size;

  // zero ksum + vcol + ctx (contiguous)
  (void)hipMemsetAsync(ws + o_ksum, 0,
                       (size_t)B_*GH_*M_*4 + (size_t)B_*GH_*DH_*4 + (size_t)B_*GH_*M_*DH_*4, stream);
  cast_f32_bf16<<<R_*D_/8/256, 256, 0, stream>>>(x, Xb, R_*D_/8);
  cast_proj<<<64, 256, 0, stream>>>(proj, projb, stab);
  transpose_w<<<dim3(16,16,4), 256, 0, stream>>>(Wq, Wk, Wv, Wo, Wqt, Wkt, Wvt, Wot);

  // fused QKV projection: C[row][3072] = Xb @ [Wqt|Wkt|Wvt]^T
  gemm_bf16<0><<<dim3(64,24), 256, 0, stream>>>(Xb, Wqt, QKV, nullptr, nullptr, D_, QLD_);

  transpose_v<<<dim3(64,16,2), 256, 0, stream>>>(QKV + 2048, Vt, vcol);

  phik_ctx<<<dim3(64,8,2), 256, 0, stream>>>(QKV + 1024, projb, Vt, ctx, ksum, stab);
  ctx_finalize<<<dim3(16,16), 256, 0, stream>>>(ctx, vcol, stab, ctxT);
  phiq_outg<<<dim3(64,8,2), 256, 0, stream>>>(QKV, projb, ctxT, ksum, stab, attnb);
  local_attn_kernel<<<512, 256, 0, stream>>>(QKV, QKV + 1024, Vt, attnb);

  gemm_bf16<1><<<dim3(64,8), 256, 0, stream>>>(attnb, Wot, nullptr, out, bo, D_, D_);
}

// Round 10
// 297.661 us; speedup vs baseline: 1.0702x; 1.0702x over previous
//
#include <hip/hip_runtime.h>
#include <hip/hip_bf16.h>

#define B_ 2
#define N_ 4096
#define D_ 1024
#define QLD_ 3072
#define H_ 16
#define GH_ 8
#define DH_ 64
#define M_ 256
#define W_ 256
#define NW_ 16
#define EPS_ 1e-4f
#define RATIO_ 0.0625f
#define R_ (B_*N_)

typedef __attribute__((ext_vector_type(8))) short short8;
typedef __attribute__((ext_vector_type(4))) short short4_;
typedef __attribute__((ext_vector_type(4))) float float4_;

__device__ __forceinline__ float b2f(unsigned short u){
  union { unsigned int i; float f; } x; x.i = ((unsigned int)u) << 16; return x.f;
}
__device__ __forceinline__ unsigned short f2b(float f){
  unsigned int u = __float_as_uint(f);
  u = u + 0x7FFFu + ((u >> 16) & 1u);
  return (unsigned short)(u >> 16);
}
__device__ __forceinline__ unsigned int encf(float x){
  unsigned int u = __float_as_uint(x);
  return (u & 0x80000000u) ? ~u : (u | 0x80000000u);
}
__device__ __forceinline__ float decf(unsigned int e){
  unsigned int u = (e & 0x80000000u) ? (e ^ 0x80000000u) : ~e;
  return __uint_as_float(u);
}
__device__ __forceinline__ void gl_lds16(const unsigned short* g, unsigned short* l){
  __builtin_amdgcn_global_load_lds((const __attribute__((address_space(1))) unsigned int*)g,
                                   (__attribute__((address_space(3))) unsigned int*)l, 16, 0, 0);
}

// ---------------------------------------------------------------- casts (init fused into cast_proj)
__global__ void cast_f32_bf16(const float* __restrict__ src, unsigned short* __restrict__ dst, int n8){
  int i = blockIdx.x*256 + threadIdx.x;
  if (i >= n8) return;
  const float4_* sp = (const float4_*)src + (size_t)i*2;
  float4_ a = sp[0], b = sp[1];
  short8 o;
  o[0]=(short)f2b(a[0]); o[1]=(short)f2b(a[1]); o[2]=(short)f2b(a[2]); o[3]=(short)f2b(a[3]);
  o[4]=(short)f2b(b[0]); o[5]=(short)f2b(b[1]); o[6]=(short)f2b(b[2]); o[7]=(short)f2b(b[3]);
  *((short8*)dst + i) = o;
}

__global__ void cast_proj(const float* __restrict__ proj, unsigned short* __restrict__ projb,
                          unsigned int* __restrict__ stab_enc){
  int i = blockIdx.x*256 + threadIdx.x;
  if (i == 0) *stab_enc = encf(-3.0e38f);
  if (i < M_*DH_) projb[i] = f2b(proj[i]*0.35355339059327373f);
}

__global__ void transpose_w(const float* w0, const float* w1, const float* w2, const float* w3,
                            unsigned short* t0, unsigned short* t1, unsigned short* t2, unsigned short* t3){
  const float* src; unsigned short* dst;
  switch (blockIdx.z){
    case 0: src = w0; dst = t0; break;
    case 1: src = w1; dst = t1; break;
    case 2: src = w2; dst = t2; break;
    default: src = w3; dst = t3; break;
  }
  __shared__ float tile[64][65];
  int r0 = blockIdx.x*64, c0 = blockIdx.y*64;
  for (int it = 0; it < 16; ++it){
    int idx = it*256 + threadIdx.x;
    int r = idx >> 6, c = idx & 63;
    tile[r][c] = src[(size_t)(r0 + r)*D_ + c0 + c];
  }
  __syncthreads();
  for (int it = 0; it < 16; ++it){
    int idx = it*256 + threadIdx.x;
    int r = idx >> 6, c = idx & 63;
    dst[(size_t)(c0 + r)*D_ + r0 + c] = f2b(tile[c][r]);
  }
}

// QKV[b][n][2048+col] (V cols) -> Vt[b*H+h][d][n]; also vcol[bh][d] = sum_n V for global heads
__global__ void transpose_v(const unsigned short* __restrict__ Vb, unsigned short* __restrict__ Vt,
                            float* __restrict__ vcol){
  __shared__ unsigned short tile[64*72];
  int nt = blockIdx.x, h = blockIdx.y, b = blockIdx.z;
  int n0 = nt*64, col0 = h*64;
  int tid = threadIdx.x;
  int r = tid >> 2, c16 = (tid & 3)*16;
  #pragma unroll
  for (int g = 0; g < 2; ++g){
    short8 v = *(const short8*)&Vb[((size_t)b*N_ + n0 + r)*QLD_ + col0 + c16 + g*8];
    #pragma unroll
    for (int e = 0; e < 8; ++e) tile[r*72 + c16 + g*8 + e] = (unsigned short)v[e];
  }
  __syncthreads();
  if (h < GH_){
    int c = tid & 63, g = tid >> 6;
    float s = 0.f;
    #pragma unroll
    for (int i = 0; i < 16; ++i) s += b2f(tile[(g*16 + i)*72 + c]);
    atomicAdd(&vcol[(b*GH_ + h)*64 + c], s);
  }
  int d = tid >> 2, ng = (tid & 3)*16;
  short8 o0, o1;
  #pragma unroll
  for (int e = 0; e < 8; ++e){ o0[e] = (short)tile[(ng + e)*72 + d]; o1[e] = (short)tile[(ng + 8 + e)*72 + d]; }
  size_t ob = ((size_t)(b*H_ + h)*64 + d)*N_ + n0 + ng;
  *(short8*)&Vt[ob] = o0;
  *(short8*)&Vt[ob + 8] = o1;
}

// ---------------------------------------------------------------- GEMM, m97 structure (global_load_lds, BK=32)
// swizzled source chunks + matching ds_read XOR -> conflict-free (verified R7: conflicts 6.3M -> 0)
template<int FINAL>
__launch_bounds__(256)
__global__ void gemm_bf16(const unsigned short* __restrict__ A, const unsigned short* __restrict__ Bt,
                          unsigned short* __restrict__ Cb, float* __restrict__ Cf,
                          const float* __restrict__ bias, int K, int Ncols){
  __shared__ __attribute__((aligned(16))) unsigned short As[128*32];
  __shared__ __attribute__((aligned(16))) unsigned short Bs[128*32];
  int tid = threadIdx.x, lane = tid & 63, wave = tid >> 6;
  int bm = blockIdx.x*128, bn = blockIdx.y*128;
  int wm = (wave >> 1)*64, wn = (wave & 1)*64;
  float4_ acc[4][4];
  #pragma unroll
  for (int i = 0; i < 4; ++i)
    #pragma unroll
    for (int j = 0; j < 4; ++j)
      #pragma unroll
      for (int r = 0; r < 4; ++r) acc[i][j][r] = 0.f;
  int srow = tid >> 2, c = tid & 3;
  int scol = (c ^ ((srow >> 1) & 3))*8;
  const unsigned short* a0 = &A[(size_t)(bm + srow)*K + scol];
  const unsigned short* a1 = &A[(size_t)(bm + 64 + srow)*K + scol];
  const unsigned short* b0 = &Bt[(size_t)(bn + srow)*K + scol];
  const unsigned short* b1 = &Bt[(size_t)(bn + 64 + srow)*K + scol];
  unsigned short* la0 = &As[tid*8];
  unsigned short* la1 = &As[2048 + tid*8];
  unsigned short* lb0 = &Bs[tid*8];
  unsigned short* lb1 = &Bs[2048 + tid*8];
  int p4 = lane >> 4, l15 = lane & 15;
  for (int k0 = 0; k0 < K; k0 += 32){
    gl_lds16(a0, la0); gl_lds16(a1, la1);
    gl_lds16(b0, lb0); gl_lds16(b1, lb1);
    a0 += 32; a1 += 32; b0 += 32; b1 += 32;
    __syncthreads();
    short8 af[4], bf[4];
    #pragma unroll
    for (int i = 0; i < 4; ++i){
      int row = wm + i*16 + l15;
      af[i] = *(const short8*)&As[row*32 + (p4 ^ ((row >> 1) & 3))*8];
    }
    #pragma unroll
    for (int j = 0; j < 4; ++j){
      int row = wn + j*16 + l15;
      bf[j] = *(const short8*)&Bs[row*32 + (p4 ^ ((row >> 1) & 3))*8];
    }
    #pragma unroll
    for (int i = 0; i < 4; ++i)
      #pragma unroll
      for (int j = 0; j < 4; ++j)
        acc[i][j] = __builtin_amdgcn_mfma_f32_16x16x32_bf16(af[i], bf[j], acc[i][j], 0, 0, 0);
    __syncthreads();
  }
  int rr = p4*4, cc = l15;
  #pragma unroll
  for (int i = 0; i < 4; ++i)
    #pragma unroll
    for (int j = 0; j < 4; ++j)
      #pragma unroll
      for (int r = 0; r < 4; ++r){
        size_t row = bm + wm + i*16 + rr + r;
        int col = bn + wn + j*16 + cc;
        if (FINAL) Cf[row*(size_t)Ncols + col] = acc[i][j][r] + bias[col];
        else       Cb[row*(size_t)Ncols + col] = f2b(acc[i][j][r]);
      }
}

// ---------------------------------------------------------------- phi-K single pass (stab-deferred):
// u = exp(dd - diag); track max(dd) -> atomicMax(stab); write uT tiles + raw ksum_u
__launch_bounds__(256)
__global__ void phik_finish(const unsigned short* __restrict__ Kb, const unsigned short* __restrict__ projb,
                            unsigned short* __restrict__ phikT, float* __restrict__ ksum,
                            unsigned int* __restrict__ stab_enc){
  __shared__ __attribute__((aligned(16))) unsigned short pl[256*64];
  int tid = threadIdx.x, lane = tid & 63, wave = tid >> 6;
  int h = blockIdx.y, b = blockIdx.z, nb = blockIdx.x;
  int n0 = nb*64;
  int col0 = h*64;
  int kk = (lane >> 4)*8, l15 = lane & 15;
  int bh = b*GH_ + h;
  size_t rowbase = (size_t)b*N_ + n0 + wave*16;
  short8 qa[2];
  #pragma unroll
  for (int ks = 0; ks < 2; ++ks)
    qa[ks] = *(const short8*)&Kb[(rowbase + l15)*QLD_ + col0 + ks*32 + kk];
  float s = 0.f;
  #pragma unroll
  for (int ks = 0; ks < 2; ++ks)
    #pragma unroll
    for (int j = 0; j < 8; ++j){ float q = b2f((unsigned short)qa[ks][j]); s += q*q; }
  s += __shfl_xor(s, 16, 64);
  s += __shfl_xor(s, 32, 64);
  s *= 0.0625f;
  float dg[4];
  #pragma unroll
  for (int r = 0; r < 4; ++r) dg[r] = __shfl(s, (lane & 48) | ((lane >> 4)*4 + r), 64);
  float mxall = -3e38f;
  #pragma unroll
  for (int mt = 0; mt < 16; ++mt){
    float4_ a; a[0]=a[1]=a[2]=a[3]=0.f;
    #pragma unroll
    for (int ks = 0; ks < 2; ++ks){
      short8 bfr = *(const short8*)&projb[(size_t)(mt*16 + l15)*DH_ + ks*32 + kk];
      a = __builtin_amdgcn_mfma_f32_16x16x32_bf16(qa[ks], bfr, a, 0, 0, 0);
    }
    int m = mt*16 + l15;
    #pragma unroll
    for (int r = 0; r < 4; ++r){
      float ddv = a[r];
      mxall = fmaxf(mxall, ddv);
      float v = __expf(ddv - dg[r]);     // u, stab applied analytically later
      int n = wave*16 + (lane>>4)*4 + r;
      int slot = (n >> 3) ^ (m & 7);
      pl[m*64 + slot*8 + (n & 7)] = f2b(v);
    }
  }
  #pragma unroll
  for (int mm = 1; mm < 64; mm <<= 1) mxall = fmaxf(mxall, __shfl_xor(mxall, mm, 64));
  if (lane == 0) atomicMax(stab_enc, encf(mxall));
  __syncthreads();
  int m = tid;
  float ssum = 0.f;
  size_t outbase = (((size_t)bh*64 + nb)*256 + m)*64;
  #pragma unroll
  for (int j = 0; j < 8; ++j){
    int slot = j ^ (m & 7);
    short8 v = *(const short8*)&pl[m*64 + slot*8];
    #pragma unroll
    for (int e = 0; e < 8; ++e) ssum += b2f((unsigned short)v[e]);
    *(short8*)&phikT[outbase + j*8] = v;
  }
  atomicAdd(&ksum[bh*M_ + m], ssum);
}

// ---------------------------------------------------------------- ctx partials: C[m][d] += uT-chunk @ Vt-chunk
__launch_bounds__(256)
__global__ void ctx_kernel(const unsigned short* __restrict__ phikT, const unsigned short* __restrict__ Vt,
                           float* __restrict__ ctxp){
  int tid = threadIdx.x, lane = tid & 63, wave = tid >> 6;
  int split = blockIdx.x, h = blockIdx.y, b = blockIdx.z;
  int bh = b*GH_ + h;
  int kk = (lane >> 4)*8, l15 = lane & 15;
  float4_ acc[4][4];
  #pragma unroll
  for (int i = 0; i < 4; ++i)
    #pragma unroll
    for (int j = 0; j < 4; ++j)
      #pragma unroll
      for (int r = 0; r < 4; ++r) acc[i][j][r] = 0.f;
  const unsigned short* Abase = phikT + (size_t)bh*64*256*64;
  const unsigned short* Bbase = Vt + (size_t)(b*H_ + h)*64*N_;
  int n0 = split*256;
  #pragma unroll
  for (int ks = 0; ks < 8; ++ks){
    int n = n0 + ks*32;
    int nb = n >> 6, in0 = n & 32;
    short8 af[4], bf[4];
    #pragma unroll
    for (int mt = 0; mt < 4; ++mt)
      af[mt] = *(const short8*)&Abase[((size_t)nb*256 + wave*64 + mt*16 + l15)*64 + in0 + kk];
    #pragma unroll
    for (int dt = 0; dt < 4; ++dt)
      bf[dt] = *(const short8*)&Bbase[(size_t)(dt*16 + l15)*N_ + n + kk];
    #pragma unroll
    for (int mt = 0; mt < 4; ++mt)
      #pragma unroll
      for (int dt = 0; dt < 4; ++dt)
        acc[mt][dt] = __builtin_amdgcn_mfma_f32_16x16x32_bf16(af[mt], bf[dt], acc[mt][dt], 0, 0, 0);
  }
  int rr = (lane >> 4)*4;
  float* obase = ctxp + (((size_t)split*16 + bh)*256)*64;
  #pragma unroll
  for (int mt = 0; mt < 4; ++mt)
    #pragma unroll
    for (int dt = 0; dt < 4; ++dt)
      #pragma unroll
      for (int r = 0; r < 4; ++r)
        obase[(size_t)(wave*64 + mt*16 + rr + r)*64 + dt*16 + l15] = acc[mt][dt][r];
}

// reduce 16 splits, apply ratio*e^{-stab} scale + ratio*eps*vcol -> ctxbT[bh][d][m] bf16
__launch_bounds__(256)
__global__ void ctx_reduce(const float* __restrict__ ctxp, const float* __restrict__ vcol,
                           const unsigned int* __restrict__ stab_enc, unsigned short* __restrict__ ctxbT){
  __shared__ float tile[16*65];
  int mt = blockIdx.x, bh = blockIdx.y;
  int tid = threadIdx.x;
  float es = RATIO_*__expf(-decf(*stab_enc));
  float epsr = RATIO_*EPS_;
  int ml = tid >> 4, d4 = (tid & 15)*4;
  const float* base = ctxp + ((size_t)bh*256 + mt*16 + ml)*64 + d4;
  float4_ acc; acc[0]=acc[1]=acc[2]=acc[3]=0.f;
  #pragma unroll
  for (int sp = 0; sp < 16; ++sp){
    float4_ v = *(const float4_*)(base + (size_t)sp*16*256*64);
    acc[0] += v[0]; acc[1] += v[1]; acc[2] += v[2]; acc[3] += v[3];
  }
  #pragma unroll
  for (int e = 0; e < 4; ++e) acc[e] = es*acc[e] + epsr*vcol[bh*64 + d4 + e];
  *(float4_*)&tile[ml*65 + d4] = acc;
  __syncthreads();
  int d = tid >> 2, mg = (tid & 3)*4;
  short4_ o;
  #pragma unroll
  for (int e = 0; e < 4; ++e) o[e] = (short)f2b(tile[(mg + e)*65 + d]);
  *(short4_*)&ctxbT[((size_t)bh*64 + d)*256 + mt*16 + mg] = o;
}

// ---------------------------------------------------------------- fused phi-Q + out_g
__launch_bounds__(256)
__global__ void phiq_outg(const unsigned short* __restrict__ Qb, const unsigned short* __restrict__ projb,
                          const unsigned short* __restrict__ ctxbT, const float* __restrict__ ksum_u,
                          const unsigned int* __restrict__ stab_enc, unsigned short* __restrict__ attnb){
  __shared__ __attribute__((aligned(16))) unsigned short pl[4][16*256];
  __shared__ float ks_l[256];
  int tid = threadIdx.x, lane = tid & 63, wave = tid >> 6;
  int h = blockIdx.y, b = blockIdx.z;
  int n0 = blockIdx.x*64;
  int col0 = h*64;
  int bh = b*GH_ + h;
  int p4 = lane >> 4, l15 = lane & 15, kk = p4*8;
  {
    float es = __expf(-decf(*stab_enc));
    ks_l[tid] = RATIO_*(es*ksum_u[bh*M_ + tid] + EPS_*(float)N_);
  }
  __syncthreads();
  size_t rowbase = (size_t)b*N_ + n0 + wave*16;
  short8 qa[2];
  #pragma unroll
  for (int ks = 0; ks < 2; ++ks)
    qa[ks] = *(const short8*)&Qb[(rowbase + l15)*QLD_ + col0 + ks*32 + kk];
  float s = 0.f;
  #pragma unroll
  for (int ks = 0; ks < 2; ++ks)
    #pragma unroll
    for (int j = 0; j < 8; ++j){ float q = b2f((unsigned short)qa[ks][j]); s += q*q; }
  s += __shfl_xor(s, 16, 64);
  s += __shfl_xor(s, 32, 64);
  s *= 0.0625f;
  float dg[4];
  #pragma unroll
  for (int r = 0; r < 4; ++r) dg[r] = __shfl(s, (lane & 48) | (p4*4 + r), 64);
  float4_ dd[16];
  #pragma unroll
  for (int mt = 0; mt < 16; ++mt){
    float4_ a; a[0]=a[1]=a[2]=a[3]=0.f;
    #pragma unroll
    for (int ks = 0; ks < 2; ++ks){
      short8 bfr = *(const short8*)&projb[(size_t)(mt*16 + l15)*DH_ + ks*32 + kk];
      a = __builtin_amdgcn_mfma_f32_16x16x32_bf16(qa[ks], bfr, a, 0, 0, 0);
    }
    dd[mt] = a;
  }
  unsigned short* plw = &pl[wave][0];
  float dinv[4];
  #pragma unroll
  for (int r = 0; r < 4; ++r){
    float mx = dd[0][r];
    #pragma unroll
    for (int mt = 1; mt < 16; ++mt) mx = fmaxf(mx, dd[mt][r]);
    mx = fmaxf(mx, __shfl_xor(mx, 1, 64));
    mx = fmaxf(mx, __shfl_xor(mx, 2, 64));
    mx = fmaxf(mx, __shfl_xor(mx, 4, 64));
    mx = fmaxf(mx, __shfl_xor(mx, 8, 64));
    float sb = mx + dg[r];
    int row = p4*4 + r;
    float dpr = 0.f;
    #pragma unroll
    for (int mt = 0; mt < 16; ++mt){
      float v = RATIO_*(__expf(dd[mt][r] - sb) + EPS_);
      dpr += v*ks_l[mt*16 + l15];
      int q = mt*2 + (l15 >> 3);
      plw[row*256 + ((q ^ (row & 7)) << 3) + (l15 & 7)] = f2b(v);
    }
    dpr += __shfl_xor(dpr, 1, 64);
    dpr += __shfl_xor(dpr, 2, 64);
    dpr += __shfl_xor(dpr, 4, 64);
    dpr += __shfl_xor(dpr, 8, 64);
    dinv[r] = 1.f/dpr;
  }
  float4_ acc[4];
  #pragma unroll
  for (int dt = 0; dt < 4; ++dt){ acc[dt][0]=acc[dt][1]=acc[dt][2]=acc[dt][3]=0.f; }
  #pragma unroll
  for (int ks = 0; ks < 8; ++ks){
    int q = ks*4 + p4;
    short8 af = *(const short8*)&plw[l15*256 + ((q ^ (l15 & 7)) << 3)];
    #pragma unroll
    for (int dt = 0; dt < 4; ++dt){
      short8 bf = *(const short8*)&ctxbT[((size_t)bh*64 + dt*16 + l15)*M_ + ks*32 + kk];
      acc[dt] = __builtin_amdgcn_mfma_f32_16x16x32_bf16(af, bf, acc[dt], 0, 0, 0);
    }
  }
  #pragma unroll
  for (int dt = 0; dt < 4; ++dt)
    #pragma unroll
    for (int r = 0; r < 4; ++r){
      int rloc = wave*16 + p4*4 + r;
      attnb[((size_t)b*N_ + n0 + rloc)*D_ + col0 + dt*16 + l15] = f2b(acc[dt][r]*dinv[r]);
    }
}

// ---------------------------------------------------------------- local windowed attention
// Swapped QK, no online rescale, QT=2. 1-D grid with XCD-aware decode: all 32 q-blocks of a
// given (head,batch) land on one XCD -> its 2MB K/V slice stays L2-resident (T1).
__launch_bounds__(256)
__global__ void local_attn_kernel(const unsigned short* __restrict__ Qb, const unsigned short* __restrict__ Kb,
                                  const unsigned short* __restrict__ Vt, unsigned short* __restrict__ attnb){
  int tid = threadIdx.x, lane = tid & 63, wv = tid >> 6;
  int wg = blockIdx.x;
  int xcd = wg & 7, k = wg >> 3;
  int pair = xcd*2 + (k >> 5);
  int bx = k & 31;
  int hl = pair & 7, b = pair >> 3;
  int w = bx >> 1;
  int col0 = (GH_ + hl)*64;
  int q0 = bx*128 + wv*32;
  int l15 = lane & 15, p4 = lane >> 4, kk = p4*8;
  int sA = ((l15 >> 2) << 3) + (l15 & 3);
  const unsigned short* Kbase = Kb + (size_t)b*N_*QLD_ + col0;
  const unsigned short* Vrow  = Vt + (size_t)(b*H_ + GH_ + hl)*64*N_;
  short8 qa[2][2];
  #pragma unroll
  for (int qt = 0; qt < 2; ++qt)
    #pragma unroll
    for (int ks = 0; ks < 2; ++ks){
      short8 v = *(const short8*)&Qb[((size_t)b*N_ + q0 + qt*16 + l15)*QLD_ + col0 + ks*32 + kk];
      #pragma unroll
      for (int j = 0; j < 8; ++j) v[j] = (short)f2b(b2f((unsigned short)v[j])*0.125f);
      qa[qt][ks] = v;
    }
  float l_part[2] = {0.f, 0.f};
  float4_ accv[2][4];
  #pragma unroll
  for (int qt = 0; qt < 2; ++qt)
    #pragma unroll
    for (int dt = 0; dt < 4; ++dt){ accv[qt][dt][0]=accv[qt][dt][1]=accv[qt][dt][2]=accv[qt][dt][3]=0.f; }
  int wlo = (w > 0) ? w - 1 : 0;
  int whi = (w < NW_ - 1) ? w + 1 : NW_ - 1;
  for (int wi = wlo; wi <= whi; ++wi){
    #pragma unroll
    for (int c = 0; c < 4; ++c){
      int key0 = wi*W_ + c*64;
      const unsigned short* Kc = Kbase + (size_t)key0*QLD_;
      float4_ s[2][4];
      #pragma unroll
      for (int qt = 0; qt < 2; ++qt)
        #pragma unroll
        for (int kt = 0; kt < 4; ++kt){ s[qt][kt][0]=s[qt][kt][1]=s[qt][kt][2]=s[qt][kt][3]=0.f; }
      #pragma unroll
      for (int ks = 0; ks < 2; ++ks){
        short8 kb0 = *(const short8*)&Kc[(size_t)(sA +  0)*QLD_ + ks*32 + kk];
        short8 kb1 = *(const short8*)&Kc[(size_t)(sA +  4)*QLD_ + ks*32 + kk];
        short8 kb2 = *(const short8*)&Kc[(size_t)(sA + 32)*QLD_ + ks*32 + kk];
        short8 kb3 = *(const short8*)&Kc[(size_t)(sA + 36)*QLD_ + ks*32 + kk];
        #pragma unroll
        for (int qt = 0; qt < 2; ++qt){
          s[qt][0] = __builtin_amdgcn_mfma_f32_16x16x32_bf16(kb0, qa[qt][ks], s[qt][0], 0, 0, 0);
          s[qt][1] = __builtin_amdgcn_mfma_f32_16x16x32_bf16(kb1, qa[qt][ks], s[qt][1], 0, 0, 0);
          s[qt][2] = __builtin_amdgcn_mfma_f32_16x16x32_bf16(kb2, qa[qt][ks], s[qt][2], 0, 0, 0);
          s[qt][3] = __builtin_amdgcn_mfma_f32_16x16x32_bf16(kb3, qa[qt][ks], s[qt][3], 0, 0, 0);
        }
      }
      short8 af[2][2];
      #pragma unroll
      for (int qt = 0; qt < 2; ++qt){
        float p[4][4];
        float rs = 0.f;
        #pragma unroll
        for (int kt = 0; kt < 4; ++kt)
          #pragma unroll
          for (int r = 0; r < 4; ++r){
            p[kt][r] = __expf(s[qt][kt][r]);
            rs += p[kt][r];
          }
        l_part[qt] += rs;
        #pragma unroll
        for (int half = 0; half < 2; ++half){
          short8 a;
          #pragma unroll
          for (int r = 0; r < 4; ++r){
            a[r]     = (short)f2b(p[half*2 + 0][r]);
            a[r + 4] = (short)f2b(p[half*2 + 1][r]);
          }
          af[qt][half] = a;
        }
      }
      #pragma unroll
      for (int ks = 0; ks < 2; ++ks){
        short8 vb0 = *(const short8*)&Vrow[(size_t)( 0 + l15)*N_ + key0 + ks*32 + kk];
        short8 vb1 = *(const short8*)&Vrow[(size_t)(16 + l15)*N_ + key0 + ks*32 + kk];
        short8 vb2 = *(const short8*)&Vrow[(size_t)(32 + l15)*N_ + key0 + ks*32 + kk];
        short8 vb3 = *(const short8*)&Vrow[(size_t)(48 + l15)*N_ + key0 + ks*32 + kk];
        #pragma unroll
        for (int qt = 0; qt < 2; ++qt){
          accv[qt][0] = __builtin_amdgcn_mfma_f32_16x16x32_bf16(af[qt][ks], vb0, accv[qt][0], 0, 0, 0);
          accv[qt][1] = __builtin_amdgcn_mfma_f32_16x16x32_bf16(af[qt][ks], vb1, accv[qt][1], 0, 0, 0);
          accv[qt][2] = __builtin_amdgcn_mfma_f32_16x16x32_bf16(af[qt][ks], vb2, accv[qt][2], 0, 0, 0);
          accv[qt][3] = __builtin_amdgcn_mfma_f32_16x16x32_bf16(af[qt][ks], vb3, accv[qt][3], 0, 0, 0);
        }
      }
    }
  }
  #pragma unroll
  for (int qt = 0; qt < 2; ++qt){
    float lv = l_part[qt];
    lv += __shfl_xor(lv, 16, 64);
    lv += __shfl_xor(lv, 32, 64);
    float ilq[4];
    #pragma unroll
    for (int r = 0; r < 4; ++r)
      ilq[r] = 1.f/__shfl(lv, (lane & 48) | (p4*4 + r), 64);
    #pragma unroll
    for (int dt = 0; dt < 4; ++dt)
      #pragma unroll
      for (int r = 0; r < 4; ++r)
        attnb[((size_t)b*N_ + q0 + qt*16 + p4*4 + r)*D_ + col0 + dt*16 + l15] = f2b(accv[qt][dt][r]*ilq[r]);
  }
}

// ---------------------------------------------------------------- host launch
extern "C" void kernel_launch(void* const* d_in, const int* in_sizes, int n_in,
                              void* d_out, int out_size, void* d_ws, size_t ws_size,
                              hipStream_t stream){
  const float* x    = (const float*)d_in[0];
  const float* Wq   = (const float*)d_in[1];
  const float* Wk   = (const float*)d_in[2];
  const float* Wv   = (const float*)d_in[3];
  const float* Wo   = (const float*)d_in[4];
  const float* bo   = (const float*)d_in[5];
  const float* proj = (const float*)d_in[6];
  float* out = (float*)d_out;
  char* ws = (char*)d_ws;

  const size_t o_Wqt  = 0;                               // Wqt|Wkt|Wvt contiguous = fused B
  const size_t o_Wkt  = o_Wqt  + (size_t)D_*D_*2;
  const size_t o_Wvt  = o_Wkt  + (size_t)D_*D_*2;
  const size_t o_Wot  = o_Wvt  + (size_t)D_*D_*2;
  const size_t o_Xb   = o_Wot  + (size_t)D_*D_*2;        // reused as attnb
  const size_t o_QKV  = o_Xb   + (size_t)R_*D_*2;        // [R][3072]
  const size_t o_Vt   = o_QKV  + (size_t)R_*QLD_*2;
  const size_t o_phikT= o_Vt   + (size_t)B_*H_*DH_*N_*2;
  const size_t o_ctxp = o_phikT+ (size_t)B_*GH_*N_*M_*2;
  const size_t o_ksum = o_ctxp + (size_t)16*B_*GH_*M_*DH_*4;
  const size_t o_vcol = o_ksum + (size_t)B_*GH_*M_*4;
  const size_t o_ctxT = o_vcol + (size_t)B_*GH_*DH_*4;
  const size_t o_projb= o_ctxT + (size_t)B_*GH_*DH_*M_*2;
  const size_t o_stab = o_projb+ (size_t)M_*DH_*2;

  unsigned short* Wqt  = (unsigned short*)(ws + o_Wqt);
  unsigned short* Wkt  = (unsigned short*)(ws + o_Wkt);
  unsigned short* Wvt  = (unsigned short*)(ws + o_Wvt);
  unsigned short* Wot  = (unsigned short*)(ws + o_Wot);
  unsigned short* Xb   = (unsigned short*)(ws + o_Xb);
  unsigned short* attnb= Xb;
  unsigned short* QKV  = (unsigned short*)(ws + o_QKV);
  unsigned short* Vt   = (unsigned short*)(ws + o_Vt);
  unsigned short* phikT= (unsigned short*)(ws + o_phikT);
  float*          ctxp = (float*)(ws + o_ctxp);
  float*          ksum = (float*)(ws + o_ksum);
  float*          vcol = (float*)(ws + o_vcol);
  unsigned short* ctxT = (unsigned short*)(ws + o_ctxT);
  unsigned short* projb= (unsigned short*)(ws + o_projb);
  unsigned int*   stab = (unsigned int*)(ws + o_stab);

  (void)in_sizes; (void)n_in; (void)out_size; (void)ws_size;

  // zero ksum + vcol (contiguous)
  (void)hipMemsetAsync(ws + o_ksum, 0, (size_t)B_*GH_*M_*4 + (size_t)B_*GH_*DH_*4, stream);
  cast_f32_bf16<<<R_*D_/8/256, 256, 0, stream>>>(x, Xb, R_*D_/8);
  cast_proj<<<64, 256, 0, stream>>>(proj, projb, stab);
  transpose_w<<<dim3(16,16,4), 256, 0, stream>>>(Wq, Wk, Wv, Wo, Wqt, Wkt, Wvt, Wot);

  // fused QKV projection: C[row][3072] = Xb @ [Wqt|Wkt|Wvt]^T
  gemm_bf16<0><<<dim3(64,24), 256, 0, stream>>>(Xb, Wqt, QKV, nullptr, nullptr, D_, QLD_);

  transpose_v<<<dim3(64,16,2), 256, 0, stream>>>(QKV + 2048, Vt, vcol);

  phik_finish<<<dim3(64,8,2), 256, 0, stream>>>(QKV + 1024, projb, phikT, ksum, stab);

  ctx_kernel<<<dim3(16,8,2), 256, 0, stream>>>(phikT, Vt, ctxp);
  ctx_reduce<<<dim3(16,16), 256, 0, stream>>>(ctxp, vcol, stab, ctxT);
  phiq_outg<<<dim3(64,8,2), 256, 0, stream>>>(QKV, projb, ctxT, ksum, stab, attnb);
  local_attn_kernel<<<512, 256, 0, stream>>>(QKV, QKV + 1024, Vt, attnb);

  gemm_bf16<1><<<dim3(64,8), 256, 0, stream>>>(attnb, Wot, nullptr, out, bo, D_, D_);
}

// Round 12
// 286.323 us; speedup vs baseline: 1.1126x; 1.0396x over previous
//
#include <hip/hip_runtime.h>
#include <hip/hip_bf16.h>

#define B_ 2
#define N_ 4096
#define D_ 1024
#define QLD_ 3072
#define H_ 16
#define GH_ 8
#define DH_ 64
#define M_ 256
#define W_ 256
#define NW_ 16
#define EPS_ 1e-4f
#define RATIO_ 0.0625f
#define R_ (B_*N_)

typedef __attribute__((ext_vector_type(8))) short short8;
typedef __attribute__((ext_vector_type(4))) short short4_;
typedef __attribute__((ext_vector_type(4))) float float4_;

__device__ __forceinline__ float b2f(unsigned short u){
  union { unsigned int i; float f; } x; x.i = ((unsigned int)u) << 16; return x.f;
}
__device__ __forceinline__ unsigned short f2b(float f){
  unsigned int u = __float_as_uint(f);
  u = u + 0x7FFFu + ((u >> 16) & 1u);
  return (unsigned short)(u >> 16);
}
__device__ __forceinline__ unsigned int encf(float x){
  unsigned int u = __float_as_uint(x);
  return (u & 0x80000000u) ? ~u : (u | 0x80000000u);
}
__device__ __forceinline__ float decf(unsigned int e){
  unsigned int u = (e & 0x80000000u) ? (e ^ 0x80000000u) : ~e;
  return __uint_as_float(u);
}
__device__ __forceinline__ void gl_lds16(const unsigned short* g, unsigned short* l){
  __builtin_amdgcn_global_load_lds((const __attribute__((address_space(1))) unsigned int*)g,
                                   (__attribute__((address_space(3))) unsigned int*)l, 16, 0, 0);
}

// ---------------------------------------------------------------- cast x (+ proj cast + stab init fused)
__global__ void cast_f32_bf16(const float* __restrict__ src, unsigned short* __restrict__ dst,
                              const float* __restrict__ proj, unsigned short* __restrict__ projb,
                              unsigned int* __restrict__ stab_enc, int n8){
  int i = blockIdx.x*256 + threadIdx.x;
  if (i == 0) *stab_enc = encf(-3.0e38f);
  if (i < M_*DH_) projb[i] = f2b(proj[i]*0.35355339059327373f);
  if (i >= n8) return;
  const float4_* sp = (const float4_*)src + (size_t)i*2;
  float4_ a = sp[0], b = sp[1];
  short8 o;
  o[0]=(short)f2b(a[0]); o[1]=(short)f2b(a[1]); o[2]=(short)f2b(a[2]); o[3]=(short)f2b(a[3]);
  o[4]=(short)f2b(b[0]); o[5]=(short)f2b(b[1]); o[6]=(short)f2b(b[2]); o[7]=(short)f2b(b[3]);
  *((short8*)dst + i) = o;
}

__global__ void transpose_w(const float* w0, const float* w1, const float* w2, const float* w3,
                            unsigned short* t0, unsigned short* t1, unsigned short* t2, unsigned short* t3){
  const float* src; unsigned short* dst;
  switch (blockIdx.z){
    case 0: src = w0; dst = t0; break;
    case 1: src = w1; dst = t1; break;
    case 2: src = w2; dst = t2; break;
    default: src = w3; dst = t3; break;
  }
  __shared__ float tile[64][65];
  int r0 = blockIdx.x*64, c0 = blockIdx.y*64;
  for (int it = 0; it < 16; ++it){
    int idx = it*256 + threadIdx.x;
    int r = idx >> 6, c = idx & 63;
    tile[r][c] = src[(size_t)(r0 + r)*D_ + c0 + c];
  }
  __syncthreads();
  for (int it = 0; it < 16; ++it){
    int idx = it*256 + threadIdx.x;
    int r = idx >> 6, c = idx & 63;
    dst[(size_t)(c0 + r)*D_ + r0 + c] = f2b(tile[c][r]);
  }
}

// QKV[b][n][2048+col] (V cols) -> Vt[b*H+h][d][n]; also vcol[bh][d] = sum_n V for global heads
__global__ void transpose_v(const unsigned short* __restrict__ Vb, unsigned short* __restrict__ Vt,
                            float* __restrict__ vcol){
  __shared__ unsigned short tile[64*72];
  int nt = blockIdx.x, h = blockIdx.y, b = blockIdx.z;
  int n0 = nt*64, col0 = h*64;
  int tid = threadIdx.x;
  int r = tid >> 2, c16 = (tid & 3)*16;
  #pragma unroll
  for (int g = 0; g < 2; ++g){
    short8 v = *(const short8*)&Vb[((size_t)b*N_ + n0 + r)*QLD_ + col0 + c16 + g*8];
    #pragma unroll
    for (int e = 0; e < 8; ++e) tile[r*72 + c16 + g*8 + e] = (unsigned short)v[e];
  }
  __syncthreads();
  if (h < GH_){
    int c = tid & 63, g = tid >> 6;
    float s = 0.f;
    #pragma unroll
    for (int i = 0; i < 16; ++i) s += b2f(tile[(g*16 + i)*72 + c]);
    atomicAdd(&vcol[(b*GH_ + h)*64 + c], s);
  }
  int d = tid >> 2, ng = (tid & 3)*16;
  short8 o0, o1;
  #pragma unroll
  for (int e = 0; e < 8; ++e){ o0[e] = (short)tile[(ng + e)*72 + d]; o1[e] = (short)tile[(ng + 8 + e)*72 + d]; }
  size_t ob = ((size_t)(b*H_ + h)*64 + d)*N_ + n0 + ng;
  *(short8*)&Vt[ob] = o0;
  *(short8*)&Vt[ob + 8] = o1;
}

// ---------------------------------------------------------------- GEMM, m97 structure, BK=64 as two
// PROVEN R10-style 32-K sub-tiles (identical 4-chunk swizzle + read math), one barrier pair per 64-K.
template<int FINAL>
__launch_bounds__(256)
__global__ void gemm_bf16(const unsigned short* __restrict__ A, const unsigned short* __restrict__ Bt,
                          unsigned short* __restrict__ Cb, float* __restrict__ Cf,
                          const float* __restrict__ bias, int K, int Ncols){
  __shared__ __attribute__((aligned(16))) unsigned short As0[128*32];
  __shared__ __attribute__((aligned(16))) unsigned short Bs0[128*32];
  __shared__ __attribute__((aligned(16))) unsigned short As1[128*32];
  __shared__ __attribute__((aligned(16))) unsigned short Bs1[128*32];
  int tid = threadIdx.x, lane = tid & 63, wave = tid >> 6;
  int bm = blockIdx.x*128, bn = blockIdx.y*128;
  int wm = (wave >> 1)*64, wn = (wave & 1)*64;
  float4_ acc[4][4];
  #pragma unroll
  for (int i = 0; i < 4; ++i)
    #pragma unroll
    for (int j = 0; j < 4; ++j)
      #pragma unroll
      for (int r = 0; r < 4; ++r) acc[i][j][r] = 0.f;
  int srow = tid >> 2, c = tid & 3;
  int scol = (c ^ ((srow >> 1) & 3))*8;
  const unsigned short* a0 = &A[(size_t)(bm + srow)*K + scol];
  const unsigned short* a1 = &A[(size_t)(bm + 64 + srow)*K + scol];
  const unsigned short* b0 = &Bt[(size_t)(bn + srow)*K + scol];
  const unsigned short* b1 = &Bt[(size_t)(bn + 64 + srow)*K + scol];
  int p4 = lane >> 4, l15 = lane & 15;
  for (int k0 = 0; k0 < K; k0 += 64){
    gl_lds16(a0,      &As0[tid*8]);
    gl_lds16(a1,      &As0[2048 + tid*8]);
    gl_lds16(b0,      &Bs0[tid*8]);
    gl_lds16(b1,      &Bs0[2048 + tid*8]);
    gl_lds16(a0 + 32, &As1[tid*8]);
    gl_lds16(a1 + 32, &As1[2048 + tid*8]);
    gl_lds16(b0 + 32, &Bs1[tid*8]);
    gl_lds16(b1 + 32, &Bs1[2048 + tid*8]);
    a0 += 64; a1 += 64; b0 += 64; b1 += 64;
    __syncthreads();
    short8 af[4], bf[4];
    #pragma unroll
    for (int i = 0; i < 4; ++i){
      int row = wm + i*16 + l15;
      af[i] = *(const short8*)&As0[row*32 + (p4 ^ ((row >> 1) & 3))*8];
    }
    #pragma unroll
    for (int j = 0; j < 4; ++j){
      int row = wn + j*16 + l15;
      bf[j] = *(const short8*)&Bs0[row*32 + (p4 ^ ((row >> 1) & 3))*8];
    }
    #pragma unroll
    for (int i = 0; i < 4; ++i)
      #pragma unroll
      for (int j = 0; j < 4; ++j)
        acc[i][j] = __builtin_amdgcn_mfma_f32_16x16x32_bf16(af[i], bf[j], acc[i][j], 0, 0, 0);
    #pragma unroll
    for (int i = 0; i < 4; ++i){
      int row = wm + i*16 + l15;
      af[i] = *(const short8*)&As1[row*32 + (p4 ^ ((row >> 1) & 3))*8];
    }
    #pragma unroll
    for (int j = 0; j < 4; ++j){
      int row = wn + j*16 + l15;
      bf[j] = *(const short8*)&Bs1[row*32 + (p4 ^ ((row >> 1) & 3))*8];
    }
    #pragma unroll
    for (int i = 0; i < 4; ++i)
      #pragma unroll
      for (int j = 0; j < 4; ++j)
        acc[i][j] = __builtin_amdgcn_mfma_f32_16x16x32_bf16(af[i], bf[j], acc[i][j], 0, 0, 0);
    __syncthreads();
  }
  int rr = p4*4, cc = l15;
  #pragma unroll
  for (int i = 0; i < 4; ++i)
    #pragma unroll
    for (int j = 0; j < 4; ++j)
      #pragma unroll
      for (int r = 0; r < 4; ++r){
        size_t row = bm + wm + i*16 + rr + r;
        int col = bn + wn + j*16 + cc;
        if (FINAL) Cf[row*(size_t)Ncols + col] = acc[i][j][r] + bias[col];
        else       Cb[row*(size_t)Ncols + col] = f2b(acc[i][j][r]);
      }
}

// ---------------------------------------------------------------- phi-K single pass (stab-deferred):
// u = exp(dd - diag); track max(dd) -> atomicMax(stab); write uT tiles + raw ksum_u
__launch_bounds__(256)
__global__ void phik_finish(const unsigned short* __restrict__ Kb, const unsigned short* __restrict__ projb,
                            unsigned short* __restrict__ phikT, float* __restrict__ ksum,
                            unsigned int* __restrict__ stab_enc){
  __shared__ __attribute__((aligned(16))) unsigned short pl[256*64];
  int tid = threadIdx.x, lane = tid & 63, wave = tid >> 6;
  int h = blockIdx.y, b = blockIdx.z, nb = blockIdx.x;
  int n0 = nb*64;
  int col0 = h*64;
  int kk = (lane >> 4)*8, l15 = lane & 15;
  int bh = b*GH_ + h;
  size_t rowbase = (size_t)b*N_ + n0 + wave*16;
  short8 qa[2];
  #pragma unroll
  for (int ks = 0; ks < 2; ++ks)
    qa[ks] = *(const short8*)&Kb[(rowbase + l15)*QLD_ + col0 + ks*32 + kk];
  float s = 0.f;
  #pragma unroll
  for (int ks = 0; ks < 2; ++ks)
    #pragma unroll
    for (int j = 0; j < 8; ++j){ float q = b2f((unsigned short)qa[ks][j]); s += q*q; }
  s += __shfl_xor(s, 16, 64);
  s += __shfl_xor(s, 32, 64);
  s *= 0.0625f;
  float dg[4];
  #pragma unroll
  for (int r = 0; r < 4; ++r) dg[r] = __shfl(s, (lane & 48) | ((lane >> 4)*4 + r), 64);
  float mxall = -3e38f;
  #pragma unroll
  for (int mt = 0; mt < 16; ++mt){
    float4_ a; a[0]=a[1]=a[2]=a[3]=0.f;
    #pragma unroll
    for (int ks = 0; ks < 2; ++ks){
      short8 bfr = *(const short8*)&projb[(size_t)(mt*16 + l15)*DH_ + ks*32 + kk];
      a = __builtin_amdgcn_mfma_f32_16x16x32_bf16(qa[ks], bfr, a, 0, 0, 0);
    }
    int m = mt*16 + l15;
    #pragma unroll
    for (int r = 0; r < 4; ++r){
      float ddv = a[r];
      mxall = fmaxf(mxall, ddv);
      float v = __expf(ddv - dg[r]);     // u, stab applied analytically later
      int n = wave*16 + (lane>>4)*4 + r;
      int slot = (n >> 3) ^ (m & 7);
      pl[m*64 + slot*8 + (n & 7)] = f2b(v);
    }
  }
  #pragma unroll
  for (int mm = 1; mm < 64; mm <<= 1) mxall = fmaxf(mxall, __shfl_xor(mxall, mm, 64));
  if (lane == 0) atomicMax(stab_enc, encf(mxall));
  __syncthreads();
  int m = tid;
  float ssum = 0.f;
  size_t outbase = (((size_t)bh*64 + nb)*256 + m)*64;
  #pragma unroll
  for (int j = 0; j < 8; ++j){
    int slot = j ^ (m & 7);
    short8 v = *(const short8*)&pl[m*64 + slot*8];
    #pragma unroll
    for (int e = 0; e < 8; ++e) ssum += b2f((unsigned short)v[e]);
    *(short8*)&phikT[outbase + j*8] = v;
  }
  atomicAdd(&ksum[bh*M_ + m], ssum);
}

// ---------------------------------------------------------------- ctx partials: C[m][d] += uT-chunk @ Vt-chunk
__launch_bounds__(256)
__global__ void ctx_kernel(const unsigned short* __restrict__ phikT, const unsigned short* __restrict__ Vt,
                           float* __restrict__ ctxp){
  int tid = threadIdx.x, lane = tid & 63, wave = tid >> 6;
  int split = blockIdx.x, h = blockIdx.y, b = blockIdx.z;
  int bh = b*GH_ + h;
  int kk = (lane >> 4)*8, l15 = lane & 15;
  float4_ acc[4][4];
  #pragma unroll
  for (int i = 0; i < 4; ++i)
    #pragma unroll
    for (int j = 0; j < 4; ++j)
      #pragma unroll
      for (int r = 0; r < 4; ++r) acc[i][j][r] = 0.f;
  const unsigned short* Abase = phikT + (size_t)bh*64*256*64;
  const unsigned short* Bbase = Vt + (size_t)(b*H_ + h)*64*N_;
  int n0 = split*256;
  #pragma unroll
  for (int ks = 0; ks < 8; ++ks){
    int n = n0 + ks*32;
    int nb = n >> 6, in0 = n & 32;
    short8 af[4], bf[4];
    #pragma unroll
    for (int mt = 0; mt < 4; ++mt)
      af[mt] = *(const short8*)&Abase[((size_t)nb*256 + wave*64 + mt*16 + l15)*64 + in0 + kk];
    #pragma unroll
    for (int dt = 0; dt < 4; ++dt)
      bf[dt] = *(const short8*)&Bbase[(size_t)(dt*16 + l15)*N_ + n + kk];
    #pragma unroll
    for (int mt = 0; mt < 4; ++mt)
      #pragma unroll
      for (int dt = 0; dt < 4; ++dt)
        acc[mt][dt] = __builtin_amdgcn_mfma_f32_16x16x32_bf16(af[mt], bf[dt], acc[mt][dt], 0, 0, 0);
  }
  int rr = (lane >> 4)*4;
  float* obase = ctxp + (((size_t)split*16 + bh)*256)*64;
  #pragma unroll
  for (int mt = 0; mt < 4; ++mt)
    #pragma unroll
    for (int dt = 0; dt < 4; ++dt)
      #pragma unroll
      for (int r = 0; r < 4; ++r)
        obase[(size_t)(wave*64 + mt*16 + rr + r)*64 + dt*16 + l15] = acc[mt][dt][r];
}

// reduce 16 splits, apply ratio*e^{-stab} scale + ratio*eps*vcol -> ctxbT[bh][d][m] bf16
__launch_bounds__(256)
__global__ void ctx_reduce(const float* __restrict__ ctxp, const float* __restrict__ vcol,
                           const unsigned int* __restrict__ stab_enc, unsigned short* __restrict__ ctxbT){
  __shared__ float tile[16*65];
  int mt = blockIdx.x, bh = blockIdx.y;
  int tid = threadIdx.x;
  float es = RATIO_*__expf(-decf(*stab_enc));
  float epsr = RATIO_*EPS_;
  int ml = tid >> 4, d4 = (tid & 15)*4;
  const float* base = ctxp + ((size_t)bh*256 + mt*16 + ml)*64 + d4;
  float4_ acc; acc[0]=acc[1]=acc[2]=acc[3]=0.f;
  #pragma unroll
  for (int sp = 0; sp < 16; ++sp){
    float4_ v = *(const float4_*)(base + (size_t)sp*16*256*64);
    acc[0] += v[0]; acc[1] += v[1]; acc[2] += v[2]; acc[3] += v[3];
  }
  #pragma unroll
  for (int e = 0; e < 4; ++e) acc[e] = es*acc[e] + epsr*vcol[bh*64 + d4 + e];
  *(float4_*)&tile[ml*65 + d4] = acc;
  __syncthreads();
  int d = tid >> 2, mg = (tid & 3)*4;
  short4_ o;
  #pragma unroll
  for (int e = 0; e < 4; ++e) o[e] = (short)f2b(tile[(mg + e)*65 + d]);
  *(short4_*)&ctxbT[((size_t)bh*64 + d)*256 + mt*16 + mg] = o;
}

// ---------------------------------------------------------------- fused phi-Q + out_g
__launch_bounds__(256)
__global__ void phiq_outg(const unsigned short* __restrict__ Qb, const unsigned short* __restrict__ projb,
                          const unsigned short* __restrict__ ctxbT, const float* __restrict__ ksum_u,
                          const unsigned int* __restrict__ stab_enc, unsigned short* __restrict__ attnb){
  __shared__ __attribute__((aligned(16))) unsigned short pl[4][16*256];
  __shared__ float ks_l[256];
  int tid = threadIdx.x, lane = tid & 63, wave = tid >> 6;
  int h = blockIdx.y, b = blockIdx.z;
  int n0 = blockIdx.x*64;
  int col0 = h*64;
  int bh = b*GH_ + h;
  int p4 = lane >> 4, l15 = lane & 15, kk = p4*8;
  {
    float es = __expf(-decf(*stab_enc));
    ks_l[tid] = RATIO_*(es*ksum_u[bh*M_ + tid] + EPS_*(float)N_);
  }
  __syncthreads();
  size_t rowbase = (size_t)b*N_ + n0 + wave*16;
  short8 qa[2];
  #pragma unroll
  for (int ks = 0; ks < 2; ++ks)
    qa[ks] = *(const short8*)&Qb[(rowbase + l15)*QLD_ + col0 + ks*32 + kk];
  float s = 0.f;
  #pragma unroll
  for (int ks = 0; ks < 2; ++ks)
    #pragma unroll
    for (int j = 0; j < 8; ++j){ float q = b2f((unsigned short)qa[ks][j]); s += q*q; }
  s += __shfl_xor(s, 16, 64);
  s += __shfl_xor(s, 32, 64);
  s *= 0.0625f;
  float dg[4];
  #pragma unroll
  for (int r = 0; r < 4; ++r) dg[r] = __shfl(s, (lane & 48) | (p4*4 + r), 64);
  float4_ dd[16];
  #pragma unroll
  for (int mt = 0; mt < 16; ++mt){
    float4_ a; a[0]=a[1]=a[2]=a[3]=0.f;
    #pragma unroll
    for (int ks = 0; ks < 2; ++ks){
      short8 bfr = *(const short8*)&projb[(size_t)(mt*16 + l15)*DH_ + ks*32 + kk];
      a = __builtin_amdgcn_mfma_f32_16x16x32_bf16(qa[ks], bfr, a, 0, 0, 0);
    }
    dd[mt] = a;
  }
  unsigned short* plw = &pl[wave][0];
  float dinv[4];
  #pragma unroll
  for (int r = 0; r < 4; ++r){
    float mx = dd[0][r];
    #pragma unroll
    for (int mt = 1; mt < 16; ++mt) mx = fmaxf(mx, dd[mt][r]);
    mx = fmaxf(mx, __shfl_xor(mx, 1, 64));
    mx = fmaxf(mx, __shfl_xor(mx, 2, 64));
    mx = fmaxf(mx, __shfl_xor(mx, 4, 64));
    mx = fmaxf(mx, __shfl_xor(mx, 8, 64));
    float sb = mx + dg[r];
    int row = p4*4 + r;
    float dpr = 0.f;
    #pragma unroll
    for (int mt = 0; mt < 16; ++mt){
      float v = RATIO_*(__expf(dd[mt][r] - sb) + EPS_);
      dpr += v*ks_l[mt*16 + l15];
      int q = mt*2 + (l15 >> 3);
      plw[row*256 + ((q ^ (row & 7)) << 3) + (l15 & 7)] = f2b(v);
    }
    dpr += __shfl_xor(dpr, 1, 64);
    dpr += __shfl_xor(dpr, 2, 64);
    dpr += __shfl_xor(dpr, 4, 64);
    dpr += __shfl_xor(dpr, 8, 64);
    dinv[r] = 1.f/dpr;
  }
  float4_ acc[4];
  #pragma unroll
  for (int dt = 0; dt < 4; ++dt){ acc[dt][0]=acc[dt][1]=acc[dt][2]=acc[dt][3]=0.f; }
  #pragma unroll
  for (int ks = 0; ks < 8; ++ks){
    int q = ks*4 + p4;
    short8 af = *(const short8*)&plw[l15*256 + ((q ^ (l15 & 7)) << 3)];
    #pragma unroll
    for (int dt = 0; dt < 4; ++dt){
      short8 bf = *(const short8*)&ctxbT[((size_t)bh*64 + dt*16 + l15)*M_ + ks*32 + kk];
      acc[dt] = __builtin_amdgcn_mfma_f32_16x16x32_bf16(af, bf, acc[dt], 0, 0, 0);
    }
  }
  #pragma unroll
  for (int dt = 0; dt < 4; ++dt)
    #pragma unroll
    for (int r = 0; r < 4; ++r){
      int rloc = wave*16 + p4*4 + r;
      attnb[((size_t)b*N_ + n0 + rloc)*D_ + col0 + dt*16 + l15] = f2b(acc[dt][r]*dinv[r]);
    }
}

// ---------------------------------------------------------------- local windowed attention
// Swapped QK, no online rescale, QT=2, XCD-aware decode (T1).
__launch_bounds__(256)
__global__ void local_attn_kernel(const unsigned short* __restrict__ Qb, const unsigned short* __restrict__ Kb,
                                  const unsigned short* __restrict__ Vt, unsigned short* __restrict__ attnb){
  int tid = threadIdx.x, lane = tid & 63, wv = tid >> 6;
  int wg = blockIdx.x;
  int xcd = wg & 7, k = wg >> 3;
  int pair = xcd*2 + (k >> 5);
  int bx = k & 31;
  int hl = pair & 7, b = pair >> 3;
  int w = bx >> 1;
  int col0 = (GH_ + hl)*64;
  int q0 = bx*128 + wv*32;
  int l15 = lane & 15, p4 = lane >> 4, kk = p4*8;
  int sA = ((l15 >> 2) << 3) + (l15 & 3);
  const unsigned short* Kbase = Kb + (size_t)b*N_*QLD_ + col0;
  const unsigned short* Vrow  = Vt + (size_t)(b*H_ + GH_ + hl)*64*N_;
  short8 qa[2][2];
  #pragma unroll
  for (int qt = 0; qt < 2; ++qt)
    #pragma unroll
    for (int ks = 0; ks < 2; ++ks){
      short8 v = *(const short8*)&Qb[((size_t)b*N_ + q0 + qt*16 + l15)*QLD_ + col0 + ks*32 + kk];
      #pragma unroll
      for (int j = 0; j < 8; ++j) v[j] = (short)f2b(b2f((unsigned short)v[j])*0.125f);
      qa[qt][ks] = v;
    }
  float l_part[2] = {0.f, 0.f};
  float4_ accv[2][4];
  #pragma unroll
  for (int qt = 0; qt < 2; ++qt)
    #pragma unroll
    for (int dt = 0; dt < 4; ++dt){ accv[qt][dt][0]=accv[qt][dt][1]=accv[qt][dt][2]=accv[qt][dt][3]=0.f; }
  int wlo = (w > 0) ? w - 1 : 0;
  int whi = (w < NW_ - 1) ? w + 1 : NW_ - 1;
  for (int wi = wlo; wi <= whi; ++wi){
    #pragma unroll
    for (int c = 0; c < 4; ++c){
      int key0 = wi*W_ + c*64;
      const unsigned short* Kc = Kbase + (size_t)key0*QLD_;
      float4_ s[2][4];
      #pragma unroll
      for (int qt = 0; qt < 2; ++qt)
        #pragma unroll
        for (int kt = 0; kt < 4; ++kt){ s[qt][kt][0]=s[qt][kt][1]=s[qt][kt][2]=s[qt][kt][3]=0.f; }
      #pragma unroll
      for (int ks = 0; ks < 2; ++ks){
        short8 kb0 = *(const short8*)&Kc[(size_t)(sA +  0)*QLD_ + ks*32 + kk];
        short8 kb1 = *(const short8*)&Kc[(size_t)(sA +  4)*QLD_ + ks*32 + kk];
        short8 kb2 = *(const short8*)&Kc[(size_t)(sA + 32)*QLD_ + ks*32 + kk];
        short8 kb3 = *(const short8*)&Kc[(size_t)(sA + 36)*QLD_ + ks*32 + kk];
        #pragma unroll
        for (int qt = 0; qt < 2; ++qt){
          s[qt][0] = __builtin_amdgcn_mfma_f32_16x16x32_bf16(kb0, qa[qt][ks], s[qt][0], 0, 0, 0);
          s[qt][1] = __builtin_amdgcn_mfma_f32_16x16x32_bf16(kb1, qa[qt][ks], s[qt][1], 0, 0, 0);
          s[qt][2] = __builtin_amdgcn_mfma_f32_16x16x32_bf16(kb2, qa[qt][ks], s[qt][2], 0, 0, 0);
          s[qt][3] = __builtin_amdgcn_mfma_f32_16x16x32_bf16(kb3, qa[qt][ks], s[qt][3], 0, 0, 0);
        }
      }
      short8 af[2][2];
      #pragma unroll
      for (int qt = 0; qt < 2; ++qt){
        float p[4][4];
        float rs = 0.f;
        #pragma unroll
        for (int kt = 0; kt < 4; ++kt)
          #pragma unroll
          for (int r = 0; r < 4; ++r){
            p[kt][r] = __expf(s[qt][kt][r]);
            rs += p[kt][r];
          }
        l_part[qt] += rs;
        #pragma unroll
        for (int half = 0; half < 2; ++half){
          short8 a;
          #pragma unroll
          for (int r = 0; r < 4; ++r){
            a[r]     = (short)f2b(p[half*2 + 0][r]);
            a[r + 4] = (short)f2b(p[half*2 + 1][r]);
          }
          af[qt][half] = a;
        }
      }
      #pragma unroll
      for (int ks = 0; ks < 2; ++ks){
        short8 vb0 = *(const short8*)&Vrow[(size_t)( 0 + l15)*N_ + key0 + ks*32 + kk];
        short8 vb1 = *(const short8*)&Vrow[(size_t)(16 + l15)*N_ + key0 + ks*32 + kk];
        short8 vb2 = *(const short8*)&Vrow[(size_t)(32 + l15)*N_ + key0 + ks*32 + kk];
        short8 vb3 = *(const short8*)&Vrow[(size_t)(48 + l15)*N_ + key0 + ks*32 + kk];
        #pragma unroll
        for (int qt = 0; qt < 2; ++qt){
          accv[qt][0] = __builtin_amdgcn_mfma_f32_16x16x32_bf16(af[qt][ks], vb0, accv[qt][0], 0, 0, 0);
          accv[qt][1] = __builtin_amdgcn_mfma_f32_16x16x32_bf16(af[qt][ks], vb1, accv[qt][1], 0, 0, 0);
          accv[qt][2] = __builtin_amdgcn_mfma_f32_16x16x32_bf16(af[qt][ks], vb2, accv[qt][2], 0, 0, 0);
          accv[qt][3] = __builtin_amdgcn_mfma_f32_16x16x32_bf16(af[qt][ks], vb3, accv[qt][3], 0, 0, 0);
        }
      }
    }
  }
  #pragma unroll
  for (int qt = 0; qt < 2; ++qt){
    float lv = l_part[qt];
    lv += __shfl_xor(lv, 16, 64);
    lv += __shfl_xor(lv, 32, 64);
    float ilq[4];
    #pragma unroll
    for (int r = 0; r < 4; ++r)
      ilq[r] = 1.f/__shfl(lv, (lane & 48) | (p4*4 + r), 64);
    #pragma unroll
    for (int dt = 0; dt < 4; ++dt)
      #pragma unroll
      for (int r = 0; r < 4; ++r)
        attnb[((size_t)b*N_ + q0 + qt*16 + p4*4 + r)*D_ + col0 + dt*16 + l15] = f2b(accv[qt][dt][r]*ilq[r]);
  }
}

// ---------------------------------------------------------------- host launch
extern "C" void kernel_launch(void* const* d_in, const int* in_sizes, int n_in,
                              void* d_out, int out_size, void* d_ws, size_t ws_size,
                              hipStream_t stream){
  const float* x    = (const float*)d_in[0];
  const float* Wq   = (const float*)d_in[1];
  const float* Wk   = (const float*)d_in[2];
  const float* Wv   = (const float*)d_in[3];
  const float* Wo   = (const float*)d_in[4];
  const float* bo   = (const float*)d_in[5];
  const float* proj = (const float*)d_in[6];
  float* out = (float*)d_out;
  char* ws = (char*)d_ws;

  const size_t o_Wqt  = 0;                               // Wqt|Wkt|Wvt contiguous = fused B
  const size_t o_Wkt  = o_Wqt  + (size_t)D_*D_*2;
  const size_t o_Wvt  = o_Wkt  + (size_t)D_*D_*2;
  const size_t o_Wot  = o_Wvt  + (size_t)D_*D_*2;
  const size_t o_Xb   = o_Wot  + (size_t)D_*D_*2;        // reused as attnb
  const size_t o_QKV  = o_Xb   + (size_t)R_*D_*2;        // [R][3072]
  const size_t o_Vt   = o_QKV  + (size_t)R_*QLD_*2;
  const size_t o_phikT= o_Vt   + (size_t)B_*H_*DH_*N_*2;
  const size_t o_ctxp = o_phikT+ (size_t)B_*GH_*N_*M_*2;
  const size_t o_ksum = o_ctxp + (size_t)16*B_*GH_*M_*DH_*4;
  const size_t o_vcol = o_ksum + (size_t)B_*GH_*M_*4;
  const size_t o_ctxT = o_vcol + (size_t)B_*GH_*DH_*4;
  const size_t o_projb= o_ctxT + (size_t)B_*GH_*DH_*M_*2;
  const size_t o_stab = o_projb+ (size_t)M_*DH_*2;

  unsigned short* Wqt  = (unsigned short*)(ws + o_Wqt);
  unsigned short* Wkt  = (unsigned short*)(ws + o_Wkt);
  unsigned short* Wvt  = (unsigned short*)(ws + o_Wvt);
  unsigned short* Wot  = (unsigned short*)(ws + o_Wot);
  unsigned short* Xb   = (unsigned short*)(ws + o_Xb);
  unsigned short* attnb= Xb;
  unsigned short* QKV  = (unsigned short*)(ws + o_QKV);
  unsigned short* Vt   = (unsigned short*)(ws + o_Vt);
  unsigned short* phikT= (unsigned short*)(ws + o_phikT);
  float*          ctxp = (float*)(ws + o_ctxp);
  float*          ksum = (float*)(ws + o_ksum);
  float*          vcol = (float*)(ws + o_vcol);
  unsigned short* ctxT = (unsigned short*)(ws + o_ctxT);
  unsigned short* projb= (unsigned short*)(ws + o_projb);
  unsigned int*   stab = (unsigned int*)(ws + o_stab);

  (void)in_sizes; (void)n_in; (void)out_size; (void)ws_size;

  // zero ksum + vcol (contiguous)
  (void)hipMemsetAsync(ws + o_ksum, 0, (size_t)B_*GH_*M_*4 + (size_t)B_*GH_*DH_*4, stream);
  cast_f32_bf16<<<R_*D_/8/256, 256, 0, stream>>>(x, Xb, proj, projb, stab, R_*D_/8);
  transpose_w<<<dim3(16,16,4), 256, 0, stream>>>(Wq, Wk, Wv, Wo, Wqt, Wkt, Wvt, Wot);

  // fused QKV projection: C[row][3072] = Xb @ [Wqt|Wkt|Wvt]^T
  gemm_bf16<0><<<dim3(64,24), 256, 0, stream>>>(Xb, Wqt, QKV, nullptr, nullptr, D_, QLD_);

  transpose_v<<<dim3(64,16,2), 256, 0, stream>>>(QKV + 2048, Vt, vcol);

  phik_finish<<<dim3(64,8,2), 256, 0, stream>>>(QKV + 1024, projb, phikT, ksum, stab);

  ctx_kernel<<<dim3(16,8,2), 256, 0, stream>>>(phikT, Vt, ctxp);
  ctx_reduce<<<dim3(16,16), 256, 0, stream>>>(ctxp, vcol, stab, ctxT);
  phiq_outg<<<dim3(64,8,2), 256, 0, stream>>>(QKV, projb, ctxT, ksum, stab, attnb);
  local_attn_kernel<<<512, 256, 0, stream>>>(QKV, QKV + 1024, Vt, attnb);

  gemm_bf16<1><<<dim3(64,8), 256, 0, stream>>>(attnb, Wot, nullptr, out, bo, D_, D_);
}

// Round 13
// 284.340 us; speedup vs baseline: 1.1204x; 1.0070x over previous
//
#include <hip/hip_runtime.h>
#include <hip/hip_bf16.h>

#define B_ 2
#define N_ 4096
#define D_ 1024
#define QLD_ 3072
#define H_ 16
#define GH_ 8
#define DH_ 64
#define M_ 256
#define W_ 256
#define NW_ 16
#define EPS_ 1e-4f
#define RATIO_ 0.0625f
#define R_ (B_*N_)

typedef __attribute__((ext_vector_type(8))) short short8;
typedef __attribute__((ext_vector_type(4))) short short4_;
typedef __attribute__((ext_vector_type(4))) float float4_;

__device__ __forceinline__ float b2f(unsigned short u){
  union { unsigned int i; float f; } x; x.i = ((unsigned int)u) << 16; return x.f;
}
__device__ __forceinline__ unsigned short f2b(float f){
  unsigned int u = __float_as_uint(f);
  u = u + 0x7FFFu + ((u >> 16) & 1u);
  return (unsigned short)(u >> 16);
}
__device__ __forceinline__ unsigned int encf(float x){
  unsigned int u = __float_as_uint(x);
  return (u & 0x80000000u) ? ~u : (u | 0x80000000u);
}
__device__ __forceinline__ float decf(unsigned int e){
  unsigned int u = (e & 0x80000000u) ? (e ^ 0x80000000u) : ~e;
  return __uint_as_float(u);
}
__device__ __forceinline__ void gl_lds16(const unsigned short* g, unsigned short* l){
  __builtin_amdgcn_global_load_lds((const __attribute__((address_space(1))) unsigned int*)g,
                                   (__attribute__((address_space(3))) unsigned int*)l, 16, 0, 0);
}

// ---------------------------------------------------------------- cast x (+ proj cast + stab init fused)
__global__ void cast_f32_bf16(const float* __restrict__ src, unsigned short* __restrict__ dst,
                              const float* __restrict__ proj, unsigned short* __restrict__ projb,
                              unsigned int* __restrict__ stab_enc, int n8){
  int i = blockIdx.x*256 + threadIdx.x;
  if (i == 0) *stab_enc = encf(-3.0e38f);
  if (i < M_*DH_) projb[i] = f2b(proj[i]*0.35355339059327373f);
  if (i >= n8) return;
  const float4_* sp = (const float4_*)src + (size_t)i*2;
  float4_ a = sp[0], b = sp[1];
  short8 o;
  o[0]=(short)f2b(a[0]); o[1]=(short)f2b(a[1]); o[2]=(short)f2b(a[2]); o[3]=(short)f2b(a[3]);
  o[4]=(short)f2b(b[0]); o[5]=(short)f2b(b[1]); o[6]=(short)f2b(b[2]); o[7]=(short)f2b(b[3]);
  *((short8*)dst + i) = o;
}

__global__ void transpose_w(const float* w0, const float* w1, const float* w2, const float* w3,
                            unsigned short* t0, unsigned short* t1, unsigned short* t2, unsigned short* t3){
  const float* src; unsigned short* dst;
  switch (blockIdx.z){
    case 0: src = w0; dst = t0; break;
    case 1: src = w1; dst = t1; break;
    case 2: src = w2; dst = t2; break;
    default: src = w3; dst = t3; break;
  }
  __shared__ float tile[64][65];
  int r0 = blockIdx.x*64, c0 = blockIdx.y*64;
  for (int it = 0; it < 16; ++it){
    int idx = it*256 + threadIdx.x;
    int r = idx >> 6, c = idx & 63;
    tile[r][c] = src[(size_t)(r0 + r)*D_ + c0 + c];
  }
  __syncthreads();
  for (int it = 0; it < 16; ++it){
    int idx = it*256 + threadIdx.x;
    int r = idx >> 6, c = idx & 63;
    dst[(size_t)(c0 + r)*D_ + r0 + c] = f2b(tile[c][r]);
  }
}

// QKV[b][n][2048+col] (V cols) -> Vt[b*H+h][d][n]; also vcol[bh][d] = sum_n V for global heads
__global__ void transpose_v(const unsigned short* __restrict__ Vb, unsigned short* __restrict__ Vt,
                            float* __restrict__ vcol){
  __shared__ unsigned short tile[64*72];
  int nt = blockIdx.x, h = blockIdx.y, b = blockIdx.z;
  int n0 = nt*64, col0 = h*64;
  int tid = threadIdx.x;
  int r = tid >> 2, c16 = (tid & 3)*16;
  #pragma unroll
  for (int g = 0; g < 2; ++g){
    short8 v = *(const short8*)&Vb[((size_t)b*N_ + n0 + r)*QLD_ + col0 + c16 + g*8];
    #pragma unroll
    for (int e = 0; e < 8; ++e) tile[r*72 + c16 + g*8 + e] = (unsigned short)v[e];
  }
  __syncthreads();
  if (h < GH_){
    int c = tid & 63, g = tid >> 6;
    float s = 0.f;
    #pragma unroll
    for (int i = 0; i < 16; ++i) s += b2f(tile[(g*16 + i)*72 + c]);
    atomicAdd(&vcol[(b*GH_ + h)*64 + c], s);
  }
  int d = tid >> 2, ng = (tid & 3)*16;
  short8 o0, o1;
  #pragma unroll
  for (int e = 0; e < 8; ++e){ o0[e] = (short)tile[(ng + e)*72 + d]; o1[e] = (short)tile[(ng + 8 + e)*72 + d]; }
  size_t ob = ((size_t)(b*H_ + h)*64 + d)*N_ + n0 + ng;
  *(short8*)&Vt[ob] = o0;
  *(short8*)&Vt[ob + 8] = o1;
}

// ---------------------------------------------------------------- GEMM, m97 structure, BK=64 as two
// PROVEN R10-style 32-K sub-tiles (identical 4-chunk swizzle + read math), one barrier pair per 64-K.
template<int FINAL>
__launch_bounds__(256)
__global__ void gemm_bf16(const unsigned short* __restrict__ A, const unsigned short* __restrict__ Bt,
                          unsigned short* __restrict__ Cb, float* __restrict__ Cf,
                          const float* __restrict__ bias, int K, int Ncols){
  __shared__ __attribute__((aligned(16))) unsigned short As0[128*32];
  __shared__ __attribute__((aligned(16))) unsigned short Bs0[128*32];
  __shared__ __attribute__((aligned(16))) unsigned short As1[128*32];
  __shared__ __attribute__((aligned(16))) unsigned short Bs1[128*32];
  int tid = threadIdx.x, lane = tid & 63, wave = tid >> 6;
  int bm = blockIdx.x*128, bn = blockIdx.y*128;
  int wm = (wave >> 1)*64, wn = (wave & 1)*64;
  float4_ acc[4][4];
  #pragma unroll
  for (int i = 0; i < 4; ++i)
    #pragma unroll
    for (int j = 0; j < 4; ++j)
      #pragma unroll
      for (int r = 0; r < 4; ++r) acc[i][j][r] = 0.f;
  int srow = tid >> 2, c = tid & 3;
  int scol = (c ^ ((srow >> 1) & 3))*8;
  const unsigned short* a0 = &A[(size_t)(bm + srow)*K + scol];
  const unsigned short* a1 = &A[(size_t)(bm + 64 + srow)*K + scol];
  const unsigned short* b0 = &Bt[(size_t)(bn + srow)*K + scol];
  const unsigned short* b1 = &Bt[(size_t)(bn + 64 + srow)*K + scol];
  int p4 = lane >> 4, l15 = lane & 15;
  for (int k0 = 0; k0 < K; k0 += 64){
    gl_lds16(a0,      &As0[tid*8]);
    gl_lds16(a1,      &As0[2048 + tid*8]);
    gl_lds16(b0,      &Bs0[tid*8]);
    gl_lds16(b1,      &Bs0[2048 + tid*8]);
    gl_lds16(a0 + 32, &As1[tid*8]);
    gl_lds16(a1 + 32, &As1[2048 + tid*8]);
    gl_lds16(b0 + 32, &Bs1[tid*8]);
    gl_lds16(b1 + 32, &Bs1[2048 + tid*8]);
    a0 += 64; a1 += 64; b0 += 64; b1 += 64;
    __syncthreads();
    short8 af[4], bf[4];
    #pragma unroll
    for (int i = 0; i < 4; ++i){
      int row = wm + i*16 + l15;
      af[i] = *(const short8*)&As0[row*32 + (p4 ^ ((row >> 1) & 3))*8];
    }
    #pragma unroll
    for (int j = 0; j < 4; ++j){
      int row = wn + j*16 + l15;
      bf[j] = *(const short8*)&Bs0[row*32 + (p4 ^ ((row >> 1) & 3))*8];
    }
    #pragma unroll
    for (int i = 0; i < 4; ++i)
      #pragma unroll
      for (int j = 0; j < 4; ++j)
        acc[i][j] = __builtin_amdgcn_mfma_f32_16x16x32_bf16(af[i], bf[j], acc[i][j], 0, 0, 0);
    #pragma unroll
    for (int i = 0; i < 4; ++i){
      int row = wm + i*16 + l15;
      af[i] = *(const short8*)&As1[row*32 + (p4 ^ ((row >> 1) & 3))*8];
    }
    #pragma unroll
    for (int j = 0; j < 4; ++j){
      int row = wn + j*16 + l15;
      bf[j] = *(const short8*)&Bs1[row*32 + (p4 ^ ((row >> 1) & 3))*8];
    }
    #pragma unroll
    for (int i = 0; i < 4; ++i)
      #pragma unroll
      for (int j = 0; j < 4; ++j)
        acc[i][j] = __builtin_amdgcn_mfma_f32_16x16x32_bf16(af[i], bf[j], acc[i][j], 0, 0, 0);
    __syncthreads();
  }
  int rr = p4*4, cc = l15;
  #pragma unroll
  for (int i = 0; i < 4; ++i)
    #pragma unroll
    for (int j = 0; j < 4; ++j)
      #pragma unroll
      for (int r = 0; r < 4; ++r){
        size_t row = bm + wm + i*16 + rr + r;
        int col = bn + wn + j*16 + cc;
        if (FINAL) Cf[row*(size_t)Ncols + col] = acc[i][j][r] + bias[col];
        else       Cb[row*(size_t)Ncols + col] = f2b(acc[i][j][r]);
      }
}

// ---------------------------------------------------------------- phi-K single pass (stab-deferred),
// 4-deep register prefetch pipeline on projb (ILP fix) + coalesced phikT stores.
__launch_bounds__(256)
__global__ void phik_finish(const unsigned short* __restrict__ Kb, const unsigned short* __restrict__ projb,
                            unsigned short* __restrict__ phikT, float* __restrict__ ksum,
                            unsigned int* __restrict__ stab_enc){
  __shared__ __attribute__((aligned(16))) unsigned short pl[256*64];
  int tid = threadIdx.x, lane = tid & 63, wave = tid >> 6;
  int h = blockIdx.y, b = blockIdx.z, nb = blockIdx.x;
  int n0 = nb*64;
  int col0 = h*64;
  int kk = (lane >> 4)*8, l15 = lane & 15;
  int bh = b*GH_ + h;
  size_t rowbase = (size_t)b*N_ + n0 + wave*16;
  short8 qa[2];
  #pragma unroll
  for (int ks = 0; ks < 2; ++ks)
    qa[ks] = *(const short8*)&Kb[(rowbase + l15)*QLD_ + col0 + ks*32 + kk];
  // prefetch pipeline prologue (mt = 0..3)
  short8 pf[4][2];
  #pragma unroll
  for (int i = 0; i < 4; ++i){
    pf[i][0] = *(const short8*)&projb[(size_t)(i*16 + l15)*DH_ + kk];
    pf[i][1] = *(const short8*)&projb[(size_t)(i*16 + l15)*DH_ + 32 + kk];
  }
  float s = 0.f;
  #pragma unroll
  for (int ks = 0; ks < 2; ++ks)
    #pragma unroll
    for (int j = 0; j < 8; ++j){ float q = b2f((unsigned short)qa[ks][j]); s += q*q; }
  s += __shfl_xor(s, 16, 64);
  s += __shfl_xor(s, 32, 64);
  s *= 0.0625f;
  float dg[4];
  #pragma unroll
  for (int r = 0; r < 4; ++r) dg[r] = __shfl(s, (lane & 48) | ((lane >> 4)*4 + r), 64);
  float mxall = -3e38f;
  #pragma unroll
  for (int mt = 0; mt < 16; ++mt){
    short8 c0 = pf[mt & 3][0], c1 = pf[mt & 3][1];
    if (mt < 12){
      pf[mt & 3][0] = *(const short8*)&projb[(size_t)((mt + 4)*16 + l15)*DH_ + kk];
      pf[mt & 3][1] = *(const short8*)&projb[(size_t)((mt + 4)*16 + l15)*DH_ + 32 + kk];
    }
    float4_ a; a[0]=a[1]=a[2]=a[3]=0.f;
    a = __builtin_amdgcn_mfma_f32_16x16x32_bf16(qa[0], c0, a, 0, 0, 0);
    a = __builtin_amdgcn_mfma_f32_16x16x32_bf16(qa[1], c1, a, 0, 0, 0);
    int m = mt*16 + l15;
    #pragma unroll
    for (int r = 0; r < 4; ++r){
      float ddv = a[r];
      mxall = fmaxf(mxall, ddv);
      float v = __expf(ddv - dg[r]);     // u, stab applied analytically later
      int n = wave*16 + (lane>>4)*4 + r;
      int slot = (n >> 3) ^ (m & 7);
      pl[m*64 + slot*8 + (n & 7)] = f2b(v);
    }
  }
  #pragma unroll
  for (int mm = 1; mm < 64; mm <<= 1) mxall = fmaxf(mxall, __shfl_xor(mxall, mm, 64));
  if (lane == 0) atomicMax(stab_enc, encf(mxall));
  __syncthreads();
  // ksum pass (row-per-thread, 1 atomic)
  {
    int m = tid;
    float ssum = 0.f;
    #pragma unroll
    for (int j = 0; j < 8; ++j){
      int slot = j ^ (m & 7);
      short8 v = *(const short8*)&pl[m*64 + slot*8];
      #pragma unroll
      for (int e = 0; e < 8; ++e) ssum += b2f((unsigned short)v[e]);
    }
    atomicAdd(&ksum[bh*M_ + m], ssum);
  }
  // coalesced phikT stores: store s2 -> each wave writes 1KB contiguous
  size_t outb = ((size_t)bh*64 + nb)*256*64;
  int j2 = tid & 7, mlo = tid >> 3;
  #pragma unroll
  for (int s2 = 0; s2 < 8; ++s2){
    int m2 = s2*32 + mlo;
    short8 v = *(const short8*)&pl[m2*64 + (j2 ^ (m2 & 7))*8];
    *(short8*)&phikT[outb + (size_t)m2*64 + j2*8] = v;
  }
}

// ---------------------------------------------------------------- ctx partials: C[m][d] += uT-chunk @ Vt-chunk
__launch_bounds__(256)
__global__ void ctx_kernel(const unsigned short* __restrict__ phikT, const unsigned short* __restrict__ Vt,
                           float* __restrict__ ctxp){
  int tid = threadIdx.x, lane = tid & 63, wave = tid >> 6;
  int split = blockIdx.x, h = blockIdx.y, b = blockIdx.z;
  int bh = b*GH_ + h;
  int kk = (lane >> 4)*8, l15 = lane & 15;
  float4_ acc[4][4];
  #pragma unroll
  for (int i = 0; i < 4; ++i)
    #pragma unroll
    for (int j = 0; j < 4; ++j)
      #pragma unroll
      for (int r = 0; r < 4; ++r) acc[i][j][r] = 0.f;
  const unsigned short* Abase = phikT + (size_t)bh*64*256*64;
  const unsigned short* Bbase = Vt + (size_t)(b*H_ + h)*64*N_;
  int n0 = split*256;
  #pragma unroll
  for (int ks = 0; ks < 8; ++ks){
    int n = n0 + ks*32;
    int nb = n >> 6, in0 = n & 32;
    short8 af[4], bf[4];
    #pragma unroll
    for (int mt = 0; mt < 4; ++mt)
      af[mt] = *(const short8*)&Abase[((size_t)nb*256 + wave*64 + mt*16 + l15)*64 + in0 + kk];
    #pragma unroll
    for (int dt = 0; dt < 4; ++dt)
      bf[dt] = *(const short8*)&Bbase[(size_t)(dt*16 + l15)*N_ + n + kk];
    #pragma unroll
    for (int mt = 0; mt < 4; ++mt)
      #pragma unroll
      for (int dt = 0; dt < 4; ++dt)
        acc[mt][dt] = __builtin_amdgcn_mfma_f32_16x16x32_bf16(af[mt], bf[dt], acc[mt][dt], 0, 0, 0);
  }
  int rr = (lane >> 4)*4;
  float* obase = ctxp + (((size_t)split*16 + bh)*256)*64;
  #pragma unroll
  for (int mt = 0; mt < 4; ++mt)
    #pragma unroll
    for (int dt = 0; dt < 4; ++dt)
      #pragma unroll
      for (int r = 0; r < 4; ++r)
        obase[(size_t)(wave*64 + mt*16 + rr + r)*64 + dt*16 + l15] = acc[mt][dt][r];
}

// reduce 16 splits, apply ratio*e^{-stab} scale + ratio*eps*vcol -> ctxbT[bh][d][m] bf16
__launch_bounds__(256)
__global__ void ctx_reduce(const float* __restrict__ ctxp, const float* __restrict__ vcol,
                           const unsigned int* __restrict__ stab_enc, unsigned short* __restrict__ ctxbT){
  __shared__ float tile[16*65];
  int mt = blockIdx.x, bh = blockIdx.y;
  int tid = threadIdx.x;
  float es = RATIO_*__expf(-decf(*stab_enc));
  float epsr = RATIO_*EPS_;
  int ml = tid >> 4, d4 = (tid & 15)*4;
  const float* base = ctxp + ((size_t)bh*256 + mt*16 + ml)*64 + d4;
  float4_ acc; acc[0]=acc[1]=acc[2]=acc[3]=0.f;
  #pragma unroll
  for (int sp = 0; sp < 16; ++sp){
    float4_ v = *(const float4_*)(base + (size_t)sp*16*256*64);
    acc[0] += v[0]; acc[1] += v[1]; acc[2] += v[2]; acc[3] += v[3];
  }
  #pragma unroll
  for (int e = 0; e < 4; ++e) acc[e] = es*acc[e] + epsr*vcol[bh*64 + d4 + e];
  *(float4_*)&tile[ml*65 + d4] = acc;
  __syncthreads();
  int d = tid >> 2, mg = (tid & 3)*4;
  short4_ o;
  #pragma unroll
  for (int e = 0; e < 4; ++e) o[e] = (short)f2b(tile[(mg + e)*65 + d]);
  *(short4_*)&ctxbT[((size_t)bh*64 + d)*256 + mt*16 + mg] = o;
}

// ---------------------------------------------------------------- fused phi-Q + out_g (prefetch pipeline)
__launch_bounds__(256)
__global__ void phiq_outg(const unsigned short* __restrict__ Qb, const unsigned short* __restrict__ projb,
                          const unsigned short* __restrict__ ctxbT, const float* __restrict__ ksum_u,
                          const unsigned int* __restrict__ stab_enc, unsigned short* __restrict__ attnb){
  __shared__ __attribute__((aligned(16))) unsigned short pl[4][16*256];
  __shared__ float ks_l[256];
  int tid = threadIdx.x, lane = tid & 63, wave = tid >> 6;
  int h = blockIdx.y, b = blockIdx.z;
  int n0 = blockIdx.x*64;
  int col0 = h*64;
  int bh = b*GH_ + h;
  int p4 = lane >> 4, l15 = lane & 15, kk = p4*8;
  {
    float es = __expf(-decf(*stab_enc));
    ks_l[tid] = RATIO_*(es*ksum_u[bh*M_ + tid] + EPS_*(float)N_);
  }
  __syncthreads();
  size_t rowbase = (size_t)b*N_ + n0 + wave*16;
  short8 qa[2];
  #pragma unroll
  for (int ks = 0; ks < 2; ++ks)
    qa[ks] = *(const short8*)&Qb[(rowbase + l15)*QLD_ + col0 + ks*32 + kk];
  short8 pf[4][2];
  #pragma unroll
  for (int i = 0; i < 4; ++i){
    pf[i][0] = *(const short8*)&projb[(size_t)(i*16 + l15)*DH_ + kk];
    pf[i][1] = *(const short8*)&projb[(size_t)(i*16 + l15)*DH_ + 32 + kk];
  }
  float s = 0.f;
  #pragma unroll
  for (int ks = 0; ks < 2; ++ks)
    #pragma unroll
    for (int j = 0; j < 8; ++j){ float q = b2f((unsigned short)qa[ks][j]); s += q*q; }
  s += __shfl_xor(s, 16, 64);
  s += __shfl_xor(s, 32, 64);
  s *= 0.0625f;
  float dg[4];
  #pragma unroll
  for (int r = 0; r < 4; ++r) dg[r] = __shfl(s, (lane & 48) | (p4*4 + r), 64);
  float4_ dd[16];
  #pragma unroll
  for (int mt = 0; mt < 16; ++mt){
    short8 c0 = pf[mt & 3][0], c1 = pf[mt & 3][1];
    if (mt < 12){
      pf[mt & 3][0] = *(const short8*)&projb[(size_t)((mt + 4)*16 + l15)*DH_ + kk];
      pf[mt & 3][1] = *(const short8*)&projb[(size_t)((mt + 4)*16 + l15)*DH_ + 32 + kk];
    }
    float4_ a; a[0]=a[1]=a[2]=a[3]=0.f;
    a = __builtin_amdgcn_mfma_f32_16x16x32_bf16(qa[0], c0, a, 0, 0, 0);
    a = __builtin_amdgcn_mfma_f32_16x16x32_bf16(qa[1], c1, a, 0, 0, 0);
    dd[mt] = a;
  }
  unsigned short* plw = &pl[wave][0];
  float dinv[4];
  #pragma unroll
  for (int r = 0; r < 4; ++r){
    float mx = dd[0][r];
    #pragma unroll
    for (int mt = 1; mt < 16; ++mt) mx = fmaxf(mx, dd[mt][r]);
    mx = fmaxf(mx, __shfl_xor(mx, 1, 64));
    mx = fmaxf(mx, __shfl_xor(mx, 2, 64));
    mx = fmaxf(mx, __shfl_xor(mx, 4, 64));
    mx = fmaxf(mx, __shfl_xor(mx, 8, 64));
    float sb = mx + dg[r];
    int row = p4*4 + r;
    float dpr = 0.f;
    #pragma unroll
    for (int mt = 0; mt < 16; ++mt){
      float v = RATIO_*(__expf(dd[mt][r] - sb) + EPS_);
      dpr += v*ks_l[mt*16 + l15];
      int q = mt*2 + (l15 >> 3);
      plw[row*256 + ((q ^ (row & 7)) << 3) + (l15 & 7)] = f2b(v);
    }
    dpr += __shfl_xor(dpr, 1, 64);
    dpr += __shfl_xor(dpr, 2, 64);
    dpr += __shfl_xor(dpr, 4, 64);
    dpr += __shfl_xor(dpr, 8, 64);
    dinv[r] = 1.f/dpr;
  }
  float4_ acc[4];
  #pragma unroll
  for (int dt = 0; dt < 4; ++dt){ acc[dt][0]=acc[dt][1]=acc[dt][2]=acc[dt][3]=0.f; }
  #pragma unroll
  for (int ks = 0; ks < 8; ++ks){
    int q = ks*4 + p4;
    short8 af = *(const short8*)&plw[l15*256 + ((q ^ (l15 & 7)) << 3)];
    #pragma unroll
    for (int dt = 0; dt < 4; ++dt){
      short8 bf = *(const short8*)&ctxbT[((size_t)bh*64 + dt*16 + l15)*M_ + ks*32 + kk];
      acc[dt] = __builtin_amdgcn_mfma_f32_16x16x32_bf16(af, bf, acc[dt], 0, 0, 0);
    }
  }
  #pragma unroll
  for (int dt = 0; dt < 4; ++dt)
    #pragma unroll
    for (int r = 0; r < 4; ++r){
      int rloc = wave*16 + p4*4 + r;
      attnb[((size_t)b*N_ + n0 + rloc)*D_ + col0 + dt*16 + l15] = f2b(acc[dt][r]*dinv[r]);
    }
}

// ---------------------------------------------------------------- local windowed attention
// Swapped QK, no online rescale, QT=2, XCD-aware decode (T1).
__launch_bounds__(256)
__global__ void local_attn_kernel(const unsigned short* __restrict__ Qb, const unsigned short* __restrict__ Kb,
                                  const unsigned short* __restrict__ Vt, unsigned short* __restrict__ attnb){
  int tid = threadIdx.x, lane = tid & 63, wv = tid >> 6;
  int wg = blockIdx.x;
  int xcd = wg & 7, k = wg >> 3;
  int pair = xcd*2 + (k >> 5);
  int bx = k & 31;
  int hl = pair & 7, b = pair >> 3;
  int w = bx >> 1;
  int col0 = (GH_ + hl)*64;
  int q0 = bx*128 + wv*32;
  int l15 = lane & 15, p4 = lane >> 4, kk = p4*8;
  int sA = ((l15 >> 2) << 3) + (l15 & 3);
  const unsigned short* Kbase = Kb + (size_t)b*N_*QLD_ + col0;
  const unsigned short* Vrow  = Vt + (size_t)(b*H_ + GH_ + hl)*64*N_;
  short8 qa[2][2];
  #pragma unroll
  for (int qt = 0; qt < 2; ++qt)
    #pragma unroll
    for (int ks = 0; ks < 2; ++ks){
      short8 v = *(const short8*)&Qb[((size_t)b*N_ + q0 + qt*16 + l15)*QLD_ + col0 + ks*32 + kk];
      #pragma unroll
      for (int j = 0; j < 8; ++j) v[j] = (short)f2b(b2f((unsigned short)v[j])*0.125f);
      qa[qt][ks] = v;
    }
  float l_part[2] = {0.f, 0.f};
  float4_ accv[2][4];
  #pragma unroll
  for (int qt = 0; qt < 2; ++qt)
    #pragma unroll
    for (int dt = 0; dt < 4; ++dt){ accv[qt][dt][0]=accv[qt][dt][1]=accv[qt][dt][2]=accv[qt][dt][3]=0.f; }
  int wlo = (w > 0) ? w - 1 : 0;
  int whi = (w < NW_ - 1) ? w + 1 : NW_ - 1;
  for (int wi = wlo; wi <= whi; ++wi){
    #pragma unroll
    for (int c = 0; c < 4; ++c){
      int key0 = wi*W_ + c*64;
      const unsigned short* Kc = Kbase + (size_t)key0*QLD_;
      float4_ s[2][4];
      #pragma unroll
      for (int qt = 0; qt < 2; ++qt)
        #pragma unroll
        for (int kt = 0; kt < 4; ++kt){ s[qt][kt][0]=s[qt][kt][1]=s[qt][kt][2]=s[qt][kt][3]=0.f; }
      #pragma unroll
      for (int ks = 0; ks < 2; ++ks){
        short8 kb0 = *(const short8*)&Kc[(size_t)(sA +  0)*QLD_ + ks*32 + kk];
        short8 kb1 = *(const short8*)&Kc[(size_t)(sA +  4)*QLD_ + ks*32 + kk];
        short8 kb2 = *(const short8*)&Kc[(size_t)(sA + 32)*QLD_ + ks*32 + kk];
        short8 kb3 = *(const short8*)&Kc[(size_t)(sA + 36)*QLD_ + ks*32 + kk];
        #pragma unroll
        for (int qt = 0; qt < 2; ++qt){
          s[qt][0] = __builtin_amdgcn_mfma_f32_16x16x32_bf16(kb0, qa[qt][ks], s[qt][0], 0, 0, 0);
          s[qt][1] = __builtin_amdgcn_mfma_f32_16x16x32_bf16(kb1, qa[qt][ks], s[qt][1], 0, 0, 0);
          s[qt][2] = __builtin_amdgcn_mfma_f32_16x16x32_bf16(kb2, qa[qt][ks], s[qt][2], 0, 0, 0);
          s[qt][3] = __builtin_amdgcn_mfma_f32_16x16x32_bf16(kb3, qa[qt][ks], s[qt][3], 0, 0, 0);
        }
      }
      short8 af[2][2];
      #pragma unroll
      for (int qt = 0; qt < 2; ++qt){
        float p[4][4];
        float rs = 0.f;
        #pragma unroll
        for (int kt = 0; kt < 4; ++kt)
          #pragma unroll
          for (int r = 0; r < 4; ++r){
            p[kt][r] = __expf(s[qt][kt][r]);
            rs += p[kt][r];
          }
        l_part[qt] += rs;
        #pragma unroll
        for (int half = 0; half < 2; ++half){
          short8 a;
          #pragma unroll
          for (int r = 0; r < 4; ++r){
            a[r]     = (short)f2b(p[half*2 + 0][r]);
            a[r + 4] = (short)f2b(p[half*2 + 1][r]);
          }
          af[qt][half] = a;
        }
      }
      #pragma unroll
      for (int ks = 0; ks < 2; ++ks){
        short8 vb0 = *(const short8*)&Vrow[(size_t)( 0 + l15)*N_ + key0 + ks*32 + kk];
        short8 vb1 = *(const short8*)&Vrow[(size_t)(16 + l15)*N_ + key0 + ks*32 + kk];
        short8 vb2 = *(const short8*)&Vrow[(size_t)(32 + l15)*N_ + key0 + ks*32 + kk];
        short8 vb3 = *(const short8*)&Vrow[(size_t)(48 + l15)*N_ + key0 + ks*32 + kk];
        #pragma unroll
        for (int qt = 0; qt < 2; ++qt){
          accv[qt][0] = __builtin_amdgcn_mfma_f32_16x16x32_bf16(af[qt][ks], vb0, accv[qt][0], 0, 0, 0);
          accv[qt][1] = __builtin_amdgcn_mfma_f32_16x16x32_bf16(af[qt][ks], vb1, accv[qt][1], 0, 0, 0);
          accv[qt][2] = __builtin_amdgcn_mfma_f32_16x16x32_bf16(af[qt][ks], vb2, accv[qt][2], 0, 0, 0);
          accv[qt][3] = __builtin_amdgcn_mfma_f32_16x16x32_bf16(af[qt][ks], vb3, accv[qt][3], 0, 0, 0);
        }
      }
    }
  }
  #pragma unroll
  for (int qt = 0; qt < 2; ++qt){
    float lv = l_part[qt];
    lv += __shfl_xor(lv, 16, 64);
    lv += __shfl_xor(lv, 32, 64);
    float ilq[4];
    #pragma unroll
    for (int r = 0; r < 4; ++r)
      ilq[r] = 1.f/__shfl(lv, (lane & 48) | (p4*4 + r), 64);
    #pragma unroll
    for (int dt = 0; dt < 4; ++dt)
      #pragma unroll
      for (int r = 0; r < 4; ++r)
        attnb[((size_t)b*N_ + q0 + qt*16 + p4*4 + r)*D_ + col0 + dt*16 + l15] = f2b(accv[qt][dt][r]*ilq[r]);
  }
}

// ---------------------------------------------------------------- host launch
extern "C" void kernel_launch(void* const* d_in, const int* in_sizes, int n_in,
                              void* d_out, int out_size, void* d_ws, size_t ws_size,
                              hipStream_t stream){
  const float* x    = (const float*)d_in[0];
  const float* Wq   = (const float*)d_in[1];
  const float* Wk   = (const float*)d_in[2];
  const float* Wv   = (const float*)d_in[3];
  const float* Wo   = (const float*)d_in[4];
  const float* bo   = (const float*)d_in[5];
  const float* proj = (const float*)d_in[6];
  float* out = (float*)d_out;
  char* ws = (char*)d_ws;

  const size_t o_Wqt  = 0;                               // Wqt|Wkt|Wvt contiguous = fused B
  const size_t o_Wkt  = o_Wqt  + (size_t)D_*D_*2;
  const size_t o_Wvt  = o_Wkt  + (size_t)D_*D_*2;
  const size_t o_Wot  = o_Wvt  + (size_t)D_*D_*2;
  const size_t o_Xb   = o_Wot  + (size_t)D_*D_*2;        // reused as attnb
  const size_t o_QKV  = o_Xb   + (size_t)R_*D_*2;        // [R][3072]
  const size_t o_Vt   = o_QKV  + (size_t)R_*QLD_*2;
  const size_t o_phikT= o_Vt   + (size_t)B_*H_*DH_*N_*2;
  const size_t o_ctxp = o_phikT+ (size_t)B_*GH_*N_*M_*2;
  const size_t o_ksum = o_ctxp + (size_t)16*B_*GH_*M_*DH_*4;
  const size_t o_vcol = o_ksum + (size_t)B_*GH_*M_*4;
  const size_t o_ctxT = o_vcol + (size_t)B_*GH_*DH_*4;
  const size_t o_projb= o_ctxT + (size_t)B_*GH_*DH_*M_*2;
  const size_t o_stab = o_projb+ (size_t)M_*DH_*2;

  unsigned short* Wqt  = (unsigned short*)(ws + o_Wqt);
  unsigned short* Wkt  = (unsigned short*)(ws + o_Wkt);
  unsigned short* Wvt  = (unsigned short*)(ws + o_Wvt);
  unsigned short* Wot  = (unsigned short*)(ws + o_Wot);
  unsigned short* Xb   = (unsigned short*)(ws + o_Xb);
  unsigned short* attnb= Xb;
  unsigned short* QKV  = (unsigned short*)(ws + o_QKV);
  unsigned short* Vt   = (unsigned short*)(ws + o_Vt);
  unsigned short* phikT= (unsigned short*)(ws + o_phikT);
  float*          ctxp = (float*)(ws + o_ctxp);
  float*          ksum = (float*)(ws + o_ksum);
  float*          vcol = (float*)(ws + o_vcol);
  unsigned short* ctxT = (unsigned short*)(ws + o_ctxT);
  unsigned short* projb= (unsigned short*)(ws + o_projb);
  unsigned int*   stab = (unsigned int*)(ws + o_stab);

  (void)in_sizes; (void)n_in; (void)out_size; (void)ws_size;

  // zero ksum + vcol (contiguous)
  (void)hipMemsetAsync(ws + o_ksum, 0, (size_t)B_*GH_*M_*4 + (size_t)B_*GH_*DH_*4, stream);
  cast_f32_bf16<<<R_*D_/8/256, 256, 0, stream>>>(x, Xb, proj, projb, stab, R_*D_/8);
  transpose_w<<<dim3(16,16,4), 256, 0, stream>>>(Wq, Wk, Wv, Wo, Wqt, Wkt, Wvt, Wot);

  // fused QKV projection: C[row][3072] = Xb @ [Wqt|Wkt|Wvt]^T
  gemm_bf16<0><<<dim3(64,24), 256, 0, stream>>>(Xb, Wqt, QKV, nullptr, nullptr, D_, QLD_);

  transpose_v<<<dim3(64,16,2), 256, 0, stream>>>(QKV + 2048, Vt, vcol);

  phik_finish<<<dim3(64,8,2), 256, 0, stream>>>(QKV + 1024, projb, phikT, ksum, stab);

  ctx_kernel<<<dim3(16,8,2), 256, 0, stream>>>(phikT, Vt, ctxp);
  ctx_reduce<<<dim3(16,16), 256, 0, stream>>>(ctxp, vcol, stab, ctxT);
  phiq_outg<<<dim3(64,8,2), 256, 0, stream>>>(QKV, projb, ctxT, ksum, stab, attnb);
  local_attn_kernel<<<512, 256, 0, stream>>>(QKV, QKV + 1024, Vt, attnb);

  gemm_bf16<1><<<dim3(64,8), 256, 0, stream>>>(attnb, Wot, nullptr, out, bo, D_, D_);
}

// Round 14
// 248.788 us; speedup vs baseline: 1.2805x; 1.1429x over previous
//
#include <hip/hip_runtime.h>
#include <hip/hip_bf16.h>

#define B_ 2
#define N_ 4096
#define D_ 1024
#define QLD_ 3072
#define H_ 16
#define GH_ 8
#define DH_ 64
#define M_ 256
#define W_ 256
#define NW_ 16
#define EPS_ 1e-4f
#define RATIO_ 0.0625f
#define R_ (B_*N_)

typedef __attribute__((ext_vector_type(8))) short short8;
typedef __attribute__((ext_vector_type(4))) short short4_;
typedef __attribute__((ext_vector_type(4))) float float4_;

__device__ __forceinline__ float b2f(unsigned short u){
  union { unsigned int i; float f; } x; x.i = ((unsigned int)u) << 16; return x.f;
}
__device__ __forceinline__ unsigned short f2b(float f){
  unsigned int u = __float_as_uint(f);
  u = u + 0x7FFFu + ((u >> 16) & 1u);
  return (unsigned short)(u >> 16);
}
__device__ __forceinline__ void gl_lds16(const unsigned short* g, unsigned short* l){
  __builtin_amdgcn_global_load_lds((const __attribute__((address_space(1))) unsigned int*)g,
                                   (__attribute__((address_space(3))) unsigned int*)l, 16, 0, 0);
}

// ---------------------------------------------------------------- cast x (+ proj cast fused)
__global__ void cast_f32_bf16(const float* __restrict__ src, unsigned short* __restrict__ dst,
                              const float* __restrict__ proj, unsigned short* __restrict__ projb,
                              int n8){
  int i = blockIdx.x*256 + threadIdx.x;
  if (i < M_*DH_) projb[i] = f2b(proj[i]*0.35355339059327373f);
  if (i >= n8) return;
  const float4_* sp = (const float4_*)src + (size_t)i*2;
  float4_ a = sp[0], b = sp[1];
  short8 o;
  o[0]=(short)f2b(a[0]); o[1]=(short)f2b(a[1]); o[2]=(short)f2b(a[2]); o[3]=(short)f2b(a[3]);
  o[4]=(short)f2b(b[0]); o[5]=(short)f2b(b[1]); o[6]=(short)f2b(b[2]); o[7]=(short)f2b(b[3]);
  *((short8*)dst + i) = o;
}

__global__ void transpose_w(const float* w0, const float* w1, const float* w2, const float* w3,
                            unsigned short* t0, unsigned short* t1, unsigned short* t2, unsigned short* t3){
  const float* src; unsigned short* dst;
  switch (blockIdx.z){
    case 0: src = w0; dst = t0; break;
    case 1: src = w1; dst = t1; break;
    case 2: src = w2; dst = t2; break;
    default: src = w3; dst = t3; break;
  }
  __shared__ float tile[64][65];
  int r0 = blockIdx.x*64, c0 = blockIdx.y*64;
  for (int it = 0; it < 16; ++it){
    int idx = it*256 + threadIdx.x;
    int r = idx >> 6, c = idx & 63;
    tile[r][c] = src[(size_t)(r0 + r)*D_ + c0 + c];
  }
  __syncthreads();
  for (int it = 0; it < 16; ++it){
    int idx = it*256 + threadIdx.x;
    int r = idx >> 6, c = idx & 63;
    dst[(size_t)(c0 + r)*D_ + r0 + c] = f2b(tile[c][r]);
  }
}

// QKV[b][n][2048+col] (V cols) -> Vt[b*H+h][d][n]; also vcol[bh][d] = sum_n V for global heads
__global__ void transpose_v(const unsigned short* __restrict__ Vb, unsigned short* __restrict__ Vt,
                            float* __restrict__ vcol){
  __shared__ unsigned short tile[64*72];
  int nt = blockIdx.x, h = blockIdx.y, b = blockIdx.z;
  int n0 = nt*64, col0 = h*64;
  int tid = threadIdx.x;
  int r = tid >> 2, c16 = (tid & 3)*16;
  #pragma unroll
  for (int g = 0; g < 2; ++g){
    short8 v = *(const short8*)&Vb[((size_t)b*N_ + n0 + r)*QLD_ + col0 + c16 + g*8];
    #pragma unroll
    for (int e = 0; e < 8; ++e) tile[r*72 + c16 + g*8 + e] = (unsigned short)v[e];
  }
  __syncthreads();
  if (h < GH_){
    int c = tid & 63, g = tid >> 6;
    float s = 0.f;
    #pragma unroll
    for (int i = 0; i < 16; ++i) s += b2f(tile[(g*16 + i)*72 + c]);
    atomicAdd(&vcol[(b*GH_ + h)*64 + c], s);
  }
  int d = tid >> 2, ng = (tid & 3)*16;
  short8 o0, o1;
  #pragma unroll
  for (int e = 0; e < 8; ++e){ o0[e] = (short)tile[(ng + e)*72 + d]; o1[e] = (short)tile[(ng + 8 + e)*72 + d]; }
  size_t ob = ((size_t)(b*H_ + h)*64 + d)*N_ + n0 + ng;
  *(short8*)&Vt[ob] = o0;
  *(short8*)&Vt[ob + 8] = o1;
}

// ---------------------------------------------------------------- GEMM, m97 structure, BK=64 as two
// PROVEN R10-style 32-K sub-tiles (identical 4-chunk swizzle + read math), one barrier pair per 64-K.
template<int FINAL>
__launch_bounds__(256)
__global__ void gemm_bf16(const unsigned short* __restrict__ A, const unsigned short* __restrict__ Bt,
                          unsigned short* __restrict__ Cb, float* __restrict__ Cf,
                          const float* __restrict__ bias, int K, int Ncols){
  __shared__ __attribute__((aligned(16))) unsigned short As0[128*32];
  __shared__ __attribute__((aligned(16))) unsigned short Bs0[128*32];
  __shared__ __attribute__((aligned(16))) unsigned short As1[128*32];
  __shared__ __attribute__((aligned(16))) unsigned short Bs1[128*32];
  int tid = threadIdx.x, lane = tid & 63, wave = tid >> 6;
  int bm = blockIdx.x*128, bn = blockIdx.y*128;
  int wm = (wave >> 1)*64, wn = (wave & 1)*64;
  float4_ acc[4][4];
  #pragma unroll
  for (int i = 0; i < 4; ++i)
    #pragma unroll
    for (int j = 0; j < 4; ++j)
      #pragma unroll
      for (int r = 0; r < 4; ++r) acc[i][j][r] = 0.f;
  int srow = tid >> 2, c = tid & 3;
  int scol = (c ^ ((srow >> 1) & 3))*8;
  const unsigned short* a0 = &A[(size_t)(bm + srow)*K + scol];
  const unsigned short* a1 = &A[(size_t)(bm + 64 + srow)*K + scol];
  const unsigned short* b0 = &Bt[(size_t)(bn + srow)*K + scol];
  const unsigned short* b1 = &Bt[(size_t)(bn + 64 + srow)*K + scol];
  int p4 = lane >> 4, l15 = lane & 15;
  for (int k0 = 0; k0 < K; k0 += 64){
    gl_lds16(a0,      &As0[tid*8]);
    gl_lds16(a1,      &As0[2048 + tid*8]);
    gl_lds16(b0,      &Bs0[tid*8]);
    gl_lds16(b1,      &Bs0[2048 + tid*8]);
    gl_lds16(a0 + 32, &As1[tid*8]);
    gl_lds16(a1 + 32, &As1[2048 + tid*8]);
    gl_lds16(b0 + 32, &Bs1[tid*8]);
    gl_lds16(b1 + 32, &Bs1[2048 + tid*8]);
    a0 += 64; a1 += 64; b0 += 64; b1 += 64;
    __syncthreads();
    short8 af[4], bf[4];
    #pragma unroll
    for (int i = 0; i < 4; ++i){
      int row = wm + i*16 + l15;
      af[i] = *(const short8*)&As0[row*32 + (p4 ^ ((row >> 1) & 3))*8];
    }
    #pragma unroll
    for (int j = 0; j < 4; ++j){
      int row = wn + j*16 + l15;
      bf[j] = *(const short8*)&Bs0[row*32 + (p4 ^ ((row >> 1) & 3))*8];
    }
    #pragma unroll
    for (int i = 0; i < 4; ++i)
      #pragma unroll
      for (int j = 0; j < 4; ++j)
        acc[i][j] = __builtin_amdgcn_mfma_f32_16x16x32_bf16(af[i], bf[j], acc[i][j], 0, 0, 0);
    #pragma unroll
    for (int i = 0; i < 4; ++i){
      int row = wm + i*16 + l15;
      af[i] = *(const short8*)&As1[row*32 + (p4 ^ ((row >> 1) & 3))*8];
    }
    #pragma unroll
    for (int j = 0; j < 4; ++j){
      int row = wn + j*16 + l15;
      bf[j] = *(const short8*)&Bs1[row*32 + (p4 ^ ((row >> 1) & 3))*8];
    }
    #pragma unroll
    for (int i = 0; i < 4; ++i)
      #pragma unroll
      for (int j = 0; j < 4; ++j)
        acc[i][j] = __builtin_amdgcn_mfma_f32_16x16x32_bf16(af[i], bf[j], acc[i][j], 0, 0, 0);
    __syncthreads();
  }
  int rr = p4*4, cc = l15;
  #pragma unroll
  for (int i = 0; i < 4; ++i)
    #pragma unroll
    for (int j = 0; j < 4; ++j)
      #pragma unroll
      for (int r = 0; r < 4; ++r){
        size_t row = bm + wm + i*16 + rr + r;
        int col = bn + wn + j*16 + cc;
        if (FINAL) Cf[row*(size_t)Ncols + col] = acc[i][j][r] + bias[col];
        else       Cb[row*(size_t)Ncols + col] = f2b(acc[i][j][r]);
      }
}

// ---------------------------------------------------------------- phi-K single pass (stab-deferred),
// prefetch pipeline + coalesced phikT stores + NO single-address atomic: block max -> blkmax[wg].
__launch_bounds__(256)
__global__ void phik_finish(const unsigned short* __restrict__ Kb, const unsigned short* __restrict__ projb,
                            unsigned short* __restrict__ phikT, float* __restrict__ ksum,
                            float* __restrict__ blkmax){
  __shared__ __attribute__((aligned(16))) unsigned short pl[256*64];
  __shared__ float sm4[4];
  int tid = threadIdx.x, lane = tid & 63, wave = tid >> 6;
  int h = blockIdx.y, b = blockIdx.z, nb = blockIdx.x;
  int n0 = nb*64;
  int col0 = h*64;
  int kk = (lane >> 4)*8, l15 = lane & 15;
  int bh = b*GH_ + h;
  size_t rowbase = (size_t)b*N_ + n0 + wave*16;
  short8 qa[2];
  #pragma unroll
  for (int ks = 0; ks < 2; ++ks)
    qa[ks] = *(const short8*)&Kb[(rowbase + l15)*QLD_ + col0 + ks*32 + kk];
  short8 pf[4][2];
  #pragma unroll
  for (int i = 0; i < 4; ++i){
    pf[i][0] = *(const short8*)&projb[(size_t)(i*16 + l15)*DH_ + kk];
    pf[i][1] = *(const short8*)&projb[(size_t)(i*16 + l15)*DH_ + 32 + kk];
  }
  float s = 0.f;
  #pragma unroll
  for (int ks = 0; ks < 2; ++ks)
    #pragma unroll
    for (int j = 0; j < 8; ++j){ float q = b2f((unsigned short)qa[ks][j]); s += q*q; }
  s += __shfl_xor(s, 16, 64);
  s += __shfl_xor(s, 32, 64);
  s *= 0.0625f;
  float dg[4];
  #pragma unroll
  for (int r = 0; r < 4; ++r) dg[r] = __shfl(s, (lane & 48) | ((lane >> 4)*4 + r), 64);
  float mxall = -3e38f;
  #pragma unroll
  for (int mt = 0; mt < 16; ++mt){
    short8 c0 = pf[mt & 3][0], c1 = pf[mt & 3][1];
    if (mt < 12){
      pf[mt & 3][0] = *(const short8*)&projb[(size_t)((mt + 4)*16 + l15)*DH_ + kk];
      pf[mt & 3][1] = *(const short8*)&projb[(size_t)((mt + 4)*16 + l15)*DH_ + 32 + kk];
    }
    float4_ a; a[0]=a[1]=a[2]=a[3]=0.f;
    a = __builtin_amdgcn_mfma_f32_16x16x32_bf16(qa[0], c0, a, 0, 0, 0);
    a = __builtin_amdgcn_mfma_f32_16x16x32_bf16(qa[1], c1, a, 0, 0, 0);
    int m = mt*16 + l15;
    #pragma unroll
    for (int r = 0; r < 4; ++r){
      float ddv = a[r];
      mxall = fmaxf(mxall, ddv);
      float v = __expf(ddv - dg[r]);     // u, stab applied analytically later
      int n = wave*16 + (lane>>4)*4 + r;
      int slot = (n >> 3) ^ (m & 7);
      pl[m*64 + slot*8 + (n & 7)] = f2b(v);
    }
  }
  #pragma unroll
  for (int mm = 1; mm < 64; mm <<= 1) mxall = fmaxf(mxall, __shfl_xor(mxall, mm, 64));
  if (lane == 0) sm4[wave] = mxall;
  __syncthreads();
  if (tid == 0)
    blkmax[((size_t)b*GH_ + h)*64 + nb] = fmaxf(fmaxf(sm4[0], sm4[1]), fmaxf(sm4[2], sm4[3]));
  // ksum pass (row-per-thread, 1 atomic across 64 blocks/addr)
  {
    int m = tid;
    float ssum = 0.f;
    #pragma unroll
    for (int j = 0; j < 8; ++j){
      int slot = j ^ (m & 7);
      short8 v = *(const short8*)&pl[m*64 + slot*8];
      #pragma unroll
      for (int e = 0; e < 8; ++e) ssum += b2f((unsigned short)v[e]);
    }
    atomicAdd(&ksum[bh*M_ + m], ssum);
  }
  // coalesced phikT stores: each wave writes 1KB contiguous per step
  size_t outb = ((size_t)bh*64 + nb)*256*64;
  int j2 = tid & 7, mlo = tid >> 3;
  #pragma unroll
  for (int s2 = 0; s2 < 8; ++s2){
    int m2 = s2*32 + mlo;
    short8 v = *(const short8*)&pl[m2*64 + (j2 ^ (m2 & 7))*8];
    *(short8*)&phikT[outb + (size_t)m2*64 + j2*8] = v;
  }
}

// ---------------------------------------------------------------- ctx partials: C[m][d] += uT-chunk @ Vt-chunk
__launch_bounds__(256)
__global__ void ctx_kernel(const unsigned short* __restrict__ phikT, const unsigned short* __restrict__ Vt,
                           float* __restrict__ ctxp){
  int tid = threadIdx.x, lane = tid & 63, wave = tid >> 6;
  int split = blockIdx.x, h = blockIdx.y, b = blockIdx.z;
  int bh = b*GH_ + h;
  int kk = (lane >> 4)*8, l15 = lane & 15;
  float4_ acc[4][4];
  #pragma unroll
  for (int i = 0; i < 4; ++i)
    #pragma unroll
    for (int j = 0; j < 4; ++j)
      #pragma unroll
      for (int r = 0; r < 4; ++r) acc[i][j][r] = 0.f;
  const unsigned short* Abase = phikT + (size_t)bh*64*256*64;
  const unsigned short* Bbase = Vt + (size_t)(b*H_ + h)*64*N_;
  int n0 = split*256;
  #pragma unroll
  for (int ks = 0; ks < 8; ++ks){
    int n = n0 + ks*32;
    int nb = n >> 6, in0 = n & 32;
    short8 af[4], bf[4];
    #pragma unroll
    for (int mt = 0; mt < 4; ++mt)
      af[mt] = *(const short8*)&Abase[((size_t)nb*256 + wave*64 + mt*16 + l15)*64 + in0 + kk];
    #pragma unroll
    for (int dt = 0; dt < 4; ++dt)
      bf[dt] = *(const short8*)&Bbase[(size_t)(dt*16 + l15)*N_ + n + kk];
    #pragma unroll
    for (int mt = 0; mt < 4; ++mt)
      #pragma unroll
      for (int dt = 0; dt < 4; ++dt)
        acc[mt][dt] = __builtin_amdgcn_mfma_f32_16x16x32_bf16(af[mt], bf[dt], acc[mt][dt], 0, 0, 0);
  }
  int rr = (lane >> 4)*4;
  float* obase = ctxp + (((size_t)split*16 + bh)*256)*64;
  #pragma unroll
  for (int mt = 0; mt < 4; ++mt)
    #pragma unroll
    for (int dt = 0; dt < 4; ++dt)
      #pragma unroll
      for (int r = 0; r < 4; ++r)
        obase[(size_t)(wave*64 + mt*16 + rr + r)*64 + dt*16 + l15] = acc[mt][dt][r];
}

// reduce 16 splits, apply ratio*e^{-stab} scale + ratio*eps*vcol -> ctxbT[bh][d][m] bf16
__launch_bounds__(256)
__global__ void ctx_reduce(const float* __restrict__ ctxp, const float* __restrict__ vcol,
                           const float* __restrict__ blkmax, unsigned short* __restrict__ ctxbT){
  __shared__ float tile[16*65];
  __shared__ float smax[4];
  int mt = blockIdx.x, bh = blockIdx.y;
  int tid = threadIdx.x, lane = tid & 63, wave = tid >> 6;
  float bm = -3e38f;
  #pragma unroll
  for (int i = 0; i < 4; ++i) bm = fmaxf(bm, blkmax[i*256 + tid]);
  #pragma unroll
  for (int mm = 1; mm < 64; mm <<= 1) bm = fmaxf(bm, __shfl_xor(bm, mm, 64));
  if (lane == 0) smax[wave] = bm;
  __syncthreads();
  float stab = fmaxf(fmaxf(smax[0], smax[1]), fmaxf(smax[2], smax[3]));
  float es = RATIO_*__expf(-stab);
  float epsr = RATIO_*EPS_;
  int ml = tid >> 4, d4 = (tid & 15)*4;
  const float* base = ctxp + ((size_t)bh*256 + mt*16 + ml)*64 + d4;
  float4_ acc; acc[0]=acc[1]=acc[2]=acc[3]=0.f;
  #pragma unroll
  for (int sp = 0; sp < 16; ++sp){
    float4_ v = *(const float4_*)(base + (size_t)sp*16*256*64);
    acc[0] += v[0]; acc[1] += v[1]; acc[2] += v[2]; acc[3] += v[3];
  }
  #pragma unroll
  for (int e = 0; e < 4; ++e) acc[e] = es*acc[e] + epsr*vcol[bh*64 + d4 + e];
  *(float4_*)&tile[ml*65 + d4] = acc;
  __syncthreads();
  int d = tid >> 2, mg = (tid & 3)*4;
  short4_ o;
  #pragma unroll
  for (int e = 0; e < 4; ++e) o[e] = (short)f2b(tile[(mg + e)*65 + d]);
  *(short4_*)&ctxbT[((size_t)bh*64 + d)*256 + mt*16 + mg] = o;
}

// ---------------------------------------------------------------- fused phi-Q + out_g (prefetch pipeline)
__launch_bounds__(256)
__global__ void phiq_outg(const unsigned short* __restrict__ Qb, const unsigned short* __restrict__ projb,
                          const unsigned short* __restrict__ ctxbT, const float* __restrict__ ksum_u,
                          const float* __restrict__ blkmax, unsigned short* __restrict__ attnb){
  __shared__ __attribute__((aligned(16))) unsigned short pl[4][16*256];
  __shared__ float ks_l[256];
  __shared__ float smax[4];
  int tid = threadIdx.x, lane = tid & 63, wave = tid >> 6;
  int h = blockIdx.y, b = blockIdx.z;
  int n0 = blockIdx.x*64;
  int col0 = h*64;
  int bh = b*GH_ + h;
  int p4 = lane >> 4, l15 = lane & 15, kk = p4*8;
  {
    float bm = -3e38f;
    #pragma unroll
    for (int i = 0; i < 4; ++i) bm = fmaxf(bm, blkmax[i*256 + tid]);
    #pragma unroll
    for (int mm = 1; mm < 64; mm <<= 1) bm = fmaxf(bm, __shfl_xor(bm, mm, 64));
    if (lane == 0) smax[wave] = bm;
  }
  __syncthreads();
  {
    float stab = fmaxf(fmaxf(smax[0], smax[1]), fmaxf(smax[2], smax[3]));
    float es = __expf(-stab);
    ks_l[tid] = RATIO_*(es*ksum_u[bh*M_ + tid] + EPS_*(float)N_);
  }
  __syncthreads();
  size_t rowbase = (size_t)b*N_ + n0 + wave*16;
  short8 qa[2];
  #pragma unroll
  for (int ks = 0; ks < 2; ++ks)
    qa[ks] = *(const short8*)&Qb[(rowbase + l15)*QLD_ + col0 + ks*32 + kk];
  short8 pf[4][2];
  #pragma unroll
  for (int i = 0; i < 4; ++i){
    pf[i][0] = *(const short8*)&projb[(size_t)(i*16 + l15)*DH_ + kk];
    pf[i][1] = *(const short8*)&projb[(size_t)(i*16 + l15)*DH_ + 32 + kk];
  }
  float s = 0.f;
  #pragma unroll
  for (int ks = 0; ks < 2; ++ks)
    #pragma unroll
    for (int j = 0; j < 8; ++j){ float q = b2f((unsigned short)qa[ks][j]); s += q*q; }
  s += __shfl_xor(s, 16, 64);
  s += __shfl_xor(s, 32, 64);
  s *= 0.0625f;
  float dg[4];
  #pragma unroll
  for (int r = 0; r < 4; ++r) dg[r] = __shfl(s, (lane & 48) | (p4*4 + r), 64);
  float4_ dd[16];
  #pragma unroll
  for (int mt = 0; mt < 16; ++mt){
    short8 c0 = pf[mt & 3][0], c1 = pf[mt & 3][1];
    if (mt < 12){
      pf[mt & 3][0] = *(const short8*)&projb[(size_t)((mt + 4)*16 + l15)*DH_ + kk];
      pf[mt & 3][1] = *(const short8*)&projb[(size_t)((mt + 4)*16 + l15)*DH_ + 32 + kk];
    }
    float4_ a; a[0]=a[1]=a[2]=a[3]=0.f;
    a = __builtin_amdgcn_mfma_f32_16x16x32_bf16(qa[0], c0, a, 0, 0, 0);
    a = __builtin_amdgcn_mfma_f32_16x16x32_bf16(qa[1], c1, a, 0, 0, 0);
    dd[mt] = a;
  }
  unsigned short* plw = &pl[wave][0];
  float dinv[4];
  #pragma unroll
  for (int r = 0; r < 4; ++r){
    float mx = dd[0][r];
    #pragma unroll
    for (int mt = 1; mt < 16; ++mt) mx = fmaxf(mx, dd[mt][r]);
    mx = fmaxf(mx, __shfl_xor(mx, 1, 64));
    mx = fmaxf(mx, __shfl_xor(mx, 2, 64));
    mx = fmaxf(mx, __shfl_xor(mx, 4, 64));
    mx = fmaxf(mx, __shfl_xor(mx, 8, 64));
    float sb = mx + dg[r];
    int row = p4*4 + r;
    float dpr = 0.f;
    #pragma unroll
    for (int mt = 0; mt < 16; ++mt){
      float v = RATIO_*(__expf(dd[mt][r] - sb) + EPS_);
      dpr += v*ks_l[mt*16 + l15];
      int q = mt*2 + (l15 >> 3);
      plw[row*256 + ((q ^ (row & 7)) << 3) + (l15 & 7)] = f2b(v);
    }
    dpr += __shfl_xor(dpr, 1, 64);
    dpr += __shfl_xor(dpr, 2, 64);
    dpr += __shfl_xor(dpr, 4, 64);
    dpr += __shfl_xor(dpr, 8, 64);
    dinv[r] = 1.f/dpr;
  }
  float4_ acc[4];
  #pragma unroll
  for (int dt = 0; dt < 4; ++dt){ acc[dt][0]=acc[dt][1]=acc[dt][2]=acc[dt][3]=0.f; }
  #pragma unroll
  for (int ks = 0; ks < 8; ++ks){
    int q = ks*4 + p4;
    short8 af = *(const short8*)&plw[l15*256 + ((q ^ (l15 & 7)) << 3)];
    #pragma unroll
    for (int dt = 0; dt < 4; ++dt){
      short8 bf = *(const short8*)&ctxbT[((size_t)bh*64 + dt*16 + l15)*M_ + ks*32 + kk];
      acc[dt] = __builtin_amdgcn_mfma_f32_16x16x32_bf16(af, bf, acc[dt], 0, 0, 0);
    }
  }
  #pragma unroll
  for (int dt = 0; dt < 4; ++dt)
    #pragma unroll
    for (int r = 0; r < 4; ++r){
      int rloc = wave*16 + p4*4 + r;
      attnb[((size_t)b*N_ + n0 + rloc)*D_ + col0 + dt*16 + l15] = f2b(acc[dt][r]*dinv[r]);
    }
}

// ---------------------------------------------------------------- local windowed attention
// Swapped QK, no online rescale, QT=2, XCD-aware decode (T1).
__launch_bounds__(256)
__global__ void local_attn_kernel(const unsigned short* __restrict__ Qb, const unsigned short* __restrict__ Kb,
                                  const unsigned short* __restrict__ Vt, unsigned short* __restrict__ attnb){
  int tid = threadIdx.x, lane = tid & 63, wv = tid >> 6;
  int wg = blockIdx.x;
  int xcd = wg & 7, k = wg >> 3;
  int pair = xcd*2 + (k >> 5);
  int bx = k & 31;
  int hl = pair & 7, b = pair >> 3;
  int w = bx >> 1;
  int col0 = (GH_ + hl)*64;
  int q0 = bx*128 + wv*32;
  int l15 = lane & 15, p4 = lane >> 4, kk = p4*8;
  int sA = ((l15 >> 2) << 3) + (l15 & 3);
  const unsigned short* Kbase = Kb + (size_t)b*N_*QLD_ + col0;
  const unsigned short* Vrow  = Vt + (size_t)(b*H_ + GH_ + hl)*64*N_;
  short8 qa[2][2];
  #pragma unroll
  for (int qt = 0; qt < 2; ++qt)
    #pragma unroll
    for (int ks = 0; ks < 2; ++ks){
      short8 v = *(const short8*)&Qb[((size_t)b*N_ + q0 + qt*16 + l15)*QLD_ + col0 + ks*32 + kk];
      #pragma unroll
      for (int j = 0; j < 8; ++j) v[j] = (short)f2b(b2f((unsigned short)v[j])*0.125f);
      qa[qt][ks] = v;
    }
  float l_part[2] = {0.f, 0.f};
  float4_ accv[2][4];
  #pragma unroll
  for (int qt = 0; qt < 2; ++qt)
    #pragma unroll
    for (int dt = 0; dt < 4; ++dt){ accv[qt][dt][0]=accv[qt][dt][1]=accv[qt][dt][2]=accv[qt][dt][3]=0.f; }
  int wlo = (w > 0) ? w - 1 : 0;
  int whi = (w < NW_ - 1) ? w + 1 : NW_ - 1;
  for (int wi = wlo; wi <= whi; ++wi){
    #pragma unroll
    for (int c = 0; c < 4; ++c){
      int key0 = wi*W_ + c*64;
      const unsigned short* Kc = Kbase + (size_t)key0*QLD_;
      float4_ s[2][4];
      #pragma unroll
      for (int qt = 0; qt < 2; ++qt)
        #pragma unroll
        for (int kt = 0; kt < 4; ++kt){ s[qt][kt][0]=s[qt][kt][1]=s[qt][kt][2]=s[qt][kt][3]=0.f; }
      #pragma unroll
      for (int ks = 0; ks < 2; ++ks){
        short8 kb0 = *(const short8*)&Kc[(size_t)(sA +  0)*QLD_ + ks*32 + kk];
        short8 kb1 = *(const short8*)&Kc[(size_t)(sA +  4)*QLD_ + ks*32 + kk];
        short8 kb2 = *(const short8*)&Kc[(size_t)(sA + 32)*QLD_ + ks*32 + kk];
        short8 kb3 = *(const short8*)&Kc[(size_t)(sA + 36)*QLD_ + ks*32 + kk];
        #pragma unroll
        for (int qt = 0; qt < 2; ++qt){
          s[qt][0] = __builtin_amdgcn_mfma_f32_16x16x32_bf16(kb0, qa[qt][ks], s[qt][0], 0, 0, 0);
          s[qt][1] = __builtin_amdgcn_mfma_f32_16x16x32_bf16(kb1, qa[qt][ks], s[qt][1], 0, 0, 0);
          s[qt][2] = __builtin_amdgcn_mfma_f32_16x16x32_bf16(kb2, qa[qt][ks], s[qt][2], 0, 0, 0);
          s[qt][3] = __builtin_amdgcn_mfma_f32_16x16x32_bf16(kb3, qa[qt][ks], s[qt][3], 0, 0, 0);
        }
      }
      short8 af[2][2];
      #pragma unroll
      for (int qt = 0; qt < 2; ++qt){
        float p[4][4];
        float rs = 0.f;
        #pragma unroll
        for (int kt = 0; kt < 4; ++kt)
          #pragma unroll
          for (int r = 0; r < 4; ++r){
            p[kt][r] = __expf(s[qt][kt][r]);
            rs += p[kt][r];
          }
        l_part[qt] += rs;
        #pragma unroll
        for (int half = 0; half < 2; ++half){
          short8 a;
          #pragma unroll
          for (int r = 0; r < 4; ++r){
            a[r]     = (short)f2b(p[half*2 + 0][r]);
            a[r + 4] = (short)f2b(p[half*2 + 1][r]);
          }
          af[qt][half] = a;
        }
      }
      #pragma unroll
      for (int ks = 0; ks < 2; ++ks){
        short8 vb0 = *(const short8*)&Vrow[(size_t)( 0 + l15)*N_ + key0 + ks*32 + kk];
        short8 vb1 = *(const short8*)&Vrow[(size_t)(16 + l15)*N_ + key0 + ks*32 + kk];
        short8 vb2 = *(const short8*)&Vrow[(size_t)(32 + l15)*N_ + key0 + ks*32 + kk];
        short8 vb3 = *(const short8*)&Vrow[(size_t)(48 + l15)*N_ + key0 + ks*32 + kk];
        #pragma unroll
        for (int qt = 0; qt < 2; ++qt){
          accv[qt][0] = __builtin_amdgcn_mfma_f32_16x16x32_bf16(af[qt][ks], vb0, accv[qt][0], 0, 0, 0);
          accv[qt][1] = __builtin_amdgcn_mfma_f32_16x16x32_bf16(af[qt][ks], vb1, accv[qt][1], 0, 0, 0);
          accv[qt][2] = __builtin_amdgcn_mfma_f32_16x16x32_bf16(af[qt][ks], vb2, accv[qt][2], 0, 0, 0);
          accv[qt][3] = __builtin_amdgcn_mfma_f32_16x16x32_bf16(af[qt][ks], vb3, accv[qt][3], 0, 0, 0);
        }
      }
    }
  }
  #pragma unroll
  for (int qt = 0; qt < 2; ++qt){
    float lv = l_part[qt];
    lv += __shfl_xor(lv, 16, 64);
    lv += __shfl_xor(lv, 32, 64);
    float ilq[4];
    #pragma unroll
    for (int r = 0; r < 4; ++r)
      ilq[r] = 1.f/__shfl(lv, (lane & 48) | (p4*4 + r), 64);
    #pragma unroll
    for (int dt = 0; dt < 4; ++dt)
      #pragma unroll
      for (int r = 0; r < 4; ++r)
        attnb[((size_t)b*N_ + q0 + qt*16 + p4*4 + r)*D_ + col0 + dt*16 + l15] = f2b(accv[qt][dt][r]*ilq[r]);
  }
}

// ---------------------------------------------------------------- host launch
extern "C" void kernel_launch(void* const* d_in, const int* in_sizes, int n_in,
                              void* d_out, int out_size, void* d_ws, size_t ws_size,
                              hipStream_t stream){
  const float* x    = (const float*)d_in[0];
  const float* Wq   = (const float*)d_in[1];
  const float* Wk   = (const float*)d_in[2];
  const float* Wv   = (const float*)d_in[3];
  const float* Wo   = (const float*)d_in[4];
  const float* bo   = (const float*)d_in[5];
  const float* proj = (const float*)d_in[6];
  float* out = (float*)d_out;
  char* ws = (char*)d_ws;

  const size_t o_Wqt  = 0;                               // Wqt|Wkt|Wvt contiguous = fused B
  const size_t o_Wkt  = o_Wqt  + (size_t)D_*D_*2;
  const size_t o_Wvt  = o_Wkt  + (size_t)D_*D_*2;
  const size_t o_Wot  = o_Wvt  + (size_t)D_*D_*2;
  const size_t o_Xb   = o_Wot  + (size_t)D_*D_*2;        // reused as attnb
  const size_t o_QKV  = o_Xb   + (size_t)R_*D_*2;        // [R][3072]
  const size_t o_Vt   = o_QKV  + (size_t)R_*QLD_*2;
  const size_t o_phikT= o_Vt   + (size_t)B_*H_*DH_*N_*2;
  const size_t o_ctxp = o_phikT+ (size_t)B_*GH_*N_*M_*2;
  const size_t o_ksum = o_ctxp + (size_t)16*B_*GH_*M_*DH_*4;
  const size_t o_vcol = o_ksum + (size_t)B_*GH_*M_*4;
  const size_t o_ctxT = o_vcol + (size_t)B_*GH_*DH_*4;
  const size_t o_projb= o_ctxT + (size_t)B_*GH_*DH_*M_*2;
  const size_t o_bmax = o_projb+ (size_t)M_*DH_*2;

  unsigned short* Wqt  = (unsigned short*)(ws + o_Wqt);
  unsigned short* Wkt  = (unsigned short*)(ws + o_Wkt);
  unsigned short* Wvt  = (unsigned short*)(ws + o_Wvt);
  unsigned short* Wot  = (unsigned short*)(ws + o_Wot);
  unsigned short* Xb   = (unsigned short*)(ws + o_Xb);
  unsigned short* attnb= Xb;
  unsigned short* QKV  = (unsigned short*)(ws + o_QKV);
  unsigned short* Vt   = (unsigned short*)(ws + o_Vt);
  unsigned short* phikT= (unsigned short*)(ws + o_phikT);
  float*          ctxp = (float*)(ws + o_ctxp);
  float*          ksum = (float*)(ws + o_ksum);
  float*          vcol = (float*)(ws + o_vcol);
  unsigned short* ctxT = (unsigned short*)(ws + o_ctxT);
  unsigned short* projb= (unsigned short*)(ws + o_projb);
  float*          bmax = (float*)(ws + o_bmax);

  (void)in_sizes; (void)n_in; (void)out_size; (void)ws_size;

  // zero ksum + vcol (contiguous)
  (void)hipMemsetAsync(ws + o_ksum, 0, (size_t)B_*GH_*M_*4 + (size_t)B_*GH_*DH_*4, stream);
  cast_f32_bf16<<<R_*D_/8/256, 256, 0, stream>>>(x, Xb, proj, projb, R_*D_/8);
  transpose_w<<<dim3(16,16,4), 256, 0, stream>>>(Wq, Wk, Wv, Wo, Wqt, Wkt, Wvt, Wot);

  // fused QKV projection: C[row][3072] = Xb @ [Wqt|Wkt|Wvt]^T
  gemm_bf16<0><<<dim3(64,24), 256, 0, stream>>>(Xb, Wqt, QKV, nullptr, nullptr, D_, QLD_);

  transpose_v<<<dim3(64,16,2), 256, 0, stream>>>(QKV + 2048, Vt, vcol);

  phik_finish<<<dim3(64,8,2), 256, 0, stream>>>(QKV + 1024, projb, phikT, ksum, bmax);

  ctx_kernel<<<dim3(16,8,2), 256, 0, stream>>>(phikT, Vt, ctxp);
  ctx_reduce<<<dim3(16,16), 256, 0, stream>>>(ctxp, vcol, bmax, ctxT);
  phiq_outg<<<dim3(64,8,2), 256, 0, stream>>>(QKV, projb, ctxT, ksum, bmax, attnb);
  local_attn_kernel<<<512, 256, 0, stream>>>(QKV, QKV + 1024, Vt, attnb);

  gemm_bf16<1><<<dim3(64,8), 256, 0, stream>>>(attnb, Wot, nullptr, out, bo, D_, D_);
}

// Round 15
// 247.722 us; speedup vs baseline: 1.2860x; 1.0043x over previous
//
#include <hip/hip_runtime.h>
#include <hip/hip_bf16.h>

#define B_ 2
#define N_ 4096
#define D_ 1024
#define QLD_ 3072
#define H_ 16
#define GH_ 8
#define DH_ 64
#define M_ 256
#define W_ 256
#define NW_ 16
#define EPS_ 1e-4f
#define RATIO_ 0.0625f
#define R_ (B_*N_)

typedef __attribute__((ext_vector_type(8))) short short8;
typedef __attribute__((ext_vector_type(4))) short short4_;
typedef __attribute__((ext_vector_type(4))) float float4_;

__device__ __forceinline__ float b2f(unsigned short u){
  union { unsigned int i; float f; } x; x.i = ((unsigned int)u) << 16; return x.f;
}
__device__ __forceinline__ unsigned short f2b(float f){
  unsigned int u = __float_as_uint(f);
  u = u + 0x7FFFu + ((u >> 16) & 1u);
  return (unsigned short)(u >> 16);
}
__device__ __forceinline__ void gl_lds16(const unsigned short* g, unsigned short* l){
  __builtin_amdgcn_global_load_lds((const __attribute__((address_space(1))) unsigned int*)g,
                                   (__attribute__((address_space(3))) unsigned int*)l, 16, 0, 0);
}

// ---------------------------------------------------------------- cast x (+ proj cast fused)
__global__ void cast_f32_bf16(const float* __restrict__ src, unsigned short* __restrict__ dst,
                              const float* __restrict__ proj, unsigned short* __restrict__ projb,
                              int n8){
  int i = blockIdx.x*256 + threadIdx.x;
  if (i < M_*DH_) projb[i] = f2b(proj[i]*0.35355339059327373f);
  if (i >= n8) return;
  const float4_* sp = (const float4_*)src + (size_t)i*2;
  float4_ a = sp[0], b = sp[1];
  short8 o;
  o[0]=(short)f2b(a[0]); o[1]=(short)f2b(a[1]); o[2]=(short)f2b(a[2]); o[3]=(short)f2b(a[3]);
  o[4]=(short)f2b(b[0]); o[5]=(short)f2b(b[1]); o[6]=(short)f2b(b[2]); o[7]=(short)f2b(b[3]);
  *((short8*)dst + i) = o;
}

__global__ void transpose_w(const float* w0, const float* w1, const float* w2, const float* w3,
                            unsigned short* t0, unsigned short* t1, unsigned short* t2, unsigned short* t3){
  const float* src; unsigned short* dst;
  switch (blockIdx.z){
    case 0: src = w0; dst = t0; break;
    case 1: src = w1; dst = t1; break;
    case 2: src = w2; dst = t2; break;
    default: src = w3; dst = t3; break;
  }
  __shared__ float tile[64][65];
  int r0 = blockIdx.x*64, c0 = blockIdx.y*64;
  for (int it = 0; it < 16; ++it){
    int idx = it*256 + threadIdx.x;
    int r = idx >> 6, c = idx & 63;
    tile[r][c] = src[(size_t)(r0 + r)*D_ + c0 + c];
  }
  __syncthreads();
  for (int it = 0; it < 16; ++it){
    int idx = it*256 + threadIdx.x;
    int r = idx >> 6, c = idx & 63;
    dst[(size_t)(c0 + r)*D_ + r0 + c] = f2b(tile[c][r]);
  }
}

// QKV[b][n][2048+col] (V cols) -> Vt[b*H+h][d][n]; also vcol[bh][d] = sum_n V for global heads
__global__ void transpose_v(const unsigned short* __restrict__ Vb, unsigned short* __restrict__ Vt,
                            float* __restrict__ vcol){
  __shared__ unsigned short tile[64*72];
  int nt = blockIdx.x, h = blockIdx.y, b = blockIdx.z;
  int n0 = nt*64, col0 = h*64;
  int tid = threadIdx.x;
  int r = tid >> 2, c16 = (tid & 3)*16;
  #pragma unroll
  for (int g = 0; g < 2; ++g){
    short8 v = *(const short8*)&Vb[((size_t)b*N_ + n0 + r)*QLD_ + col0 + c16 + g*8];
    #pragma unroll
    for (int e = 0; e < 8; ++e) tile[r*72 + c16 + g*8 + e] = (unsigned short)v[e];
  }
  __syncthreads();
  if (h < GH_){
    int c = tid & 63, g = tid >> 6;
    float s = 0.f;
    #pragma unroll
    for (int i = 0; i < 16; ++i) s += b2f(tile[(g*16 + i)*72 + c]);
    atomicAdd(&vcol[(b*GH_ + h)*64 + c], s);
  }
  int d = tid >> 2, ng = (tid & 3)*16;
  short8 o0, o1;
  #pragma unroll
  for (int e = 0; e < 8; ++e){ o0[e] = (short)tile[(ng + e)*72 + d]; o1[e] = (short)tile[(ng + 8 + e)*72 + d]; }
  size_t ob = ((size_t)(b*H_ + h)*64 + d)*N_ + n0 + ng;
  *(short8*)&Vt[ob] = o0;
  *(short8*)&Vt[ob + 8] = o1;
}

// ---------------------------------------------------------------- GEMM: R12's proven BK=64 sub-tile math
// + minimum 2-phase pipeline (stage NEXT tile before computing CURRENT; ONE __syncthreads per tile,
// whose implicit vmcnt(0) lands after compute has covered the load latency). NT must be even (K=1024).
template<int FINAL>
__launch_bounds__(256)
__global__ void gemm_bf16(const unsigned short* __restrict__ A, const unsigned short* __restrict__ Bt,
                          unsigned short* __restrict__ Cb, float* __restrict__ Cf,
                          const float* __restrict__ bias, int K, int Ncols){
  __shared__ __attribute__((aligned(16))) unsigned short As0[2][4096];
  __shared__ __attribute__((aligned(16))) unsigned short Bs0[2][4096];
  __shared__ __attribute__((aligned(16))) unsigned short As1[2][4096];
  __shared__ __attribute__((aligned(16))) unsigned short Bs1[2][4096];
  int tid = threadIdx.x, lane = tid & 63, wave = tid >> 6;
  int bm = blockIdx.x*128, bn = blockIdx.y*128;
  int wm = (wave >> 1)*64, wn = (wave & 1)*64;
  float4_ acc[4][4];
  #pragma unroll
  for (int i = 0; i < 4; ++i)
    #pragma unroll
    for (int j = 0; j < 4; ++j)
      #pragma unroll
      for (int r = 0; r < 4; ++r) acc[i][j][r] = 0.f;
  int srow = tid >> 2, c = tid & 3;
  int scol = (c ^ ((srow >> 1) & 3))*8;
  const unsigned short* a0 = &A[(size_t)(bm + srow)*K + scol];
  const unsigned short* a1 = &A[(size_t)(bm + 64 + srow)*K + scol];
  const unsigned short* b0 = &Bt[(size_t)(bn + srow)*K + scol];
  const unsigned short* b1 = &Bt[(size_t)(bn + 64 + srow)*K + scol];
  int p4 = lane >> 4, l15 = lane & 15;

#define STAGE_(bi, ko) do{ \
    gl_lds16(a0 + (ko),      &As0[bi][tid*8]); \
    gl_lds16(a1 + (ko),      &As0[bi][2048 + tid*8]); \
    gl_lds16(b0 + (ko),      &Bs0[bi][tid*8]); \
    gl_lds16(b1 + (ko),      &Bs0[bi][2048 + tid*8]); \
    gl_lds16(a0 + (ko) + 32, &As1[bi][tid*8]); \
    gl_lds16(a1 + (ko) + 32, &As1[bi][2048 + tid*8]); \
    gl_lds16(b0 + (ko) + 32, &Bs1[bi][tid*8]); \
    gl_lds16(b1 + (ko) + 32, &Bs1[bi][2048 + tid*8]); \
  }while(0)

#define COMPUTE_(bi) do{ \
    short8 af[4], bf[4]; \
    _Pragma("unroll") \
    for (int i = 0; i < 4; ++i){ \
      int row = wm + i*16 + l15; \
      af[i] = *(const short8*)&As0[bi][row*32 + (p4 ^ ((row >> 1) & 3))*8]; \
    } \
    _Pragma("unroll") \
    for (int j = 0; j < 4; ++j){ \
      int row = wn + j*16 + l15; \
      bf[j] = *(const short8*)&Bs0[bi][row*32 + (p4 ^ ((row >> 1) & 3))*8]; \
    } \
    _Pragma("unroll") \
    for (int i = 0; i < 4; ++i) \
      _Pragma("unroll") \
      for (int j = 0; j < 4; ++j) \
        acc[i][j] = __builtin_amdgcn_mfma_f32_16x16x32_bf16(af[i], bf[j], acc[i][j], 0, 0, 0); \
    _Pragma("unroll") \
    for (int i = 0; i < 4; ++i){ \
      int row = wm + i*16 + l15; \
      af[i] = *(const short8*)&As1[bi][row*32 + (p4 ^ ((row >> 1) & 3))*8]; \
    } \
    _Pragma("unroll") \
    for (int j = 0; j < 4; ++j){ \
      int row = wn + j*16 + l15; \
      bf[j] = *(const short8*)&Bs1[bi][row*32 + (p4 ^ ((row >> 1) & 3))*8]; \
    } \
    _Pragma("unroll") \
    for (int i = 0; i < 4; ++i) \
      _Pragma("unroll") \
      for (int j = 0; j < 4; ++j) \
        acc[i][j] = __builtin_amdgcn_mfma_f32_16x16x32_bf16(af[i], bf[j], acc[i][j], 0, 0, 0); \
  }while(0)

  const int NT = K >> 6;
  STAGE_(0, 0);
  __syncthreads();
  #pragma unroll 1
  for (int t = 0; t < NT; t += 2){
    if (t + 1 < NT) STAGE_(1, (t + 1) << 6);
    COMPUTE_(0);
    __syncthreads();
    if (t + 2 < NT) STAGE_(0, (t + 2) << 6);
    COMPUTE_(1);
    __syncthreads();
  }
#undef STAGE_
#undef COMPUTE_

  int rr = p4*4, cc = l15;
  #pragma unroll
  for (int i = 0; i < 4; ++i)
    #pragma unroll
    for (int j = 0; j < 4; ++j)
      #pragma unroll
      for (int r = 0; r < 4; ++r){
        size_t row = bm + wm + i*16 + rr + r;
        int col = bn + wn + j*16 + cc;
        if (FINAL) Cf[row*(size_t)Ncols + col] = acc[i][j][r] + bias[col];
        else       Cb[row*(size_t)Ncols + col] = f2b(acc[i][j][r]);
      }
}

// ---------------------------------------------------------------- phi-K single pass (stab-deferred),
// prefetch pipeline + coalesced phikT stores + block max -> blkmax[wg] (no single-address atomic).
__launch_bounds__(256)
__global__ void phik_finish(const unsigned short* __restrict__ Kb, const unsigned short* __restrict__ projb,
                            unsigned short* __restrict__ phikT, float* __restrict__ ksum,
                            float* __restrict__ blkmax){
  __shared__ __attribute__((aligned(16))) unsigned short pl[256*64];
  __shared__ float sm4[4];
  int tid = threadIdx.x, lane = tid & 63, wave = tid >> 6;
  int h = blockIdx.y, b = blockIdx.z, nb = blockIdx.x;
  int n0 = nb*64;
  int col0 = h*64;
  int kk = (lane >> 4)*8, l15 = lane & 15;
  int bh = b*GH_ + h;
  size_t rowbase = (size_t)b*N_ + n0 + wave*16;
  short8 qa[2];
  #pragma unroll
  for (int ks = 0; ks < 2; ++ks)
    qa[ks] = *(const short8*)&Kb[(rowbase + l15)*QLD_ + col0 + ks*32 + kk];
  short8 pf[4][2];
  #pragma unroll
  for (int i = 0; i < 4; ++i){
    pf[i][0] = *(const short8*)&projb[(size_t)(i*16 + l15)*DH_ + kk];
    pf[i][1] = *(const short8*)&projb[(size_t)(i*16 + l15)*DH_ + 32 + kk];
  }
  float s = 0.f;
  #pragma unroll
  for (int ks = 0; ks < 2; ++ks)
    #pragma unroll
    for (int j = 0; j < 8; ++j){ float q = b2f((unsigned short)qa[ks][j]); s += q*q; }
  s += __shfl_xor(s, 16, 64);
  s += __shfl_xor(s, 32, 64);
  s *= 0.0625f;
  float dg[4];
  #pragma unroll
  for (int r = 0; r < 4; ++r) dg[r] = __shfl(s, (lane & 48) | ((lane >> 4)*4 + r), 64);
  float mxall = -3e38f;
  #pragma unroll
  for (int mt = 0; mt < 16; ++mt){
    short8 c0 = pf[mt & 3][0], c1 = pf[mt & 3][1];
    if (mt < 12){
      pf[mt & 3][0] = *(const short8*)&projb[(size_t)((mt + 4)*16 + l15)*DH_ + kk];
      pf[mt & 3][1] = *(const short8*)&projb[(size_t)((mt + 4)*16 + l15)*DH_ + 32 + kk];
    }
    float4_ a; a[0]=a[1]=a[2]=a[3]=0.f;
    a = __builtin_amdgcn_mfma_f32_16x16x32_bf16(qa[0], c0, a, 0, 0, 0);
    a = __builtin_amdgcn_mfma_f32_16x16x32_bf16(qa[1], c1, a, 0, 0, 0);
    int m = mt*16 + l15;
    #pragma unroll
    for (int r = 0; r < 4; ++r){
      float ddv = a[r];
      mxall = fmaxf(mxall, ddv);
      float v = __expf(ddv - dg[r]);     // u, stab applied analytically later
      int n = wave*16 + (lane>>4)*4 + r;
      int slot = (n >> 3) ^ (m & 7);
      pl[m*64 + slot*8 + (n & 7)] = f2b(v);
    }
  }
  #pragma unroll
  for (int mm = 1; mm < 64; mm <<= 1) mxall = fmaxf(mxall, __shfl_xor(mxall, mm, 64));
  if (lane == 0) sm4[wave] = mxall;
  __syncthreads();
  if (tid == 0)
    blkmax[((size_t)b*GH_ + h)*64 + nb] = fmaxf(fmaxf(sm4[0], sm4[1]), fmaxf(sm4[2], sm4[3]));
  {
    int m = tid;
    float ssum = 0.f;
    #pragma unroll
    for (int j = 0; j < 8; ++j){
      int slot = j ^ (m & 7);
      short8 v = *(const short8*)&pl[m*64 + slot*8];
      #pragma unroll
      for (int e = 0; e < 8; ++e) ssum += b2f((unsigned short)v[e]);
    }
    atomicAdd(&ksum[bh*M_ + m], ssum);
  }
  size_t outb = ((size_t)bh*64 + nb)*256*64;
  int j2 = tid & 7, mlo = tid >> 3;
  #pragma unroll
  for (int s2 = 0; s2 < 8; ++s2){
    int m2 = s2*32 + mlo;
    short8 v = *(const short8*)&pl[m2*64 + (j2 ^ (m2 & 7))*8];
    *(short8*)&phikT[outb + (size_t)m2*64 + j2*8] = v;
  }
}

// ---------------------------------------------------------------- ctx partials: C[m][d] += uT-chunk @ Vt-chunk
__launch_bounds__(256)
__global__ void ctx_kernel(const unsigned short* __restrict__ phikT, const unsigned short* __restrict__ Vt,
                           float* __restrict__ ctxp){
  int tid = threadIdx.x, lane = tid & 63, wave = tid >> 6;
  int split = blockIdx.x, h = blockIdx.y, b = blockIdx.z;
  int bh = b*GH_ + h;
  int kk = (lane >> 4)*8, l15 = lane & 15;
  float4_ acc[4][4];
  #pragma unroll
  for (int i = 0; i < 4; ++i)
    #pragma unroll
    for (int j = 0; j < 4; ++j)
      #pragma unroll
      for (int r = 0; r < 4; ++r) acc[i][j][r] = 0.f;
  const unsigned short* Abase = phikT + (size_t)bh*64*256*64;
  const unsigned short* Bbase = Vt + (size_t)(b*H_ + h)*64*N_;
  int n0 = split*256;
  #pragma unroll
  for (int ks = 0; ks < 8; ++ks){
    int n = n0 + ks*32;
    int nb = n >> 6, in0 = n & 32;
    short8 af[4], bf[4];
    #pragma unroll
    for (int mt = 0; mt < 4; ++mt)
      af[mt] = *(const short8*)&Abase[((size_t)nb*256 + wave*64 + mt*16 + l15)*64 + in0 + kk];
    #pragma unroll
    for (int dt = 0; dt < 4; ++dt)
      bf[dt] = *(const short8*)&Bbase[(size_t)(dt*16 + l15)*N_ + n + kk];
    #pragma unroll
    for (int mt = 0; mt < 4; ++mt)
      #pragma unroll
      for (int dt = 0; dt < 4; ++dt)
        acc[mt][dt] = __builtin_amdgcn_mfma_f32_16x16x32_bf16(af[mt], bf[dt], acc[mt][dt], 0, 0, 0);
  }
  int rr = (lane >> 4)*4;
  float* obase = ctxp + (((size_t)split*16 + bh)*256)*64;
  #pragma unroll
  for (int mt = 0; mt < 4; ++mt)
    #pragma unroll
    for (int dt = 0; dt < 4; ++dt)
      #pragma unroll
      for (int r = 0; r < 4; ++r)
        obase[(size_t)(wave*64 + mt*16 + rr + r)*64 + dt*16 + l15] = acc[mt][dt][r];
}

// reduce 16 splits, apply ratio*e^{-stab} scale + ratio*eps*vcol -> ctxbT[bh][d][m] bf16
__launch_bounds__(256)
__global__ void ctx_reduce(const float* __restrict__ ctxp, const float* __restrict__ vcol,
                           const float* __restrict__ blkmax, unsigned short* __restrict__ ctxbT){
  __shared__ float tile[16*65];
  __shared__ float smax[4];
  int mt = blockIdx.x, bh = blockIdx.y;
  int tid = threadIdx.x, lane = tid & 63, wave = tid >> 6;
  float bm = -3e38f;
  #pragma unroll
  for (int i = 0; i < 4; ++i) bm = fmaxf(bm, blkmax[i*256 + tid]);
  #pragma unroll
  for (int mm = 1; mm < 64; mm <<= 1) bm = fmaxf(bm, __shfl_xor(bm, mm, 64));
  if (lane == 0) smax[wave] = bm;
  __syncthreads();
  float stab = fmaxf(fmaxf(smax[0], smax[1]), fmaxf(smax[2], smax[3]));
  float es = RATIO_*__expf(-stab);
  float epsr = RATIO_*EPS_;
  int ml = tid >> 4, d4 = (tid & 15)*4;
  const float* base = ctxp + ((size_t)bh*256 + mt*16 + ml)*64 + d4;
  float4_ acc; acc[0]=acc[1]=acc[2]=acc[3]=0.f;
  #pragma unroll
  for (int sp = 0; sp < 16; ++sp){
    float4_ v = *(const float4_*)(base + (size_t)sp*16*256*64);
    acc[0] += v[0]; acc[1] += v[1]; acc[2] += v[2]; acc[3] += v[3];
  }
  #pragma unroll
  for (int e = 0; e < 4; ++e) acc[e] = es*acc[e] + epsr*vcol[bh*64 + d4 + e];
  *(float4_*)&tile[ml*65 + d4] = acc;
  __syncthreads();
  int d = tid >> 2, mg = (tid & 3)*4;
  short4_ o;
  #pragma unroll
  for (int e = 0; e < 4; ++e) o[e] = (short)f2b(tile[(mg + e)*65 + d]);
  *(short4_*)&ctxbT[((size_t)bh*64 + d)*256 + mt*16 + mg] = o;
}

// ---------------------------------------------------------------- fused phi-Q + out_g (prefetch pipeline)
__launch_bounds__(256)
__global__ void phiq_outg(const unsigned short* __restrict__ Qb, const unsigned short* __restrict__ projb,
                          const unsigned short* __restrict__ ctxbT, const float* __restrict__ ksum_u,
                          const float* __restrict__ blkmax, unsigned short* __restrict__ attnb){
  __shared__ __attribute__((aligned(16))) unsigned short pl[4][16*256];
  __shared__ float ks_l[256];
  __shared__ float smax[4];
  int tid = threadIdx.x, lane = tid & 63, wave = tid >> 6;
  int h = blockIdx.y, b = blockIdx.z;
  int n0 = blockIdx.x*64;
  int col0 = h*64;
  int bh = b*GH_ + h;
  int p4 = lane >> 4, l15 = lane & 15, kk = p4*8;
  {
    float bm = -3e38f;
    #pragma unroll
    for (int i = 0; i < 4; ++i) bm = fmaxf(bm, blkmax[i*256 + tid]);
    #pragma unroll
    for (int mm = 1; mm < 64; mm <<= 1) bm = fmaxf(bm, __shfl_xor(bm, mm, 64));
    if (lane == 0) smax[wave] = bm;
  }
  __syncthreads();
  {
    float stab = fmaxf(fmaxf(smax[0], smax[1]), fmaxf(smax[2], smax[3]));
    float es = __expf(-stab);
    ks_l[tid] = RATIO_*(es*ksum_u[bh*M_ + tid] + EPS_*(float)N_);
  }
  __syncthreads();
  size_t rowbase = (size_t)b*N_ + n0 + wave*16;
  short8 qa[2];
  #pragma unroll
  for (int ks = 0; ks < 2; ++ks)
    qa[ks] = *(const short8*)&Qb[(rowbase + l15)*QLD_ + col0 + ks*32 + kk];
  short8 pf[4][2];
  #pragma unroll
  for (int i = 0; i < 4; ++i){
    pf[i][0] = *(const short8*)&projb[(size_t)(i*16 + l15)*DH_ + kk];
    pf[i][1] = *(const short8*)&projb[(size_t)(i*16 + l15)*DH_ + 32 + kk];
  }
  float s = 0.f;
  #pragma unroll
  for (int ks = 0; ks < 2; ++ks)
    #pragma unroll
    for (int j = 0; j < 8; ++j){ float q = b2f((unsigned short)qa[ks][j]); s += q*q; }
  s += __shfl_xor(s, 16, 64);
  s += __shfl_xor(s, 32, 64);
  s *= 0.0625f;
  float dg[4];
  #pragma unroll
  for (int r = 0; r < 4; ++r) dg[r] = __shfl(s, (lane & 48) | (p4*4 + r), 64);
  float4_ dd[16];
  #pragma unroll
  for (int mt = 0; mt < 16; ++mt){
    short8 c0 = pf[mt & 3][0], c1 = pf[mt & 3][1];
    if (mt < 12){
      pf[mt & 3][0] = *(const short8*)&projb[(size_t)((mt + 4)*16 + l15)*DH_ + kk];
      pf[mt & 3][1] = *(const short8*)&projb[(size_t)((mt + 4)*16 + l15)*DH_ + 32 + kk];
    }
    float4_ a; a[0]=a[1]=a[2]=a[3]=0.f;
    a = __builtin_amdgcn_mfma_f32_16x16x32_bf16(qa[0], c0, a, 0, 0, 0);
    a = __builtin_amdgcn_mfma_f32_16x16x32_bf16(qa[1], c1, a, 0, 0, 0);
    dd[mt] = a;
  }
  unsigned short* plw = &pl[wave][0];
  float dinv[4];
  #pragma unroll
  for (int r = 0; r < 4; ++r){
    float mx = dd[0][r];
    #pragma unroll
    for (int mt = 1; mt < 16; ++mt) mx = fmaxf(mx, dd[mt][r]);
    mx = fmaxf(mx, __shfl_xor(mx, 1, 64));
    mx = fmaxf(mx, __shfl_xor(mx, 2, 64));
    mx = fmaxf(mx, __shfl_xor(mx, 4, 64));
    mx = fmaxf(mx, __shfl_xor(mx, 8, 64));
    float sb = mx + dg[r];
    int row = p4*4 + r;
    float dpr = 0.f;
    #pragma unroll
    for (int mt = 0; mt < 16; ++mt){
      float v = RATIO_*(__expf(dd[mt][r] - sb) + EPS_);
      dpr += v*ks_l[mt*16 + l15];
      int q = mt*2 + (l15 >> 3);
      plw[row*256 + ((q ^ (row & 7)) << 3) + (l15 & 7)] = f2b(v);
    }
    dpr += __shfl_xor(dpr, 1, 64);
    dpr += __shfl_xor(dpr, 2, 64);
    dpr += __shfl_xor(dpr, 4, 64);
    dpr += __shfl_xor(dpr, 8, 64);
    dinv[r] = 1.f/dpr;
  }
  float4_ acc[4];
  #pragma unroll
  for (int dt = 0; dt < 4; ++dt){ acc[dt][0]=acc[dt][1]=acc[dt][2]=acc[dt][3]=0.f; }
  #pragma unroll
  for (int ks = 0; ks < 8; ++ks){
    int q = ks*4 + p4;
    short8 af = *(const short8*)&plw[l15*256 + ((q ^ (l15 & 7)) << 3)];
    #pragma unroll
    for (int dt = 0; dt < 4; ++dt){
      short8 bf = *(const short8*)&ctxbT[((size_t)bh*64 + dt*16 + l15)*M_ + ks*32 + kk];
      acc[dt] = __builtin_amdgcn_mfma_f32_16x16x32_bf16(af, bf, acc[dt], 0, 0, 0);
    }
  }
  #pragma unroll
  for (int dt = 0; dt < 4; ++dt)
    #pragma unroll
    for (int r = 0; r < 4; ++r){
      int rloc = wave*16 + p4*4 + r;
      attnb[((size_t)b*N_ + n0 + rloc)*D_ + col0 + dt*16 + l15] = f2b(acc[dt][r]*dinv[r]);
    }
}

// ---------------------------------------------------------------- local windowed attention
// Swapped QK, no online rescale, QT=2, XCD-aware decode (T1).
__launch_bounds__(256)
__global__ void local_attn_kernel(const unsigned short* __restrict__ Qb, const unsigned short* __restrict__ Kb,
                                  const unsigned short* __restrict__ Vt, unsigned short* __restrict__ attnb){
  int tid = threadIdx.x, lane = tid & 63, wv = tid >> 6;
  int wg = blockIdx.x;
  int xcd = wg & 7, k = wg >> 3;
  int pair = xcd*2 + (k >> 5);
  int bx = k & 31;
  int hl = pair & 7, b = pair >> 3;
  int w = bx >> 1;
  int col0 = (GH_ + hl)*64;
  int q0 = bx*128 + wv*32;
  int l15 = lane & 15, p4 = lane >> 4, kk = p4*8;
  int sA = ((l15 >> 2) << 3) + (l15 & 3);
  const unsigned short* Kbase = Kb + (size_t)b*N_*QLD_ + col0;
  const unsigned short* Vrow  = Vt + (size_t)(b*H_ + GH_ + hl)*64*N_;
  short8 qa[2][2];
  #pragma unroll
  for (int qt = 0; qt < 2; ++qt)
    #pragma unroll
    for (int ks = 0; ks < 2; ++ks){
      short8 v = *(const short8*)&Qb[((size_t)b*N_ + q0 + qt*16 + l15)*QLD_ + col0 + ks*32 + kk];
      #pragma unroll
      for (int j = 0; j < 8; ++j) v[j] = (short)f2b(b2f((unsigned short)v[j])*0.125f);
      qa[qt][ks] = v;
    }
  float l_part[2] = {0.f, 0.f};
  float4_ accv[2][4];
  #pragma unroll
  for (int qt = 0; qt < 2; ++qt)
    #pragma unroll
    for (int dt = 0; dt < 4; ++dt){ accv[qt][dt][0]=accv[qt][dt][1]=accv[qt][dt][2]=accv[qt][dt][3]=0.f; }
  int wlo = (w > 0) ? w - 1 : 0;
  int whi = (w < NW_ - 1) ? w + 1 : NW_ - 1;
  for (int wi = wlo; wi <= whi; ++wi){
    #pragma unroll
    for (int c = 0; c < 4; ++c){
      int key0 = wi*W_ + c*64;
      const unsigned short* Kc = Kbase + (size_t)key0*QLD_;
      float4_ s[2][4];
      #pragma unroll
      for (int qt = 0; qt < 2; ++qt)
        #pragma unroll
        for (int kt = 0; kt < 4; ++kt){ s[qt][kt][0]=s[qt][kt][1]=s[qt][kt][2]=s[qt][kt][3]=0.f; }
      #pragma unroll
      for (int ks = 0; ks < 2; ++ks){
        short8 kb0 = *(const short8*)&Kc[(size_t)(sA +  0)*QLD_ + ks*32 + kk];
        short8 kb1 = *(const short8*)&Kc[(size_t)(sA +  4)*QLD_ + ks*32 + kk];
        short8 kb2 = *(const short8*)&Kc[(size_t)(sA + 32)*QLD_ + ks*32 + kk];
        short8 kb3 = *(const short8*)&Kc[(size_t)(sA + 36)*QLD_ + ks*32 + kk];
        #pragma unroll
        for (int qt = 0; qt < 2; ++qt){
          s[qt][0] = __builtin_amdgcn_mfma_f32_16x16x32_bf16(kb0, qa[qt][ks], s[qt][0], 0, 0, 0);
          s[qt][1] = __builtin_amdgcn_mfma_f32_16x16x32_bf16(kb1, qa[qt][ks], s[qt][1], 0, 0, 0);
          s[qt][2] = __builtin_amdgcn_mfma_f32_16x16x32_bf16(kb2, qa[qt][ks], s[qt][2], 0, 0, 0);
          s[qt][3] = __builtin_amdgcn_mfma_f32_16x16x32_bf16(kb3, qa[qt][ks], s[qt][3], 0, 0, 0);
        }
      }
      short8 af[2][2];
      #pragma unroll
      for (int qt = 0; qt < 2; ++qt){
        float p[4][4];
        float rs = 0.f;
        #pragma unroll
        for (int kt = 0; kt < 4; ++kt)
          #pragma unroll
          for (int r = 0; r < 4; ++r){
            p[kt][r] = __expf(s[qt][kt][r]);
            rs += p[kt][r];
          }
        l_part[qt] += rs;
        #pragma unroll
        for (int half = 0; half < 2; ++half){
          short8 a;
          #pragma unroll
          for (int r = 0; r < 4; ++r){
            a[r]     = (short)f2b(p[half*2 + 0][r]);
            a[r + 4] = (short)f2b(p[half*2 + 1][r]);
          }
          af[qt][half] = a;
        }
      }
      #pragma unroll
      for (int ks = 0; ks < 2; ++ks){
        short8 vb0 = *(const short8*)&Vrow[(size_t)( 0 + l15)*N_ + key0 + ks*32 + kk];
        short8 vb1 = *(const short8*)&Vrow[(size_t)(16 + l15)*N_ + key0 + ks*32 + kk];
        short8 vb2 = *(const short8*)&Vrow[(size_t)(32 + l15)*N_ + key0 + ks*32 + kk];
        short8 vb3 = *(const short8*)&Vrow[(size_t)(48 + l15)*N_ + key0 + ks*32 + kk];
        #pragma unroll
        for (int qt = 0; qt < 2; ++qt){
          accv[qt][0] = __builtin_amdgcn_mfma_f32_16x16x32_bf16(af[qt][ks], vb0, accv[qt][0], 0, 0, 0);
          accv[qt][1] = __builtin_amdgcn_mfma_f32_16x16x32_bf16(af[qt][ks], vb1, accv[qt][1], 0, 0, 0);
          accv[qt][2] = __builtin_amdgcn_mfma_f32_16x16x32_bf16(af[qt][ks], vb2, accv[qt][2], 0, 0, 0);
          accv[qt][3] = __builtin_amdgcn_mfma_f32_16x16x32_bf16(af[qt][ks], vb3, accv[qt][3], 0, 0, 0);
        }
      }
    }
  }
  #pragma unroll
  for (int qt = 0; qt < 2; ++qt){
    float lv = l_part[qt];
    lv += __shfl_xor(lv, 16, 64);
    lv += __shfl_xor(lv, 32, 64);
    float ilq[4];
    #pragma unroll
    for (int r = 0; r < 4; ++r)
      ilq[r] = 1.f/__shfl(lv, (lane & 48) | (p4*4 + r), 64);
    #pragma unroll
    for (int dt = 0; dt < 4; ++dt)
      #pragma unroll
      for (int r = 0; r < 4; ++r)
        attnb[((size_t)b*N_ + q0 + qt*16 + p4*4 + r)*D_ + col0 + dt*16 + l15] = f2b(accv[qt][dt][r]*ilq[r]);
  }
}

// ---------------------------------------------------------------- host launch
extern "C" void kernel_launch(void* const* d_in, const int* in_sizes, int n_in,
                              void* d_out, int out_size, void* d_ws, size_t ws_size,
                              hipStream_t stream){
  const float* x    = (const float*)d_in[0];
  const float* Wq   = (const float*)d_in[1];
  const float* Wk   = (const float*)d_in[2];
  const float* Wv   = (const float*)d_in[3];
  const float* Wo   = (const float*)d_in[4];
  const float* bo   = (const float*)d_in[5];
  const float* proj = (const float*)d_in[6];
  float* out = (float*)d_out;
  char* ws = (char*)d_ws;

  const size_t o_Wqt  = 0;                               // Wqt|Wkt|Wvt contiguous = fused B
  const size_t o_Wkt  = o_Wqt  + (size_t)D_*D_*2;
  const size_t o_Wvt  = o_Wkt  + (size_t)D_*D_*2;
  const size_t o_Wot  = o_Wvt  + (size_t)D_*D_*2;
  const size_t o_Xb   = o_Wot  + (size_t)D_*D_*2;        // reused as attnb
  const size_t o_QKV  = o_Xb   + (size_t)R_*D_*2;        // [R][3072]
  const size_t o_Vt   = o_QKV  + (size_t)R_*QLD_*2;
  const size_t o_phikT= o_Vt   + (size_t)B_*H_*DH_*N_*2;
  const size_t o_ctxp = o_phikT+ (size_t)B_*GH_*N_*M_*2;
  const size_t o_ksum = o_ctxp + (size_t)16*B_*GH_*M_*DH_*4;
  const size_t o_vcol = o_ksum + (size_t)B_*GH_*M_*4;
  const size_t o_ctxT = o_vcol + (size_t)B_*GH_*DH_*4;
  const size_t o_projb= o_ctxT + (size_t)B_*GH_*DH_*M_*2;
  const size_t o_bmax = o_projb+ (size_t)M_*DH_*2;

  unsigned short* Wqt  = (unsigned short*)(ws + o_Wqt);
  unsigned short* Wkt  = (unsigned short*)(ws + o_Wkt);
  unsigned short* Wvt  = (unsigned short*)(ws + o_Wvt);
  unsigned short* Wot  = (unsigned short*)(ws + o_Wot);
  unsigned short* Xb   = (unsigned short*)(ws + o_Xb);
  unsigned short* attnb= Xb;
  unsigned short* QKV  = (unsigned short*)(ws + o_QKV);
  unsigned short* Vt   = (unsigned short*)(ws + o_Vt);
  unsigned short* phikT= (unsigned short*)(ws + o_phikT);
  float*          ctxp = (float*)(ws + o_ctxp);
  float*          ksum = (float*)(ws + o_ksum);
  float*          vcol = (float*)(ws + o_vcol);
  unsigned short* ctxT = (unsigned short*)(ws + o_ctxT);
  unsigned short* projb= (unsigned short*)(ws + o_projb);
  float*          bmax = (float*)(ws + o_bmax);

  (void)in_sizes; (void)n_in; (void)out_size; (void)ws_size;

  // zero ksum + vcol (contiguous)
  (void)hipMemsetAsync(ws + o_ksum, 0, (size_t)B_*GH_*M_*4 + (size_t)B_*GH_*DH_*4, stream);
  cast_f32_bf16<<<R_*D_/8/256, 256, 0, stream>>>(x, Xb, proj, projb, R_*D_/8);
  transpose_w<<<dim3(16,16,4), 256, 0, stream>>>(Wq, Wk, Wv, Wo, Wqt, Wkt, Wvt, Wot);

  // fused QKV projection: C[row][3072] = Xb @ [Wqt|Wkt|Wvt]^T
  gemm_bf16<0><<<dim3(64,24), 256, 0, stream>>>(Xb, Wqt, QKV, nullptr, nullptr, D_, QLD_);

  transpose_v<<<dim3(64,16,2), 256, 0, stream>>>(QKV + 2048, Vt, vcol);

  phik_finish<<<dim3(64,8,2), 256, 0, stream>>>(QKV + 1024, projb, phikT, ksum, bmax);

  ctx_kernel<<<dim3(16,8,2), 256, 0, stream>>>(phikT, Vt, ctxp);
  ctx_reduce<<<dim3(16,16), 256, 0, stream>>>(ctxp, vcol, bmax, ctxT);
  phiq_outg<<<dim3(64,8,2), 256, 0, stream>>>(QKV, projb, ctxT, ksum, bmax, attnb);
  local_attn_kernel<<<512, 256, 0, stream>>>(QKV, QKV + 1024, Vt, attnb);

  gemm_bf16<1><<<dim3(64,8), 256, 0, stream>>>(attnb, Wot, nullptr, out, bo, D_, D_);
}